// Round 15
// baseline (663.347 us; speedup 1.0000x reference)
//
#include <hip/hip_runtime.h>
#include <hip/hip_bf16.h>
#include <math.h>

#define BN_ 32
#define CIN 512
#define KN 1024
#define CMID 128
#define COUT 64
#define NCLS 5
#define NUM_TOP 205
#define NUM_KEPT 409
#define NUM_DROP 410
#define ADJ_KK 204
#define EPSF 1e-8f
#define INV_DS (1.0f / 0.599609375f)

typedef __bf16 bf16x8 __attribute__((ext_vector_type(8)));
typedef float f32x4 __attribute__((ext_vector_type(4)));

__device__ inline ushort f2bf(float x) {
  union { __hip_bfloat16 b; ushort u; } c;
  c.b = __float2bfloat16(x);
  return c.u;
}

// async global->LDS, 16B per lane (dest = wave-uniform base + lane*16)
__device__ inline void gll16(const ushort* g, ushort* l) {
  __builtin_amdgcn_global_load_lds(
      (const __attribute__((address_space(1))) unsigned int*)g,
      (__attribute__((address_space(3))) unsigned int*)l, 16, 0, 0);
}

// ---------------- masks stage 1: top mask via rank counting --------------
__global__ __launch_bounds__(256) void masks1_kernel(const float* __restrict__ imp,
                                                     float* __restrict__ topM) {
  int b = blockIdx.y;
  int i = blockIdx.x * 256 + threadIdx.x;
  __shared__ float im[KN];
  for (int j = threadIdx.x; j < KN; j += 256) im[j] = imp[(size_t)b * KN + j];
  __syncthreads();
  float vi = im[i];
  int r0 = 0, r1 = 0, r2 = 0, r3 = 0;
  for (int j = 0; j < KN; j += 4) {
    float a0 = im[j], a1 = im[j + 1], a2 = im[j + 2], a3 = im[j + 3];
    r0 += (a0 > vi || (a0 == vi && j < i)) ? 1 : 0;
    r1 += (a1 > vi || (a1 == vi && j + 1 < i)) ? 1 : 0;
    r2 += (a2 > vi || (a2 == vi && j + 2 < i)) ? 1 : 0;
    r3 += (a3 > vi || (a3 == vi && j + 3 < i)) ? 1 : 0;
  }
  int rank = r0 + r1 + r2 + r3;
  topM[(size_t)b * KN + i] = (rank < NUM_TOP) ? 1.0f : 0.0f;
}

// ---------------- masks stage 2: kept/drop ranks, fused ------------------
__global__ __launch_bounds__(256) void masks2_kernel(const float* __restrict__ rnd,
                                                     const float* __restrict__ topM,
                                                     float* __restrict__ mTK,
                                                     float* __restrict__ mTD) {
  int b = blockIdx.y;
  int i = blockIdx.x * 256 + threadIdx.x;
  __shared__ float r1s[KN];
  __shared__ float r2s[KN];
  for (int j = threadIdx.x; j < KN; j += 256) {
    float tv = topM[(size_t)b * KN + j];
    float rv = rnd[(size_t)b * KN + j];
    r1s[j] = (tv > 0.5f) ? -10.0f : rv;
    r2s[j] = (tv > 0.5f) ? 10.0f : rv;
  }
  __syncthreads();
  float v1 = r1s[i];
  float v2 = r2s[i];
  int c1a = 0, c1b = 0, c2a = 0, c2b = 0;
  for (int j = 0; j < KN; j += 2) {
    float a0 = r1s[j], a1 = r1s[j + 1];
    float b0 = r2s[j], b1 = r2s[j + 1];
    c1a += (a0 > v1 || (a0 == v1 && j < i)) ? 1 : 0;
    c1b += (a1 > v1 || (a1 == v1 && j + 1 < i)) ? 1 : 0;
    c2a += (b0 < v2 || (b0 == v2 && j < i)) ? 1 : 0;
    c2b += (b1 < v2 || (b1 == v2 && j + 1 < i)) ? 1 : 0;
  }
  int kept = (c1a + c1b) < NUM_KEPT;
  int drop = (c2a + c2b) < NUM_DROP;
  int top = topM[(size_t)b * KN + i] > 0.5f;
  mTK[(size_t)b * KN + i] = (top || kept) ? 1.0f : 0.0f;
  mTD[(size_t)b * KN + i] = (top || drop) ? 1.0f : 0.0f;
}

// ---------------- adjP row-sum reciprocals -------------------------------
__global__ void psum_kernel(const float* __restrict__ imp, float* __restrict__ invSumP) {
  int b = blockIdx.y;
  int i = blockIdx.x * 256 + threadIdx.x;
  __shared__ float im[KN];
  for (int j = threadIdx.x; j < KN; j += 256) im[j] = imp[(size_t)b * KN + j];
  __syncthreads();
  float vi = im[i];
  float s = 0.0f;
  for (int j = 0; j < KN; ++j) {
    float d = vi - im[j];
    s += __expf(-d * d * 0.125f);
  }
  invSumP[(size_t)b * KN + i] = 1.0f / (s + 1.0f + EPSF);
}

// ---------------- per-column L2 norm reciprocals -------------------------
template <int C>
__global__ void colnorm_kernel(const float* __restrict__ f, float* __restrict__ inv) {
  int idx = blockIdx.x * 256 + threadIdx.x;
  int b = idx >> 10;
  int k = idx & (KN - 1);
  const float* fb = f + (size_t)b * C * KN + k;
  float ss = 0.0f;
  for (int c = 0; c < C; ++c) {
    float v = fb[(size_t)c * KN];
    ss += v * v;
  }
  inv[idx] = 1.0f / (sqrtf(ss) + EPSF);
}

// ------- transpose + normalize + bf16: oT[b][k][c] = f[b][c][k]*inv[b][k] --
template <int C>
__global__ void xpose_kernel(const float* __restrict__ f, const float* __restrict__ inv,
                             __hip_bfloat16* __restrict__ oT) {
  int b = blockIdx.z;
  int k0 = blockIdx.x * 64;
  int c0 = blockIdx.y * 64;
  __shared__ float t[64][65];
  const float* fb = f + (size_t)b * C * KN;
  int tx = threadIdx.x & 63;
  int ty = threadIdx.x >> 6;
  for (int r = 0; r < 64; r += 4) t[r + ty][tx] = fb[(size_t)(c0 + r + ty) * KN + k0 + tx];
  __syncthreads();
  __hip_bfloat16* ob = oT + (size_t)b * KN * C;
  for (int r = 0; r < 64; r += 4) {
    int k = r + ty;
    float s = inv[(size_t)b * KN + k0 + k];
    ob[(size_t)(k0 + k) * C + c0 + tx] = __float2bfloat16(t[tx][k] * s);
  }
}

// ---------------- MFMA sim: sim = XnT * XnT^T (Gram, symmetric) ----------
template <int C>
__global__ __launch_bounds__(256) void simf_kernel(const ushort* __restrict__ xT,
                                                   float* __restrict__ sim, int bstart, int nb) {
  int f = blockIdx.x;
  int brel, tile;
  if ((nb & 7) == 0) {
    int xcd = f & 7;
    int wdx = f >> 3;
    brel = xcd * (nb >> 3) + (wdx >> 6);
    tile = wdx & 63;
  } else {
    brel = f >> 6;
    tile = f & 63;
  }
  int b = bstart + brel;
  int t = threadIdx.x;
  int lane = t & 63;
  int wid = t >> 6;
  int iB = (tile >> 3) * 128;
  int jB = (tile & 7) * 128;
  const ushort* X = xT + (size_t)b * KN * C;

  __shared__ ushort As[2][128 * 32];
  __shared__ ushort Bs[2][128 * 32];
  __shared__ float ep[4][16][65];

  int srow = t >> 2;
  int scol = (t & 3) * 8;
  int ldst = t * 8;

  auto stage = [&](int buf, int c0) {
    gll16(X + (size_t)(iB + srow) * C + c0 + scol, &As[buf][ldst]);
    gll16(X + (size_t)(iB + 64 + srow) * C + c0 + scol, &As[buf][2048 + ldst]);
    gll16(X + (size_t)(jB + srow) * C + c0 + scol, &Bs[buf][ldst]);
    gll16(X + (size_t)(jB + 64 + srow) * C + c0 + scol, &Bs[buf][2048 + ldst]);
  };

  int i0loc = (wid >> 1) * 64;
  int j0loc = (wid & 1) * 64;
  int r = lane & 15;
  int s = (lane >> 4) * 8;

  f32x4 acc[4][4] = {};
  stage(0, 0);
  __syncthreads();
  constexpr int NT = C / 32;
  int cur = 0;
#pragma unroll 2
  for (int ks = 0; ks < NT; ++ks) {
    if (ks + 1 < NT) stage(cur ^ 1, (ks + 1) * 32);
    bf16x8 a[4], bb[4];
#pragma unroll
    for (int m = 0; m < 4; ++m)
      a[m] = *reinterpret_cast<const bf16x8*>(&As[cur][(i0loc + m * 16 + r) * 32 + s]);
#pragma unroll
    for (int n = 0; n < 4; ++n)
      bb[n] = *reinterpret_cast<const bf16x8*>(&Bs[cur][(j0loc + n * 16 + r) * 32 + s]);
#pragma unroll
    for (int m = 0; m < 4; ++m)
#pragma unroll
      for (int n = 0; n < 4; ++n)
        acc[m][n] = __builtin_amdgcn_mfma_f32_16x16x32_bf16(a[m], bb[n], acc[m][n], 0, 0, 0);
    __syncthreads();
    cur ^= 1;
  }

  float(*buf)[65] = ep[wid];
  int orow = (lane >> 4) * 4;
  int ocol = lane & 15;
  int i0 = iB + i0loc;
  int j0 = jB + j0loc;
  float* simb = sim + (size_t)brel * KN * KN;
#pragma unroll
  for (int m = 0; m < 4; ++m) {
#pragma unroll
    for (int n = 0; n < 4; ++n)
#pragma unroll
      for (int rr = 0; rr < 4; ++rr) buf[orow + rr][n * 16 + ocol] = acc[m][n][rr];
#pragma unroll
    for (int rr = 0; rr < 4; ++rr) {
      int row = rr * 4 + (lane >> 4);
      float4 v4 = *(const float4*)&buf[row][(lane & 15) * 4];
      *(float4*)(simb + (size_t)(i0 + m * 16 + row) * KN + j0 + (lane & 15) * 4) = v4;
    }
  }
}

// ------- fused per-wave threshold select + finalize ----------------------
// Bisection over bits 31..8 (24-bit threshold granularity). Count split
// across pipes: 8 keys ballot+s_bcnt (SALU), 8 keys per-lane + shfl (VALU/DS).
__global__ __launch_bounds__(256) void thrfin_kernel(float* __restrict__ A,
                                                     const float* __restrict__ imp,
                                                     const float* __restrict__ invSumP,
                                                     int bstart) {
  int brel = blockIdx.y;
  int b = bstart + brel;
  int wid = threadIdx.x >> 6;
  int lane = threadIdx.x & 63;
  int i = blockIdx.x * 4 + wid;
  float* row = A + ((size_t)brel * KN + i) * KN;
  __shared__ float im[KN];
  ((float4*)im)[threadIdx.x] = ((const float4*)(imp + (size_t)b * KN))[threadIdx.x];
  __syncthreads();

  float4 v[4];
  unsigned key[16];
#pragma unroll
  for (int q = 0; q < 4; ++q) v[q] = ((const float4*)row)[lane + 64 * q];
#pragma unroll
  for (int q = 0; q < 4; ++q) {
    const float* pv = (const float*)&v[q];
#pragma unroll
    for (int e = 0; e < 4; ++e) {
      unsigned u = __float_as_uint(pv[e]);
      key[q * 4 + e] = (u & 0x80000000u) ? ~u : (u | 0x80000000u);
    }
  }
  unsigned tk = 0u;
#pragma unroll 1
  for (int bit = 31; bit >= 8; --bit) {
    unsigned cand = tk | (1u << bit);
    int c = 0;
#pragma unroll
    for (int e = 0; e < 8; ++e)
      c += (int)__popcll(__ballot(key[e] >= cand));
    int cl = 0;
#pragma unroll
    for (int e = 8; e < 16; ++e) cl += (key[e] >= cand) ? 1 : 0;
#pragma unroll
    for (int off = 32; off > 0; off >>= 1) cl += __shfl_xor(cl, off);
    c += cl;
    if (c >= ADJ_KK) tk = cand;
  }
  float m[16];
  float s = 0.0f;
#pragma unroll
  for (int q = 0; q < 4; ++q) {
    const float* pv = (const float*)&v[q];
#pragma unroll
    for (int e = 0; e < 4; ++e) {
      float mv = (key[q * 4 + e] >= tk) ? pv[e] : 0.0f;
      m[q * 4 + e] = mv;
      s += mv;
    }
  }
#pragma unroll
  for (int off = 32; off > 0; off >>= 1) s += __shfl_xor(s, off);
  float invF = 1.0f / (s + 1.0f + EPSF);
  float vi = im[i];
  float invP = invSumP[(size_t)b * KN + i];
  ushort* rowb = (ushort*)row;
#pragma unroll
  for (int q = 0; q < 4; ++q) {
    float4 iv = ((const float4*)im)[lane + 64 * q];
    const float* ip = (const float*)&iv;
    ushort4 r;
    ushort* rp = (ushort*)&r;
    int colb = 4 * lane + 256 * q;
#pragma unroll
    for (int e = 0; e < 4; ++e) {
      float diag = (colb + e == i) ? 1.0f : 0.0f;
      float d = vi - ip[e];
      rp[e] = f2bf((m[q * 4 + e] + diag) * invF + (__expf(-d * d * 0.125f) + diag) * invP);
    }
    ((ushort4*)rowb)[lane + 64 * q] = r;
  }
}

// ------- bf16 transpose: At[b][j][k] = A[b][k][j] (A row stride 2048) ----
// ushort4-vectorized both sides; [64][68] pad keeps 8B alignment.
__global__ __launch_bounds__(256) void at_kernel(const float* __restrict__ Asim,
                                                 ushort* __restrict__ At) {
  int brel = blockIdx.z;
  int k0 = blockIdx.x * 64;
  int j0 = blockIdx.y * 64;
  __shared__ ushort t[64][68];
  const ushort* Ab = (const ushort*)(Asim + (size_t)brel * KN * KN);
  int g = threadIdx.x & 15;
  int r = threadIdx.x >> 4;
#pragma unroll
  for (int p = 0; p < 4; ++p) {
    int row = p * 16 + r;
    *(ushort4*)&t[row][g * 4] =
        *(const ushort4*)&Ab[(size_t)(k0 + row) * 2048 + j0 + g * 4];
  }
  __syncthreads();
  ushort* ob = At + (size_t)brel * KN * KN;
#pragma unroll
  for (int p = 0; p < 4; ++p) {
    int j = p * 16 + r;
    ushort4 v;
    v.x = t[g * 4 + 0][j];
    v.y = t[g * 4 + 1][j];
    v.z = t[g * 4 + 2][j];
    v.w = t[g * 4 + 3][j];
    *(ushort4*)&ob[(size_t)(j0 + j) * KN + k0 + g * 4] = v;
  }
}

// ---------------- per-node linear: h[b,o,k] = sum_c f[b,c,k] W[c,o] (bf16 out)
// o-tile = 8, software-prefetched c-loop (next x row loaded before FMAs on
// current). b-major flat grid keeps batch b's blocks on one XCD.
template <int C, int M, bool MASK>
__global__ __launch_bounds__(256) void linear_kernel(const float* __restrict__ f,
                                                     const float* __restrict__ W,
                                                     ushort* __restrict__ outp,
                                                     const float* __restrict__ mTK) {
  int fl = blockIdx.x;
  int b = fl & 31;
  int o0 = (fl >> 5) * 8;
  __shared__ float Ws[C][8];
  for (int l = threadIdx.x; l < C * 8; l += 256) {
    int c = l >> 3, o = l & 7;
    Ws[c][o] = W[(size_t)c * M + o0 + o];
  }
  __syncthreads();
  int k0 = threadIdx.x * 4;
  const float* fb = f + (size_t)b * C * KN;
  float acc[8][4] = {};
  float4 xv = *(const float4*)(fb + k0);
#pragma unroll 2
  for (int c = 0; c < C - 1; ++c) {
    float4 xn = *(const float4*)(fb + (size_t)(c + 1) * KN + k0);
#pragma unroll
    for (int o = 0; o < 8; ++o) {
      float w = Ws[c][o];
      acc[o][0] += xv.x * w;
      acc[o][1] += xv.y * w;
      acc[o][2] += xv.z * w;
      acc[o][3] += xv.w * w;
    }
    xv = xn;
  }
#pragma unroll
  for (int o = 0; o < 8; ++o) {
    float w = Ws[C - 1][o];
    acc[o][0] += xv.x * w;
    acc[o][1] += xv.y * w;
    acc[o][2] += xv.z * w;
    acc[o][3] += xv.w * w;
  }
  float ms[4] = {1.0f, 1.0f, 1.0f, 1.0f};
  if (MASK) {
#pragma unroll
    for (int jj = 0; jj < 4; ++jj) ms[jj] = mTK[(size_t)b * KN + k0 + jj] * INV_DS;
  }
#pragma unroll
  for (int o = 0; o < 8; ++o) {
    ushort4 r;
    r.x = f2bf(acc[o][0] * ms[0]);
    r.y = f2bf(acc[o][1] * ms[1]);
    r.z = f2bf(acc[o][2] * ms[2]);
    r.w = f2bf(acc[o][3] * ms[3]);
    *(ushort4*)(outp + ((size_t)b * M + o0 + o) * KN + k0) = r;
  }
}

// ---------------- MFMA s = relu(h @ A) via At, LDS-staged ----------------
template <int M>
__global__ __launch_bounds__(256) void sgemmf_kernel(const ushort* __restrict__ hB,
                                                     const ushort* __restrict__ At,
                                                     float* __restrict__ outp, int bstart) {
  int brel = blockIdx.z;
  int b = bstart + brel;
  int t = threadIdx.x;
  int lane = t & 63;
  int wid = t >> 6;
  int iB = blockIdx.y * 64;
  int jB = blockIdx.x * 128;
  const ushort* hb = hB + (size_t)b * M * KN;
  const ushort* Ab = At + (size_t)brel * KN * KN;

  __shared__ ushort Hs[2][64 * 32];
  __shared__ ushort Bs[2][128 * 32];
  __shared__ float ep[4][16][65];

  int srow = t >> 2;
  int scol = (t & 3) * 8;
  int ldst = t * 8;

  auto stage = [&](int buf, int k0) {
    gll16(hb + (size_t)(iB + srow) * KN + k0 + scol, &Hs[buf][ldst]);
    gll16(Ab + (size_t)(jB + srow) * KN + k0 + scol, &Bs[buf][ldst]);
    gll16(Ab + (size_t)(jB + 64 + srow) * KN + k0 + scol, &Bs[buf][2048 + ldst]);
  };

  int i0loc = (wid >> 1) * 32;
  int j0loc = (wid & 1) * 64;
  int r = lane & 15;
  int s = (lane >> 4) * 8;

  f32x4 acc[2][4] = {};
  stage(0, 0);
  __syncthreads();
  int cur = 0;
#pragma unroll 2
  for (int ks = 0; ks < KN / 32; ++ks) {
    if (ks + 1 < KN / 32) stage(cur ^ 1, (ks + 1) * 32);
    bf16x8 a[2], bb[4];
#pragma unroll
    for (int m = 0; m < 2; ++m)
      a[m] = *reinterpret_cast<const bf16x8*>(&Hs[cur][(i0loc + m * 16 + r) * 32 + s]);
#pragma unroll
    for (int n = 0; n < 4; ++n)
      bb[n] = *reinterpret_cast<const bf16x8*>(&Bs[cur][(j0loc + n * 16 + r) * 32 + s]);
#pragma unroll
    for (int m = 0; m < 2; ++m)
#pragma unroll
      for (int n = 0; n < 4; ++n)
        acc[m][n] = __builtin_amdgcn_mfma_f32_16x16x32_bf16(a[m], bb[n], acc[m][n], 0, 0, 0);
    __syncthreads();
    cur ^= 1;
  }

  float(*buf)[65] = ep[wid];
  int orow = (lane >> 4) * 4;
  int ocol = lane & 15;
  int i0 = iB + i0loc;
  int j0 = jB + j0loc;
  float* ob = outp + (size_t)b * M * KN;
#pragma unroll
  for (int m = 0; m < 2; ++m) {
#pragma unroll
    for (int n = 0; n < 4; ++n)
#pragma unroll
      for (int rr = 0; rr < 4; ++rr) buf[orow + rr][n * 16 + ocol] = fmaxf(acc[m][n][rr], 0.0f);
#pragma unroll
    for (int rr = 0; rr < 4; ++rr) {
      int row = rr * 4 + (lane >> 4);
      float4 v4 = *(const float4*)&buf[row][(lane & 15) * 4];
      *(float4*)(ob + (size_t)(i0 + m * 16 + row) * KN + j0 + (lane & 15) * 4) = v4;
    }
  }
}

// ---------------- reductions ---------------------------------------------
__global__ void bag12_kernel(const float* __restrict__ emb1, const float* __restrict__ mTK,
                             const float* __restrict__ mTD, const float* __restrict__ imp,
                             float* __restrict__ bagk, float* __restrict__ bagd) {
  int c = blockIdx.x, b = blockIdx.y;
  int t = threadIdx.x;
  const float* e = emb1 + ((size_t)b * CMID + c) * KN;
  const float* ir = imp + (size_t)b * KN;
  const float* m1 = mTK + (size_t)b * KN;
  const float* m2 = mTD + (size_t)b * KN;
  float s1 = 0.0f, sd = 0.0f;
  for (int k = t; k < KN; k += 256) {
    float ev = e[k] * ir[k];
    s1 += ev * m1[k];
    sd += ev * m2[k];
  }
  __shared__ float r1[256], r2[256];
  r1[t] = s1;
  r2[t] = sd;
  __syncthreads();
  for (int st = 128; st > 0; st >>= 1) {
    if (t < st) {
      r1[t] += r1[t + st];
      r2[t] += r2[t + st];
    }
    __syncthreads();
  }
  if (t == 0) {
    bagk[(size_t)b * CMID + c] = r1[0] * INV_DS;
    bagd[(size_t)b * CMID + c] = r2[0] * INV_DS;
  }
}

__global__ void bag2_kernel(const float* __restrict__ s2, const float* __restrict__ mTK,
                            const float* __restrict__ imp, float* __restrict__ bag) {
  int o = blockIdx.x, b = blockIdx.y;
  int t = threadIdx.x;
  const float* sr = s2 + ((size_t)b * COUT + o) * KN;
  const float* ir = imp + (size_t)b * KN;
  const float* mr = mTK + (size_t)b * KN;
  float s = 0.0f;
  for (int k = t; k < KN; k += 256) s += sr[k] * mr[k] * ir[k];
  __shared__ float red[256];
  red[t] = s;
  __syncthreads();
  for (int st = 128; st > 0; st >>= 1) {
    if (t < st) red[t] += red[t + st];
    __syncthreads();
  }
  if (t == 0) bag[(size_t)b * COUT + o] = red[0];
}

__global__ void pooled_kernel(const float* __restrict__ x, const float* __restrict__ imp,
                              float* __restrict__ pooled) {
  int c = blockIdx.x, b = blockIdx.y;
  int t = threadIdx.x;
  const float* xr = x + ((size_t)b * CIN + c) * KN;
  const float* ir = imp + (size_t)b * KN;
  float s = 0.0f;
  for (int k = t; k < KN; k += 256) s += xr[k] * ir[k];
  __shared__ float red[256];
  red[t] = s;
  __syncthreads();
  for (int st = 128; st > 0; st >>= 1) {
    if (t < st) red[t] += red[t + st];
    __syncthreads();
  }
  if (t == 0) pooled[(size_t)b * CIN + c] = red[0];
}

__global__ void final_kernel(const float* __restrict__ pooled, const float* __restrict__ bag,
                             const float* __restrict__ id_w, const float* __restrict__ id_b,
                             const float* __restrict__ fc_w, float* __restrict__ out) {
  int b = blockIdx.x;
  int o = threadIdx.x;
  __shared__ float v[COUT];
  float s = id_b[o];
  const float* pr = pooled + (size_t)b * CIN;
  for (int c = 0; c < CIN; ++c) s += pr[c] * id_w[(size_t)c * COUT + o];
  v[o] = bag[(size_t)b * COUT + o] + fmaxf(s, 0.0f);
  __syncthreads();
  if (o < NCLS) {
    float acc = 0.0f;
    for (int oo = 0; oo < COUT; ++oo) acc += v[oo] * fc_w[(size_t)oo * NCLS + o];
    out[(size_t)b * NCLS + o] = acc;
  }
}

// ---------------- launch --------------------------------------------------
extern "C" void kernel_launch(void* const* d_in, const int* in_sizes, int n_in,
                              void* d_out, int out_size, void* d_ws, size_t ws_size,
                              hipStream_t stream) {
  const float* x = (const float*)d_in[0];
  const float* imp = (const float*)d_in[1];
  const float* rnd = (const float*)d_in[2];
  const float* W1 = (const float*)d_in[3];
  const float* W2 = (const float*)d_in[4];
  const float* fc_w = (const float*)d_in[5];
  const float* id_w = (const float*)d_in[6];
  const float* id_b = (const float*)d_in[7];
  float* out = (float*)d_out;
  float* emb1 = out + BN_ * NCLS;
  float* bagk = emb1 + (size_t)BN_ * CMID * KN;
  float* bagd = bagk + (size_t)BN_ * CMID;

  float* w = (float*)d_ws;
  size_t off = 0;
  auto take = [&](size_t n) {
    float* p = w + off;
    off += n;
    return p;
  };
  float* invSumP = take((size_t)BN_ * KN);
  float* invNX = take((size_t)BN_ * KN);
  float* invNE = take((size_t)BN_ * KN);
  float* topM = take((size_t)BN_ * KN);
  float* mTK = take((size_t)BN_ * KN);
  float* mTD = take((size_t)BN_ * KN);
  ushort* h = (ushort*)take((size_t)BN_ * CMID * KN / 2);
  ushort* h2 = (ushort*)take((size_t)BN_ * COUT * KN / 2);
  float* s2 = take((size_t)BN_ * COUT * KN);
  float* bag = take((size_t)BN_ * COUT);
  float* pooled = take((size_t)BN_ * CIN);
  ushort* xnT = (ushort*)take((size_t)BN_ * CIN * KN / 2);
  ushort* enT = (ushort*)take((size_t)BN_ * CMID * KN / 2);
  long long avail = (long long)(ws_size / 4) - (long long)off;
  int nb = 1;
  const int cands[6] = {32, 16, 8, 4, 2, 1};
  for (int ci = 0; ci < 6; ++ci) {
    if ((long long)cands[ci] * KN * KN * 3 / 2 <= avail) {
      nb = cands[ci];
      break;
    }
  }
  float* simA = take((size_t)nb * KN * KN);
  ushort* At = (ushort*)take((size_t)nb * KN * KN / 2);

  masks1_kernel<<<dim3(KN / 256, BN_), 256, 0, stream>>>(imp, topM);
  masks2_kernel<<<dim3(KN / 256, BN_), 256, 0, stream>>>(rnd, topM, mTK, mTD);
  psum_kernel<<<dim3(KN / 256, BN_), 256, 0, stream>>>(imp, invSumP);
  colnorm_kernel<CIN><<<(BN_ * KN) / 256, 256, 0, stream>>>(x, invNX);
  xpose_kernel<CIN><<<dim3(KN / 64, CIN / 64, BN_), 256, 0, stream>>>(x, invNX,
                                                                      (__hip_bfloat16*)xnT);
  linear_kernel<CIN, CMID, false><<<(CMID / 8) * BN_, 256, 0, stream>>>(x, W1, h, nullptr);

  for (int bs = 0; bs < BN_; bs += nb) {
    simf_kernel<CIN><<<nb * 64, 256, 0, stream>>>(xnT, simA, bs, nb);
    thrfin_kernel<<<dim3(KN / 4, nb), 256, 0, stream>>>(simA, imp, invSumP, bs);
    at_kernel<<<dim3(KN / 64, KN / 64, nb), 256, 0, stream>>>(simA, At);
    sgemmf_kernel<CMID><<<dim3(KN / 128, CMID / 64, nb), 256, 0, stream>>>(h, At, emb1, bs);
  }

  colnorm_kernel<CMID><<<(BN_ * KN) / 256, 256, 0, stream>>>(emb1, invNE);
  xpose_kernel<CMID><<<dim3(KN / 64, CMID / 64, BN_), 256, 0, stream>>>(emb1, invNE,
                                                                        (__hip_bfloat16*)enT);
  linear_kernel<CMID, COUT, true><<<(COUT / 8) * BN_, 256, 0, stream>>>(emb1, W2, h2, mTK);

  for (int bs = 0; bs < BN_; bs += nb) {
    simf_kernel<CMID><<<nb * 64, 256, 0, stream>>>(enT, simA, bs, nb);
    thrfin_kernel<<<dim3(KN / 4, nb), 256, 0, stream>>>(simA, imp, invSumP, bs);
    at_kernel<<<dim3(KN / 64, KN / 64, nb), 256, 0, stream>>>(simA, At);
    sgemmf_kernel<COUT><<<dim3(KN / 128, COUT / 64, nb), 256, 0, stream>>>(h2, At, s2, bs);
  }

  bag12_kernel<<<dim3(CMID, BN_), 256, 0, stream>>>(emb1, mTK, mTD, imp, bagk, bagd);
  bag2_kernel<<<dim3(COUT, BN_), 256, 0, stream>>>(s2, mTK, imp, bag);
  pooled_kernel<<<dim3(CIN, BN_), 256, 0, stream>>>(x, imp, pooled);
  final_kernel<<<BN_, 64, 0, stream>>>(pooled, bag, id_w, id_b, fc_w, out);
}

// Round 16
// 624.752 us; speedup vs baseline: 1.0618x; 1.0618x over previous
//
#include <hip/hip_runtime.h>
#include <hip/hip_bf16.h>
#include <math.h>

#define BN_ 32
#define CIN 512
#define KN 1024
#define CMID 128
#define COUT 64
#define NCLS 5
#define NUM_TOP 205
#define NUM_KEPT 409
#define NUM_DROP 410
#define ADJ_KK 204
#define EPSF 1e-8f
#define INV_DS (1.0f / 0.599609375f)

typedef __bf16 bf16x8 __attribute__((ext_vector_type(8)));
typedef float f32x4 __attribute__((ext_vector_type(4)));

__device__ inline ushort f2bf(float x) {
  union { __hip_bfloat16 b; ushort u; } c;
  c.b = __float2bfloat16(x);
  return c.u;
}

// async global->LDS, 16B per lane (dest = wave-uniform base + lane*16)
__device__ inline void gll16(const ushort* g, ushort* l) {
  __builtin_amdgcn_global_load_lds(
      (const __attribute__((address_space(1))) unsigned int*)g,
      (__attribute__((address_space(3))) unsigned int*)l, 16, 0, 0);
}

// ---------------- masks stage 1: top mask via rank counting --------------
__global__ __launch_bounds__(256) void masks1_kernel(const float* __restrict__ imp,
                                                     float* __restrict__ topM) {
  int b = blockIdx.y;
  int i = blockIdx.x * 256 + threadIdx.x;
  __shared__ float im[KN];
  for (int j = threadIdx.x; j < KN; j += 256) im[j] = imp[(size_t)b * KN + j];
  __syncthreads();
  float vi = im[i];
  int r0 = 0, r1 = 0, r2 = 0, r3 = 0;
  for (int j = 0; j < KN; j += 4) {
    float a0 = im[j], a1 = im[j + 1], a2 = im[j + 2], a3 = im[j + 3];
    r0 += (a0 > vi || (a0 == vi && j < i)) ? 1 : 0;
    r1 += (a1 > vi || (a1 == vi && j + 1 < i)) ? 1 : 0;
    r2 += (a2 > vi || (a2 == vi && j + 2 < i)) ? 1 : 0;
    r3 += (a3 > vi || (a3 == vi && j + 3 < i)) ? 1 : 0;
  }
  int rank = r0 + r1 + r2 + r3;
  topM[(size_t)b * KN + i] = (rank < NUM_TOP) ? 1.0f : 0.0f;
}

// ---------------- masks stage 2: kept/drop ranks, fused ------------------
__global__ __launch_bounds__(256) void masks2_kernel(const float* __restrict__ rnd,
                                                     const float* __restrict__ topM,
                                                     float* __restrict__ mTK,
                                                     float* __restrict__ mTD) {
  int b = blockIdx.y;
  int i = blockIdx.x * 256 + threadIdx.x;
  __shared__ float r1s[KN];
  __shared__ float r2s[KN];
  for (int j = threadIdx.x; j < KN; j += 256) {
    float tv = topM[(size_t)b * KN + j];
    float rv = rnd[(size_t)b * KN + j];
    r1s[j] = (tv > 0.5f) ? -10.0f : rv;
    r2s[j] = (tv > 0.5f) ? 10.0f : rv;
  }
  __syncthreads();
  float v1 = r1s[i];
  float v2 = r2s[i];
  int c1a = 0, c1b = 0, c2a = 0, c2b = 0;
  for (int j = 0; j < KN; j += 2) {
    float a0 = r1s[j], a1 = r1s[j + 1];
    float b0 = r2s[j], b1 = r2s[j + 1];
    c1a += (a0 > v1 || (a0 == v1 && j < i)) ? 1 : 0;
    c1b += (a1 > v1 || (a1 == v1 && j + 1 < i)) ? 1 : 0;
    c2a += (b0 < v2 || (b0 == v2 && j < i)) ? 1 : 0;
    c2b += (b1 < v2 || (b1 == v2 && j + 1 < i)) ? 1 : 0;
  }
  int kept = (c1a + c1b) < NUM_KEPT;
  int drop = (c2a + c2b) < NUM_DROP;
  int top = topM[(size_t)b * KN + i] > 0.5f;
  mTK[(size_t)b * KN + i] = (top || kept) ? 1.0f : 0.0f;
  mTD[(size_t)b * KN + i] = (top || drop) ? 1.0f : 0.0f;
}

// ---------------- adjP row-sum reciprocals -------------------------------
__global__ void psum_kernel(const float* __restrict__ imp, float* __restrict__ invSumP) {
  int b = blockIdx.y;
  int i = blockIdx.x * 256 + threadIdx.x;
  __shared__ float im[KN];
  for (int j = threadIdx.x; j < KN; j += 256) im[j] = imp[(size_t)b * KN + j];
  __syncthreads();
  float vi = im[i];
  float s = 0.0f;
  for (int j = 0; j < KN; ++j) {
    float d = vi - im[j];
    s += __expf(-d * d * 0.125f);
  }
  invSumP[(size_t)b * KN + i] = 1.0f / (s + 1.0f + EPSF);
}

// ---------------- per-column L2 norm reciprocals -------------------------
template <int C>
__global__ void colnorm_kernel(const float* __restrict__ f, float* __restrict__ inv) {
  int idx = blockIdx.x * 256 + threadIdx.x;
  int b = idx >> 10;
  int k = idx & (KN - 1);
  const float* fb = f + (size_t)b * C * KN + k;
  float ss = 0.0f;
  for (int c = 0; c < C; ++c) {
    float v = fb[(size_t)c * KN];
    ss += v * v;
  }
  inv[idx] = 1.0f / (sqrtf(ss) + EPSF);
}

// ------- transpose + normalize + bf16: oT[b][k][c] = f[b][c][k]*inv[b][k] --
template <int C>
__global__ void xpose_kernel(const float* __restrict__ f, const float* __restrict__ inv,
                             __hip_bfloat16* __restrict__ oT) {
  int b = blockIdx.z;
  int k0 = blockIdx.x * 64;
  int c0 = blockIdx.y * 64;
  __shared__ float t[64][65];
  const float* fb = f + (size_t)b * C * KN;
  int tx = threadIdx.x & 63;
  int ty = threadIdx.x >> 6;
  for (int r = 0; r < 64; r += 4) t[r + ty][tx] = fb[(size_t)(c0 + r + ty) * KN + k0 + tx];
  __syncthreads();
  __hip_bfloat16* ob = oT + (size_t)b * KN * C;
  for (int r = 0; r < 64; r += 4) {
    int k = r + ty;
    float s = inv[(size_t)b * KN + k0 + k];
    ob[(size_t)(k0 + k) * C + c0 + tx] = __float2bfloat16(t[tx][k] * s);
  }
}

// ---------------- MFMA sim: sim = XnT * XnT^T (Gram, symmetric) ----------
template <int C>
__global__ __launch_bounds__(256) void simf_kernel(const ushort* __restrict__ xT,
                                                   float* __restrict__ sim, int bstart, int nb) {
  int f = blockIdx.x;
  int brel, tile;
  if ((nb & 7) == 0) {
    int xcd = f & 7;
    int wdx = f >> 3;
    brel = xcd * (nb >> 3) + (wdx >> 6);
    tile = wdx & 63;
  } else {
    brel = f >> 6;
    tile = f & 63;
  }
  int b = bstart + brel;
  int t = threadIdx.x;
  int lane = t & 63;
  int wid = t >> 6;
  int iB = (tile >> 3) * 128;
  int jB = (tile & 7) * 128;
  const ushort* X = xT + (size_t)b * KN * C;

  __shared__ ushort As[2][128 * 32];
  __shared__ ushort Bs[2][128 * 32];
  __shared__ float ep[4][16][65];

  int srow = t >> 2;
  int scol = (t & 3) * 8;
  int ldst = t * 8;

  auto stage = [&](int buf, int c0) {
    gll16(X + (size_t)(iB + srow) * C + c0 + scol, &As[buf][ldst]);
    gll16(X + (size_t)(iB + 64 + srow) * C + c0 + scol, &As[buf][2048 + ldst]);
    gll16(X + (size_t)(jB + srow) * C + c0 + scol, &Bs[buf][ldst]);
    gll16(X + (size_t)(jB + 64 + srow) * C + c0 + scol, &Bs[buf][2048 + ldst]);
  };

  int i0loc = (wid >> 1) * 64;
  int j0loc = (wid & 1) * 64;
  int r = lane & 15;
  int s = (lane >> 4) * 8;

  f32x4 acc[4][4] = {};
  stage(0, 0);
  __syncthreads();
  constexpr int NT = C / 32;
  int cur = 0;
#pragma unroll 2
  for (int ks = 0; ks < NT; ++ks) {
    if (ks + 1 < NT) stage(cur ^ 1, (ks + 1) * 32);
    bf16x8 a[4], bb[4];
#pragma unroll
    for (int m = 0; m < 4; ++m)
      a[m] = *reinterpret_cast<const bf16x8*>(&As[cur][(i0loc + m * 16 + r) * 32 + s]);
#pragma unroll
    for (int n = 0; n < 4; ++n)
      bb[n] = *reinterpret_cast<const bf16x8*>(&Bs[cur][(j0loc + n * 16 + r) * 32 + s]);
#pragma unroll
    for (int m = 0; m < 4; ++m)
#pragma unroll
      for (int n = 0; n < 4; ++n)
        acc[m][n] = __builtin_amdgcn_mfma_f32_16x16x32_bf16(a[m], bb[n], acc[m][n], 0, 0, 0);
    __syncthreads();
    cur ^= 1;
  }

  float(*buf)[65] = ep[wid];
  int orow = (lane >> 4) * 4;
  int ocol = lane & 15;
  int i0 = iB + i0loc;
  int j0 = jB + j0loc;
  float* simb = sim + (size_t)brel * KN * KN;
#pragma unroll
  for (int m = 0; m < 4; ++m) {
#pragma unroll
    for (int n = 0; n < 4; ++n)
#pragma unroll
      for (int rr = 0; rr < 4; ++rr) buf[orow + rr][n * 16 + ocol] = acc[m][n][rr];
#pragma unroll
    for (int rr = 0; rr < 4; ++rr) {
      int row = rr * 4 + (lane >> 4);
      float4 v4 = *(const float4*)&buf[row][(lane & 15) * 4];
      *(float4*)(simb + (size_t)(i0 + m * 16 + row) * KN + j0 + (lane & 15) * 4) = v4;
    }
  }
}

// ------- fused per-wave threshold select + finalize ----------------------
// Bisection over bits 31..8 (24-bit threshold granularity). Count split
// across pipes: 8 keys ballot+s_bcnt (SALU), 8 keys per-lane + shfl (VALU/DS).
__global__ __launch_bounds__(256) void thrfin_kernel(float* __restrict__ A,
                                                     const float* __restrict__ imp,
                                                     const float* __restrict__ invSumP,
                                                     int bstart) {
  int brel = blockIdx.y;
  int b = bstart + brel;
  int wid = threadIdx.x >> 6;
  int lane = threadIdx.x & 63;
  int i = blockIdx.x * 4 + wid;
  float* row = A + ((size_t)brel * KN + i) * KN;
  __shared__ float im[KN];
  ((float4*)im)[threadIdx.x] = ((const float4*)(imp + (size_t)b * KN))[threadIdx.x];
  __syncthreads();

  float4 v[4];
  unsigned key[16];
#pragma unroll
  for (int q = 0; q < 4; ++q) v[q] = ((const float4*)row)[lane + 64 * q];
#pragma unroll
  for (int q = 0; q < 4; ++q) {
    const float* pv = (const float*)&v[q];
#pragma unroll
    for (int e = 0; e < 4; ++e) {
      unsigned u = __float_as_uint(pv[e]);
      key[q * 4 + e] = (u & 0x80000000u) ? ~u : (u | 0x80000000u);
    }
  }
  unsigned tk = 0u;
#pragma unroll 1
  for (int bit = 31; bit >= 8; --bit) {
    unsigned cand = tk | (1u << bit);
    int c = 0;
#pragma unroll
    for (int e = 0; e < 8; ++e)
      c += (int)__popcll(__ballot(key[e] >= cand));
    int cl = 0;
#pragma unroll
    for (int e = 8; e < 16; ++e) cl += (key[e] >= cand) ? 1 : 0;
#pragma unroll
    for (int off = 32; off > 0; off >>= 1) cl += __shfl_xor(cl, off);
    c += cl;
    if (c >= ADJ_KK) tk = cand;
  }
  float m[16];
  float s = 0.0f;
#pragma unroll
  for (int q = 0; q < 4; ++q) {
    const float* pv = (const float*)&v[q];
#pragma unroll
    for (int e = 0; e < 4; ++e) {
      float mv = (key[q * 4 + e] >= tk) ? pv[e] : 0.0f;
      m[q * 4 + e] = mv;
      s += mv;
    }
  }
#pragma unroll
  for (int off = 32; off > 0; off >>= 1) s += __shfl_xor(s, off);
  float invF = 1.0f / (s + 1.0f + EPSF);
  float vi = im[i];
  float invP = invSumP[(size_t)b * KN + i];
  ushort* rowb = (ushort*)row;
#pragma unroll
  for (int q = 0; q < 4; ++q) {
    float4 iv = ((const float4*)im)[lane + 64 * q];
    const float* ip = (const float*)&iv;
    ushort4 r;
    ushort* rp = (ushort*)&r;
    int colb = 4 * lane + 256 * q;
#pragma unroll
    for (int e = 0; e < 4; ++e) {
      float diag = (colb + e == i) ? 1.0f : 0.0f;
      float d = vi - ip[e];
      rp[e] = f2bf((m[q * 4 + e] + diag) * invF + (__expf(-d * d * 0.125f) + diag) * invP);
    }
    ((ushort4*)rowb)[lane + 64 * q] = r;
  }
}

// ------- bf16 transpose: At[b][j][k] = A[b][k][j] (A row stride 2048) ----
// ushort4-vectorized both sides; [64][68] pad keeps 8B alignment.
__global__ __launch_bounds__(256) void at_kernel(const float* __restrict__ Asim,
                                                 ushort* __restrict__ At) {
  int brel = blockIdx.z;
  int k0 = blockIdx.x * 64;
  int j0 = blockIdx.y * 64;
  __shared__ ushort t[64][68];
  const ushort* Ab = (const ushort*)(Asim + (size_t)brel * KN * KN);
  int g = threadIdx.x & 15;
  int r = threadIdx.x >> 4;
#pragma unroll
  for (int p = 0; p < 4; ++p) {
    int row = p * 16 + r;
    *(ushort4*)&t[row][g * 4] =
        *(const ushort4*)&Ab[(size_t)(k0 + row) * 2048 + j0 + g * 4];
  }
  __syncthreads();
  ushort* ob = At + (size_t)brel * KN * KN;
#pragma unroll
  for (int p = 0; p < 4; ++p) {
    int j = p * 16 + r;
    ushort4 v;
    v.x = t[g * 4 + 0][j];
    v.y = t[g * 4 + 1][j];
    v.z = t[g * 4 + 2][j];
    v.w = t[g * 4 + 3][j];
    *(ushort4*)&ob[(size_t)(j0 + j) * KN + k0 + g * 4] = v;
  }
}

// ---------------- per-node linear: h[b,o,k] = sum_c f[b,c,k] W[c,o] (bf16 out)
// o-tile = 8: 16KB LDS Ws tile, grid (M/8)*32 (2 blk/CU), b-major flat grid
// (stride 32 = 0 mod 8) keeps batch b's blocks on one XCD sharing x[b] in L2.
template <int C, int M, bool MASK>
__global__ __launch_bounds__(256) void linear_kernel(const float* __restrict__ f,
                                                     const float* __restrict__ W,
                                                     ushort* __restrict__ outp,
                                                     const float* __restrict__ mTK) {
  int fl = blockIdx.x;
  int b = fl & 31;
  int o0 = (fl >> 5) * 8;
  __shared__ float Ws[C][8];
  for (int l = threadIdx.x; l < C * 8; l += 256) {
    int c = l >> 3, o = l & 7;
    Ws[c][o] = W[(size_t)c * M + o0 + o];
  }
  __syncthreads();
  int k0 = threadIdx.x * 4;
  const float* fb = f + (size_t)b * C * KN;
  float acc[8][4] = {};
  for (int c = 0; c < C; ++c) {
    float4 xv = *(const float4*)(fb + (size_t)c * KN + k0);
#pragma unroll
    for (int o = 0; o < 8; ++o) {
      float w = Ws[c][o];
      acc[o][0] += xv.x * w;
      acc[o][1] += xv.y * w;
      acc[o][2] += xv.z * w;
      acc[o][3] += xv.w * w;
    }
  }
  float ms[4] = {1.0f, 1.0f, 1.0f, 1.0f};
  if (MASK) {
#pragma unroll
    for (int jj = 0; jj < 4; ++jj) ms[jj] = mTK[(size_t)b * KN + k0 + jj] * INV_DS;
  }
#pragma unroll
  for (int o = 0; o < 8; ++o) {
    ushort4 r;
    r.x = f2bf(acc[o][0] * ms[0]);
    r.y = f2bf(acc[o][1] * ms[1]);
    r.z = f2bf(acc[o][2] * ms[2]);
    r.w = f2bf(acc[o][3] * ms[3]);
    *(ushort4*)(outp + ((size_t)b * M + o0 + o) * KN + k0) = r;
  }
}

// ---------------- MFMA s = relu(h @ A) via At, LDS-staged ----------------
template <int M>
__global__ __launch_bounds__(256) void sgemmf_kernel(const ushort* __restrict__ hB,
                                                     const ushort* __restrict__ At,
                                                     float* __restrict__ outp, int bstart) {
  int brel = blockIdx.z;
  int b = bstart + brel;
  int t = threadIdx.x;
  int lane = t & 63;
  int wid = t >> 6;
  int iB = blockIdx.y * 64;
  int jB = blockIdx.x * 128;
  const ushort* hb = hB + (size_t)b * M * KN;
  const ushort* Ab = At + (size_t)brel * KN * KN;

  __shared__ ushort Hs[2][64 * 32];
  __shared__ ushort Bs[2][128 * 32];
  __shared__ float ep[4][16][65];

  int srow = t >> 2;
  int scol = (t & 3) * 8;
  int ldst = t * 8;

  auto stage = [&](int buf, int k0) {
    gll16(hb + (size_t)(iB + srow) * KN + k0 + scol, &Hs[buf][ldst]);
    gll16(Ab + (size_t)(jB + srow) * KN + k0 + scol, &Bs[buf][ldst]);
    gll16(Ab + (size_t)(jB + 64 + srow) * KN + k0 + scol, &Bs[buf][2048 + ldst]);
  };

  int i0loc = (wid >> 1) * 32;
  int j0loc = (wid & 1) * 64;
  int r = lane & 15;
  int s = (lane >> 4) * 8;

  f32x4 acc[2][4] = {};
  stage(0, 0);
  __syncthreads();
  int cur = 0;
#pragma unroll 2
  for (int ks = 0; ks < KN / 32; ++ks) {
    if (ks + 1 < KN / 32) stage(cur ^ 1, (ks + 1) * 32);
    bf16x8 a[2], bb[4];
#pragma unroll
    for (int m = 0; m < 2; ++m)
      a[m] = *reinterpret_cast<const bf16x8*>(&Hs[cur][(i0loc + m * 16 + r) * 32 + s]);
#pragma unroll
    for (int n = 0; n < 4; ++n)
      bb[n] = *reinterpret_cast<const bf16x8*>(&Bs[cur][(j0loc + n * 16 + r) * 32 + s]);
#pragma unroll
    for (int m = 0; m < 2; ++m)
#pragma unroll
      for (int n = 0; n < 4; ++n)
        acc[m][n] = __builtin_amdgcn_mfma_f32_16x16x32_bf16(a[m], bb[n], acc[m][n], 0, 0, 0);
    __syncthreads();
    cur ^= 1;
  }

  float(*buf)[65] = ep[wid];
  int orow = (lane >> 4) * 4;
  int ocol = lane & 15;
  int i0 = iB + i0loc;
  int j0 = jB + j0loc;
  float* ob = outp + (size_t)b * M * KN;
#pragma unroll
  for (int m = 0; m < 2; ++m) {
#pragma unroll
    for (int n = 0; n < 4; ++n)
#pragma unroll
      for (int rr = 0; rr < 4; ++rr) buf[orow + rr][n * 16 + ocol] = fmaxf(acc[m][n][rr], 0.0f);
#pragma unroll
    for (int rr = 0; rr < 4; ++rr) {
      int row = rr * 4 + (lane >> 4);
      float4 v4 = *(const float4*)&buf[row][(lane & 15) * 4];
      *(float4*)(ob + (size_t)(i0 + m * 16 + row) * KN + j0 + (lane & 15) * 4) = v4;
    }
  }
}

// ---------------- reductions ---------------------------------------------
__global__ void bag12_kernel(const float* __restrict__ emb1, const float* __restrict__ mTK,
                             const float* __restrict__ mTD, const float* __restrict__ imp,
                             float* __restrict__ bagk, float* __restrict__ bagd) {
  int c = blockIdx.x, b = blockIdx.y;
  int t = threadIdx.x;
  const float* e = emb1 + ((size_t)b * CMID + c) * KN;
  const float* ir = imp + (size_t)b * KN;
  const float* m1 = mTK + (size_t)b * KN;
  const float* m2 = mTD + (size_t)b * KN;
  float s1 = 0.0f, sd = 0.0f;
  for (int k = t; k < KN; k += 256) {
    float ev = e[k] * ir[k];
    s1 += ev * m1[k];
    sd += ev * m2[k];
  }
  __shared__ float r1[256], r2[256];
  r1[t] = s1;
  r2[t] = sd;
  __syncthreads();
  for (int st = 128; st > 0; st >>= 1) {
    if (t < st) {
      r1[t] += r1[t + st];
      r2[t] += r2[t + st];
    }
    __syncthreads();
  }
  if (t == 0) {
    bagk[(size_t)b * CMID + c] = r1[0] * INV_DS;
    bagd[(size_t)b * CMID + c] = r2[0] * INV_DS;
  }
}

__global__ void bag2_kernel(const float* __restrict__ s2, const float* __restrict__ mTK,
                            const float* __restrict__ imp, float* __restrict__ bag) {
  int o = blockIdx.x, b = blockIdx.y;
  int t = threadIdx.x;
  const float* sr = s2 + ((size_t)b * COUT + o) * KN;
  const float* ir = imp + (size_t)b * KN;
  const float* mr = mTK + (size_t)b * KN;
  float s = 0.0f;
  for (int k = t; k < KN; k += 256) s += sr[k] * mr[k] * ir[k];
  __shared__ float red[256];
  red[t] = s;
  __syncthreads();
  for (int st = 128; st > 0; st >>= 1) {
    if (t < st) red[t] += red[t + st];
    __syncthreads();
  }
  if (t == 0) bag[(size_t)b * COUT + o] = red[0];
}

__global__ void pooled_kernel(const float* __restrict__ x, const float* __restrict__ imp,
                              float* __restrict__ pooled) {
  int c = blockIdx.x, b = blockIdx.y;
  int t = threadIdx.x;
  const float* xr = x + ((size_t)b * CIN + c) * KN;
  const float* ir = imp + (size_t)b * KN;
  float s = 0.0f;
  for (int k = t; k < KN; k += 256) s += xr[k] * ir[k];
  __shared__ float red[256];
  red[t] = s;
  __syncthreads();
  for (int st = 128; st > 0; st >>= 1) {
    if (t < st) red[t] += red[t + st];
    __syncthreads();
  }
  if (t == 0) pooled[(size_t)b * CIN + c] = red[0];
}

__global__ void final_kernel(const float* __restrict__ pooled, const float* __restrict__ bag,
                             const float* __restrict__ id_w, const float* __restrict__ id_b,
                             const float* __restrict__ fc_w, float* __restrict__ out) {
  int b = blockIdx.x;
  int o = threadIdx.x;
  __shared__ float v[COUT];
  float s = id_b[o];
  const float* pr = pooled + (size_t)b * CIN;
  for (int c = 0; c < CIN; ++c) s += pr[c] * id_w[(size_t)c * COUT + o];
  v[o] = bag[(size_t)b * COUT + o] + fmaxf(s, 0.0f);
  __syncthreads();
  if (o < NCLS) {
    float acc = 0.0f;
    for (int oo = 0; oo < COUT; ++oo) acc += v[oo] * fc_w[(size_t)oo * NCLS + o];
    out[(size_t)b * NCLS + o] = acc;
  }
}

// ---------------- launch --------------------------------------------------
extern "C" void kernel_launch(void* const* d_in, const int* in_sizes, int n_in,
                              void* d_out, int out_size, void* d_ws, size_t ws_size,
                              hipStream_t stream) {
  const float* x = (const float*)d_in[0];
  const float* imp = (const float*)d_in[1];
  const float* rnd = (const float*)d_in[2];
  const float* W1 = (const float*)d_in[3];
  const float* W2 = (const float*)d_in[4];
  const float* fc_w = (const float*)d_in[5];
  const float* id_w = (const float*)d_in[6];
  const float* id_b = (const float*)d_in[7];
  float* out = (float*)d_out;
  float* emb1 = out + BN_ * NCLS;
  float* bagk = emb1 + (size_t)BN_ * CMID * KN;
  float* bagd = bagk + (size_t)BN_ * CMID;

  float* w = (float*)d_ws;
  size_t off = 0;
  auto take = [&](size_t n) {
    float* p = w + off;
    off += n;
    return p;
  };
  float* invSumP = take((size_t)BN_ * KN);
  float* invNX = take((size_t)BN_ * KN);
  float* invNE = take((size_t)BN_ * KN);
  float* topM = take((size_t)BN_ * KN);
  float* mTK = take((size_t)BN_ * KN);
  float* mTD = take((size_t)BN_ * KN);
  ushort* h = (ushort*)take((size_t)BN_ * CMID * KN / 2);
  ushort* h2 = (ushort*)take((size_t)BN_ * COUT * KN / 2);
  float* s2 = take((size_t)BN_ * COUT * KN);
  float* bag = take((size_t)BN_ * COUT);
  float* pooled = take((size_t)BN_ * CIN);
  ushort* xnT = (ushort*)take((size_t)BN_ * CIN * KN / 2);
  ushort* enT = (ushort*)take((size_t)BN_ * CMID * KN / 2);
  long long avail = (long long)(ws_size / 4) - (long long)off;
  int nb = 1;
  const int cands[6] = {32, 16, 8, 4, 2, 1};
  for (int ci = 0; ci < 6; ++ci) {
    if ((long long)cands[ci] * KN * KN * 3 / 2 <= avail) {
      nb = cands[ci];
      break;
    }
  }
  float* simA = take((size_t)nb * KN * KN);
  ushort* At = (ushort*)take((size_t)nb * KN * KN / 2);

  masks1_kernel<<<dim3(KN / 256, BN_), 256, 0, stream>>>(imp, topM);
  masks2_kernel<<<dim3(KN / 256, BN_), 256, 0, stream>>>(rnd, topM, mTK, mTD);
  psum_kernel<<<dim3(KN / 256, BN_), 256, 0, stream>>>(imp, invSumP);
  colnorm_kernel<CIN><<<(BN_ * KN) / 256, 256, 0, stream>>>(x, invNX);
  xpose_kernel<CIN><<<dim3(KN / 64, CIN / 64, BN_), 256, 0, stream>>>(x, invNX,
                                                                      (__hip_bfloat16*)xnT);
  linear_kernel<CIN, CMID, false><<<(CMID / 8) * BN_, 256, 0, stream>>>(x, W1, h, nullptr);

  for (int bs = 0; bs < BN_; bs += nb) {
    simf_kernel<CIN><<<nb * 64, 256, 0, stream>>>(xnT, simA, bs, nb);
    thrfin_kernel<<<dim3(KN / 4, nb), 256, 0, stream>>>(simA, imp, invSumP, bs);
    at_kernel<<<dim3(KN / 64, KN / 64, nb), 256, 0, stream>>>(simA, At);
    sgemmf_kernel<CMID><<<dim3(KN / 128, CMID / 64, nb), 256, 0, stream>>>(h, At, emb1, bs);
  }

  colnorm_kernel<CMID><<<(BN_ * KN) / 256, 256, 0, stream>>>(emb1, invNE);
  xpose_kernel<CMID><<<dim3(KN / 64, CMID / 64, BN_), 256, 0, stream>>>(emb1, invNE,
                                                                        (__hip_bfloat16*)enT);
  linear_kernel<CMID, COUT, true><<<(COUT / 8) * BN_, 256, 0, stream>>>(emb1, W2, h2, mTK);

  for (int bs = 0; bs < BN_; bs += nb) {
    simf_kernel<CMID><<<nb * 64, 256, 0, stream>>>(enT, simA, bs, nb);
    thrfin_kernel<<<dim3(KN / 4, nb), 256, 0, stream>>>(simA, imp, invSumP, bs);
    at_kernel<<<dim3(KN / 64, KN / 64, nb), 256, 0, stream>>>(simA, At);
    sgemmf_kernel<COUT><<<dim3(KN / 128, COUT / 64, nb), 256, 0, stream>>>(h2, At, s2, bs);
  }

  bag12_kernel<<<dim3(CMID, BN_), 256, 0, stream>>>(emb1, mTK, mTD, imp, bagk, bagd);
  bag2_kernel<<<dim3(COUT, BN_), 256, 0, stream>>>(s2, mTK, imp, bag);
  pooled_kernel<<<dim3(CIN, BN_), 256, 0, stream>>>(x, imp, pooled);
  final_kernel<<<BN_, 64, 0, stream>>>(pooled, bag, id_w, id_b, fc_w, out);
}

// Round 17
// 622.289 us; speedup vs baseline: 1.0660x; 1.0040x over previous
//
#include <hip/hip_runtime.h>
#include <hip/hip_bf16.h>
#include <math.h>

#define BN_ 32
#define CIN 512
#define KN 1024
#define CMID 128
#define COUT 64
#define NCLS 5
#define NUM_TOP 205
#define NUM_KEPT 409
#define NUM_DROP 410
#define ADJ_KK 204
#define EPSF 1e-8f
#define INV_DS (1.0f / 0.599609375f)

typedef __bf16 bf16x8 __attribute__((ext_vector_type(8)));
typedef float f32x4 __attribute__((ext_vector_type(4)));

__device__ inline ushort f2bf(float x) {
  union { __hip_bfloat16 b; ushort u; } c;
  c.b = __float2bfloat16(x);
  return c.u;
}

// async global->LDS, 16B per lane (dest = wave-uniform base + lane*16)
__device__ inline void gll16(const ushort* g, ushort* l) {
  __builtin_amdgcn_global_load_lds(
      (const __attribute__((address_space(1))) unsigned int*)g,
      (__attribute__((address_space(3))) unsigned int*)l, 16, 0, 0);
}

// ---------------- masks stage 1: top mask via rank counting --------------
__global__ __launch_bounds__(256) void masks1_kernel(const float* __restrict__ imp,
                                                     float* __restrict__ topM) {
  int b = blockIdx.y;
  int i = blockIdx.x * 256 + threadIdx.x;
  __shared__ float im[KN];
  for (int j = threadIdx.x; j < KN; j += 256) im[j] = imp[(size_t)b * KN + j];
  __syncthreads();
  float vi = im[i];
  int r0 = 0, r1 = 0, r2 = 0, r3 = 0;
  for (int j = 0; j < KN; j += 4) {
    float a0 = im[j], a1 = im[j + 1], a2 = im[j + 2], a3 = im[j + 3];
    r0 += (a0 > vi || (a0 == vi && j < i)) ? 1 : 0;
    r1 += (a1 > vi || (a1 == vi && j + 1 < i)) ? 1 : 0;
    r2 += (a2 > vi || (a2 == vi && j + 2 < i)) ? 1 : 0;
    r3 += (a3 > vi || (a3 == vi && j + 3 < i)) ? 1 : 0;
  }
  int rank = r0 + r1 + r2 + r3;
  topM[(size_t)b * KN + i] = (rank < NUM_TOP) ? 1.0f : 0.0f;
}

// ---------------- masks stage 2: kept/drop ranks, fused ------------------
__global__ __launch_bounds__(256) void masks2_kernel(const float* __restrict__ rnd,
                                                     const float* __restrict__ topM,
                                                     float* __restrict__ mTK,
                                                     float* __restrict__ mTD) {
  int b = blockIdx.y;
  int i = blockIdx.x * 256 + threadIdx.x;
  __shared__ float r1s[KN];
  __shared__ float r2s[KN];
  for (int j = threadIdx.x; j < KN; j += 256) {
    float tv = topM[(size_t)b * KN + j];
    float rv = rnd[(size_t)b * KN + j];
    r1s[j] = (tv > 0.5f) ? -10.0f : rv;
    r2s[j] = (tv > 0.5f) ? 10.0f : rv;
  }
  __syncthreads();
  float v1 = r1s[i];
  float v2 = r2s[i];
  int c1a = 0, c1b = 0, c2a = 0, c2b = 0;
  for (int j = 0; j < KN; j += 2) {
    float a0 = r1s[j], a1 = r1s[j + 1];
    float b0 = r2s[j], b1 = r2s[j + 1];
    c1a += (a0 > v1 || (a0 == v1 && j < i)) ? 1 : 0;
    c1b += (a1 > v1 || (a1 == v1 && j + 1 < i)) ? 1 : 0;
    c2a += (b0 < v2 || (b0 == v2 && j < i)) ? 1 : 0;
    c2b += (b1 < v2 || (b1 == v2 && j + 1 < i)) ? 1 : 0;
  }
  int kept = (c1a + c1b) < NUM_KEPT;
  int drop = (c2a + c2b) < NUM_DROP;
  int top = topM[(size_t)b * KN + i] > 0.5f;
  mTK[(size_t)b * KN + i] = (top || kept) ? 1.0f : 0.0f;
  mTD[(size_t)b * KN + i] = (top || drop) ? 1.0f : 0.0f;
}

// ---------------- adjP row-sum reciprocals -------------------------------
__global__ void psum_kernel(const float* __restrict__ imp, float* __restrict__ invSumP) {
  int b = blockIdx.y;
  int i = blockIdx.x * 256 + threadIdx.x;
  __shared__ float im[KN];
  for (int j = threadIdx.x; j < KN; j += 256) im[j] = imp[(size_t)b * KN + j];
  __syncthreads();
  float vi = im[i];
  float s = 0.0f;
  for (int j = 0; j < KN; ++j) {
    float d = vi - im[j];
    s += __expf(-d * d * 0.125f);
  }
  invSumP[(size_t)b * KN + i] = 1.0f / (s + 1.0f + EPSF);
}

// ---------------- per-column L2 norm reciprocals -------------------------
template <int C>
__global__ void colnorm_kernel(const float* __restrict__ f, float* __restrict__ inv) {
  int idx = blockIdx.x * 256 + threadIdx.x;
  int b = idx >> 10;
  int k = idx & (KN - 1);
  const float* fb = f + (size_t)b * C * KN + k;
  float ss = 0.0f;
  for (int c = 0; c < C; ++c) {
    float v = fb[(size_t)c * KN];
    ss += v * v;
  }
  inv[idx] = 1.0f / (sqrtf(ss) + EPSF);
}

// ------- transpose + normalize + bf16: oT[b][k][c] = f[b][c][k]*inv[b][k] --
template <int C>
__global__ void xpose_kernel(const float* __restrict__ f, const float* __restrict__ inv,
                             __hip_bfloat16* __restrict__ oT) {
  int b = blockIdx.z;
  int k0 = blockIdx.x * 64;
  int c0 = blockIdx.y * 64;
  __shared__ float t[64][65];
  const float* fb = f + (size_t)b * C * KN;
  int tx = threadIdx.x & 63;
  int ty = threadIdx.x >> 6;
  for (int r = 0; r < 64; r += 4) t[r + ty][tx] = fb[(size_t)(c0 + r + ty) * KN + k0 + tx];
  __syncthreads();
  __hip_bfloat16* ob = oT + (size_t)b * KN * C;
  for (int r = 0; r < 64; r += 4) {
    int k = r + ty;
    float s = inv[(size_t)b * KN + k0 + k];
    ob[(size_t)(k0 + k) * C + c0 + tx] = __float2bfloat16(t[tx][k] * s);
  }
}

// ---------------- MFMA sim: sim = XnT * XnT^T (Gram, symmetric) ----------
template <int C>
__global__ __launch_bounds__(256) void simf_kernel(const ushort* __restrict__ xT,
                                                   float* __restrict__ sim, int bstart, int nb) {
  int f = blockIdx.x;
  int brel, tile;
  if ((nb & 7) == 0) {
    int xcd = f & 7;
    int wdx = f >> 3;
    brel = xcd * (nb >> 3) + (wdx >> 6);
    tile = wdx & 63;
  } else {
    brel = f >> 6;
    tile = f & 63;
  }
  int b = bstart + brel;
  int t = threadIdx.x;
  int lane = t & 63;
  int wid = t >> 6;
  int iB = (tile >> 3) * 128;
  int jB = (tile & 7) * 128;
  const ushort* X = xT + (size_t)b * KN * C;

  __shared__ ushort As[2][128 * 32];
  __shared__ ushort Bs[2][128 * 32];
  __shared__ float ep[4][16][65];

  int srow = t >> 2;
  int scol = (t & 3) * 8;
  int ldst = t * 8;

  auto stage = [&](int buf, int c0) {
    gll16(X + (size_t)(iB + srow) * C + c0 + scol, &As[buf][ldst]);
    gll16(X + (size_t)(iB + 64 + srow) * C + c0 + scol, &As[buf][2048 + ldst]);
    gll16(X + (size_t)(jB + srow) * C + c0 + scol, &Bs[buf][ldst]);
    gll16(X + (size_t)(jB + 64 + srow) * C + c0 + scol, &Bs[buf][2048 + ldst]);
  };

  int i0loc = (wid >> 1) * 64;
  int j0loc = (wid & 1) * 64;
  int r = lane & 15;
  int s = (lane >> 4) * 8;

  f32x4 acc[4][4] = {};
  stage(0, 0);
  __syncthreads();
  constexpr int NT = C / 32;
  int cur = 0;
#pragma unroll 2
  for (int ks = 0; ks < NT; ++ks) {
    if (ks + 1 < NT) stage(cur ^ 1, (ks + 1) * 32);
    bf16x8 a[4], bb[4];
#pragma unroll
    for (int m = 0; m < 4; ++m)
      a[m] = *reinterpret_cast<const bf16x8*>(&As[cur][(i0loc + m * 16 + r) * 32 + s]);
#pragma unroll
    for (int n = 0; n < 4; ++n)
      bb[n] = *reinterpret_cast<const bf16x8*>(&Bs[cur][(j0loc + n * 16 + r) * 32 + s]);
#pragma unroll
    for (int m = 0; m < 4; ++m)
#pragma unroll
      for (int n = 0; n < 4; ++n)
        acc[m][n] = __builtin_amdgcn_mfma_f32_16x16x32_bf16(a[m], bb[n], acc[m][n], 0, 0, 0);
    __syncthreads();
    cur ^= 1;
  }

  float(*buf)[65] = ep[wid];
  int orow = (lane >> 4) * 4;
  int ocol = lane & 15;
  int i0 = iB + i0loc;
  int j0 = jB + j0loc;
  float* simb = sim + (size_t)brel * KN * KN;
#pragma unroll
  for (int m = 0; m < 4; ++m) {
#pragma unroll
    for (int n = 0; n < 4; ++n)
#pragma unroll
      for (int rr = 0; rr < 4; ++rr) buf[orow + rr][n * 16 + ocol] = acc[m][n][rr];
#pragma unroll
    for (int rr = 0; rr < 4; ++rr) {
      int row = rr * 4 + (lane >> 4);
      float4 v4 = *(const float4*)&buf[row][(lane & 15) * 4];
      *(float4*)(simb + (size_t)(i0 + m * 16 + row) * KN + j0 + (lane & 15) * 4) = v4;
    }
  }
}

// ------- fused per-wave threshold select + finalize ----------------------
// Bisection over bits 31..8 (24-bit threshold granularity). Count split
// across pipes: 8 keys ballot+s_bcnt (SALU), 8 keys per-lane + shfl (VALU/DS).
__global__ __launch_bounds__(256) void thrfin_kernel(float* __restrict__ A,
                                                     const float* __restrict__ imp,
                                                     const float* __restrict__ invSumP,
                                                     int bstart) {
  int brel = blockIdx.y;
  int b = bstart + brel;
  int wid = threadIdx.x >> 6;
  int lane = threadIdx.x & 63;
  int i = blockIdx.x * 4 + wid;
  float* row = A + ((size_t)brel * KN + i) * KN;
  __shared__ float im[KN];
  ((float4*)im)[threadIdx.x] = ((const float4*)(imp + (size_t)b * KN))[threadIdx.x];
  __syncthreads();

  float4 v[4];
  unsigned key[16];
#pragma unroll
  for (int q = 0; q < 4; ++q) v[q] = ((const float4*)row)[lane + 64 * q];
#pragma unroll
  for (int q = 0; q < 4; ++q) {
    const float* pv = (const float*)&v[q];
#pragma unroll
    for (int e = 0; e < 4; ++e) {
      unsigned u = __float_as_uint(pv[e]);
      key[q * 4 + e] = (u & 0x80000000u) ? ~u : (u | 0x80000000u);
    }
  }
  unsigned tk = 0u;
#pragma unroll 1
  for (int bit = 31; bit >= 8; --bit) {
    unsigned cand = tk | (1u << bit);
    int c = 0;
#pragma unroll
    for (int e = 0; e < 8; ++e)
      c += (int)__popcll(__ballot(key[e] >= cand));
    int cl = 0;
#pragma unroll
    for (int e = 8; e < 16; ++e) cl += (key[e] >= cand) ? 1 : 0;
#pragma unroll
    for (int off = 32; off > 0; off >>= 1) cl += __shfl_xor(cl, off);
    c += cl;
    if (c >= ADJ_KK) tk = cand;
  }
  float m[16];
  float s = 0.0f;
#pragma unroll
  for (int q = 0; q < 4; ++q) {
    const float* pv = (const float*)&v[q];
#pragma unroll
    for (int e = 0; e < 4; ++e) {
      float mv = (key[q * 4 + e] >= tk) ? pv[e] : 0.0f;
      m[q * 4 + e] = mv;
      s += mv;
    }
  }
#pragma unroll
  for (int off = 32; off > 0; off >>= 1) s += __shfl_xor(s, off);
  float invF = 1.0f / (s + 1.0f + EPSF);
  float vi = im[i];
  float invP = invSumP[(size_t)b * KN + i];
  ushort* rowb = (ushort*)row;
#pragma unroll
  for (int q = 0; q < 4; ++q) {
    float4 iv = ((const float4*)im)[lane + 64 * q];
    const float* ip = (const float*)&iv;
    ushort4 r;
    ushort* rp = (ushort*)&r;
    int colb = 4 * lane + 256 * q;
#pragma unroll
    for (int e = 0; e < 4; ++e) {
      float diag = (colb + e == i) ? 1.0f : 0.0f;
      float d = vi - ip[e];
      rp[e] = f2bf((m[q * 4 + e] + diag) * invF + (__expf(-d * d * 0.125f) + diag) * invP);
    }
    ((ushort4*)rowb)[lane + 64 * q] = r;
  }
}

// ------- bf16 transpose: At[b][j][k] = A[b][k][j] (A row stride 2048) ----
// ushort4-vectorized both sides; [64][68] pad keeps 8B alignment.
__global__ __launch_bounds__(256) void at_kernel(const float* __restrict__ Asim,
                                                 ushort* __restrict__ At) {
  int brel = blockIdx.z;
  int k0 = blockIdx.x * 64;
  int j0 = blockIdx.y * 64;
  __shared__ ushort t[64][68];
  const ushort* Ab = (const ushort*)(Asim + (size_t)brel * KN * KN);
  int g = threadIdx.x & 15;
  int r = threadIdx.x >> 4;
#pragma unroll
  for (int p = 0; p < 4; ++p) {
    int row = p * 16 + r;
    *(ushort4*)&t[row][g * 4] =
        *(const ushort4*)&Ab[(size_t)(k0 + row) * 2048 + j0 + g * 4];
  }
  __syncthreads();
  ushort* ob = At + (size_t)brel * KN * KN;
#pragma unroll
  for (int p = 0; p < 4; ++p) {
    int j = p * 16 + r;
    ushort4 v;
    v.x = t[g * 4 + 0][j];
    v.y = t[g * 4 + 1][j];
    v.z = t[g * 4 + 2][j];
    v.w = t[g * 4 + 3][j];
    *(ushort4*)&ob[(size_t)(j0 + j) * KN + k0 + g * 4] = v;
  }
}

// ---------------- per-node linear: h[b,o,k] = sum_c f[b,c,k] W[c,o] (bf16 out)
// o-tile = 8: 16KB LDS Ws tile, grid (M/8)*32 (2 blk/CU), b-major flat grid
// (stride 32 = 0 mod 8) keeps batch b's blocks on one XCD sharing x[b] in L2.
template <int C, int M, bool MASK>
__global__ __launch_bounds__(256) void linear_kernel(const float* __restrict__ f,
                                                     const float* __restrict__ W,
                                                     ushort* __restrict__ outp,
                                                     const float* __restrict__ mTK) {
  int fl = blockIdx.x;
  int b = fl & 31;
  int o0 = (fl >> 5) * 8;
  __shared__ float Ws[C][8];
  for (int l = threadIdx.x; l < C * 8; l += 256) {
    int c = l >> 3, o = l & 7;
    Ws[c][o] = W[(size_t)c * M + o0 + o];
  }
  __syncthreads();
  int k0 = threadIdx.x * 4;
  const float* fb = f + (size_t)b * C * KN;
  float acc[8][4] = {};
  for (int c = 0; c < C; ++c) {
    float4 xv = *(const float4*)(fb + (size_t)c * KN + k0);
#pragma unroll
    for (int o = 0; o < 8; ++o) {
      float w = Ws[c][o];
      acc[o][0] += xv.x * w;
      acc[o][1] += xv.y * w;
      acc[o][2] += xv.z * w;
      acc[o][3] += xv.w * w;
    }
  }
  float ms[4] = {1.0f, 1.0f, 1.0f, 1.0f};
  if (MASK) {
#pragma unroll
    for (int jj = 0; jj < 4; ++jj) ms[jj] = mTK[(size_t)b * KN + k0 + jj] * INV_DS;
  }
#pragma unroll
  for (int o = 0; o < 8; ++o) {
    ushort4 r;
    r.x = f2bf(acc[o][0] * ms[0]);
    r.y = f2bf(acc[o][1] * ms[1]);
    r.z = f2bf(acc[o][2] * ms[2]);
    r.w = f2bf(acc[o][3] * ms[3]);
    *(ushort4*)(outp + ((size_t)b * M + o0 + o) * KN + k0) = r;
  }
}

// ---------------- MFMA s = relu(h @ A) via At, LDS-staged ----------------
template <int M>
__global__ __launch_bounds__(256) void sgemmf_kernel(const ushort* __restrict__ hB,
                                                     const ushort* __restrict__ At,
                                                     float* __restrict__ outp, int bstart) {
  int brel = blockIdx.z;
  int b = bstart + brel;
  int t = threadIdx.x;
  int lane = t & 63;
  int wid = t >> 6;
  int iB = blockIdx.y * 64;
  int jB = blockIdx.x * 128;
  const ushort* hb = hB + (size_t)b * M * KN;
  const ushort* Ab = At + (size_t)brel * KN * KN;

  __shared__ ushort Hs[2][64 * 32];
  __shared__ ushort Bs[2][128 * 32];
  __shared__ float ep[4][16][65];

  int srow = t >> 2;
  int scol = (t & 3) * 8;
  int ldst = t * 8;

  auto stage = [&](int buf, int k0) {
    gll16(hb + (size_t)(iB + srow) * KN + k0 + scol, &Hs[buf][ldst]);
    gll16(Ab + (size_t)(jB + srow) * KN + k0 + scol, &Bs[buf][ldst]);
    gll16(Ab + (size_t)(jB + 64 + srow) * KN + k0 + scol, &Bs[buf][2048 + ldst]);
  };

  int i0loc = (wid >> 1) * 32;
  int j0loc = (wid & 1) * 64;
  int r = lane & 15;
  int s = (lane >> 4) * 8;

  f32x4 acc[2][4] = {};
  stage(0, 0);
  __syncthreads();
  int cur = 0;
#pragma unroll 2
  for (int ks = 0; ks < KN / 32; ++ks) {
    if (ks + 1 < KN / 32) stage(cur ^ 1, (ks + 1) * 32);
    bf16x8 a[2], bb[4];
#pragma unroll
    for (int m = 0; m < 2; ++m)
      a[m] = *reinterpret_cast<const bf16x8*>(&Hs[cur][(i0loc + m * 16 + r) * 32 + s]);
#pragma unroll
    for (int n = 0; n < 4; ++n)
      bb[n] = *reinterpret_cast<const bf16x8*>(&Bs[cur][(j0loc + n * 16 + r) * 32 + s]);
#pragma unroll
    for (int m = 0; m < 2; ++m)
#pragma unroll
      for (int n = 0; n < 4; ++n)
        acc[m][n] = __builtin_amdgcn_mfma_f32_16x16x32_bf16(a[m], bb[n], acc[m][n], 0, 0, 0);
    __syncthreads();
    cur ^= 1;
  }

  float(*buf)[65] = ep[wid];
  int orow = (lane >> 4) * 4;
  int ocol = lane & 15;
  int i0 = iB + i0loc;
  int j0 = jB + j0loc;
  float* ob = outp + (size_t)b * M * KN;
#pragma unroll
  for (int m = 0; m < 2; ++m) {
#pragma unroll
    for (int n = 0; n < 4; ++n)
#pragma unroll
      for (int rr = 0; rr < 4; ++rr) buf[orow + rr][n * 16 + ocol] = fmaxf(acc[m][n][rr], 0.0f);
#pragma unroll
    for (int rr = 0; rr < 4; ++rr) {
      int row = rr * 4 + (lane >> 4);
      float4 v4 = *(const float4*)&buf[row][(lane & 15) * 4];
      *(float4*)(ob + (size_t)(i0 + m * 16 + row) * KN + j0 + (lane & 15) * 4) = v4;
    }
  }
}

// ---------------- reductions ---------------------------------------------
__global__ void bag12_kernel(const float* __restrict__ emb1, const float* __restrict__ mTK,
                             const float* __restrict__ mTD, const float* __restrict__ imp,
                             float* __restrict__ bagk, float* __restrict__ bagd) {
  int c = blockIdx.x, b = blockIdx.y;
  int t = threadIdx.x;
  const float* e = emb1 + ((size_t)b * CMID + c) * KN;
  const float* ir = imp + (size_t)b * KN;
  const float* m1 = mTK + (size_t)b * KN;
  const float* m2 = mTD + (size_t)b * KN;
  float s1 = 0.0f, sd = 0.0f;
  for (int k = t; k < KN; k += 256) {
    float ev = e[k] * ir[k];
    s1 += ev * m1[k];
    sd += ev * m2[k];
  }
  __shared__ float r1[256], r2[256];
  r1[t] = s1;
  r2[t] = sd;
  __syncthreads();
  for (int st = 128; st > 0; st >>= 1) {
    if (t < st) {
      r1[t] += r1[t + st];
      r2[t] += r2[t + st];
    }
    __syncthreads();
  }
  if (t == 0) {
    bagk[(size_t)b * CMID + c] = r1[0] * INV_DS;
    bagd[(size_t)b * CMID + c] = r2[0] * INV_DS;
  }
}

__global__ void bag2_kernel(const float* __restrict__ s2, const float* __restrict__ mTK,
                            const float* __restrict__ imp, float* __restrict__ bag) {
  int o = blockIdx.x, b = blockIdx.y;
  int t = threadIdx.x;
  const float* sr = s2 + ((size_t)b * COUT + o) * KN;
  const float* ir = imp + (size_t)b * KN;
  const float* mr = mTK + (size_t)b * KN;
  float s = 0.0f;
  for (int k = t; k < KN; k += 256) s += sr[k] * mr[k] * ir[k];
  __shared__ float red[256];
  red[t] = s;
  __syncthreads();
  for (int st = 128; st > 0; st >>= 1) {
    if (t < st) red[t] += red[t + st];
    __syncthreads();
  }
  if (t == 0) bag[(size_t)b * COUT + o] = red[0];
}

__global__ void pooled_kernel(const float* __restrict__ x, const float* __restrict__ imp,
                              float* __restrict__ pooled) {
  int c = blockIdx.x, b = blockIdx.y;
  int t = threadIdx.x;
  const float* xr = x + ((size_t)b * CIN + c) * KN;
  const float* ir = imp + (size_t)b * KN;
  float s = 0.0f;
  for (int k = t; k < KN; k += 256) s += xr[k] * ir[k];
  __shared__ float red[256];
  red[t] = s;
  __syncthreads();
  for (int st = 128; st > 0; st >>= 1) {
    if (t < st) red[t] += red[t + st];
    __syncthreads();
  }
  if (t == 0) pooled[(size_t)b * CIN + c] = red[0];
}

__global__ void final_kernel(const float* __restrict__ pooled, const float* __restrict__ bag,
                             const float* __restrict__ id_w, const float* __restrict__ id_b,
                             const float* __restrict__ fc_w, float* __restrict__ out) {
  int b = blockIdx.x;
  int o = threadIdx.x;
  __shared__ float v[COUT];
  float s = id_b[o];
  const float* pr = pooled + (size_t)b * CIN;
  for (int c = 0; c < CIN; ++c) s += pr[c] * id_w[(size_t)c * COUT + o];
  v[o] = bag[(size_t)b * COUT + o] + fmaxf(s, 0.0f);
  __syncthreads();
  if (o < NCLS) {
    float acc = 0.0f;
    for (int oo = 0; oo < COUT; ++oo) acc += v[oo] * fc_w[(size_t)oo * NCLS + o];
    out[(size_t)b * NCLS + o] = acc;
  }
}

// ---------------- launch --------------------------------------------------
extern "C" void kernel_launch(void* const* d_in, const int* in_sizes, int n_in,
                              void* d_out, int out_size, void* d_ws, size_t ws_size,
                              hipStream_t stream) {
  const float* x = (const float*)d_in[0];
  const float* imp = (const float*)d_in[1];
  const float* rnd = (const float*)d_in[2];
  const float* W1 = (const float*)d_in[3];
  const float* W2 = (const float*)d_in[4];
  const float* fc_w = (const float*)d_in[5];
  const float* id_w = (const float*)d_in[6];
  const float* id_b = (const float*)d_in[7];
  float* out = (float*)d_out;
  float* emb1 = out + BN_ * NCLS;
  float* bagk = emb1 + (size_t)BN_ * CMID * KN;
  float* bagd = bagk + (size_t)BN_ * CMID;

  float* w = (float*)d_ws;
  size_t off = 0;
  auto take = [&](size_t n) {
    float* p = w + off;
    off += n;
    return p;
  };
  float* invSumP = take((size_t)BN_ * KN);
  float* invNX = take((size_t)BN_ * KN);
  float* invNE = take((size_t)BN_ * KN);
  float* topM = take((size_t)BN_ * KN);
  float* mTK = take((size_t)BN_ * KN);
  float* mTD = take((size_t)BN_ * KN);
  float* bag = take((size_t)BN_ * COUT);
  float* pooled = take((size_t)BN_ * CIN);

  // Lifetime-aliased union region: layer-1 {xnT, h} dies before layer-2
  // {enT, h2, s2} is born (colnorm<CMID> runs after the layer-1 loop).
  const size_t xnT_f = (size_t)BN_ * CIN * KN / 2;   // xnT as floats
  const size_t h_f = (size_t)BN_ * CMID * KN / 2;    // h as floats
  const size_t enT_f = (size_t)BN_ * CMID * KN / 2;  // enT as floats
  const size_t h2_f = (size_t)BN_ * COUT * KN / 2;   // h2 as floats
  const size_t s2_f = (size_t)BN_ * COUT * KN;       // s2 floats
  size_t uA = xnT_f + h_f;
  size_t uB = enT_f + h2_f + s2_f;
  float* U = take(uA > uB ? uA : uB);
  ushort* xnT = (ushort*)U;
  ushort* h = (ushort*)(U + xnT_f);
  ushort* enT = (ushort*)U;
  ushort* h2 = (ushort*)(U + enT_f);
  float* s2 = U + enT_f + h2_f;

  long long avail = (long long)(ws_size / 4) - (long long)off;
  int nb = 1;
  const int cands[6] = {32, 16, 8, 4, 2, 1};
  for (int ci = 0; ci < 6; ++ci) {
    if ((long long)cands[ci] * KN * KN * 3 / 2 <= avail) {
      nb = cands[ci];
      break;
    }
  }
  float* simA = take((size_t)nb * KN * KN);
  ushort* At = (ushort*)take((size_t)nb * KN * KN / 2);

  masks1_kernel<<<dim3(KN / 256, BN_), 256, 0, stream>>>(imp, topM);
  masks2_kernel<<<dim3(KN / 256, BN_), 256, 0, stream>>>(rnd, topM, mTK, mTD);
  psum_kernel<<<dim3(KN / 256, BN_), 256, 0, stream>>>(imp, invSumP);
  colnorm_kernel<CIN><<<(BN_ * KN) / 256, 256, 0, stream>>>(x, invNX);
  xpose_kernel<CIN><<<dim3(KN / 64, CIN / 64, BN_), 256, 0, stream>>>(x, invNX,
                                                                      (__hip_bfloat16*)xnT);
  linear_kernel<CIN, CMID, false><<<(CMID / 8) * BN_, 256, 0, stream>>>(x, W1, h, nullptr);

  for (int bs = 0; bs < BN_; bs += nb) {
    simf_kernel<CIN><<<nb * 64, 256, 0, stream>>>(xnT, simA, bs, nb);
    thrfin_kernel<<<dim3(KN / 4, nb), 256, 0, stream>>>(simA, imp, invSumP, bs);
    at_kernel<<<dim3(KN / 64, KN / 64, nb), 256, 0, stream>>>(simA, At);
    sgemmf_kernel<CMID><<<dim3(KN / 128, CMID / 64, nb), 256, 0, stream>>>(h, At, emb1, bs);
  }

  colnorm_kernel<CMID><<<(BN_ * KN) / 256, 256, 0, stream>>>(emb1, invNE);
  xpose_kernel<CMID><<<dim3(KN / 64, CMID / 64, BN_), 256, 0, stream>>>(emb1, invNE,
                                                                        (__hip_bfloat16*)enT);
  linear_kernel<CMID, COUT, true><<<(COUT / 8) * BN_, 256, 0, stream>>>(emb1, W2, h2, mTK);

  for (int bs = 0; bs < BN_; bs += nb) {
    simf_kernel<CMID><<<nb * 64, 256, 0, stream>>>(enT, simA, bs, nb);
    thrfin_kernel<<<dim3(KN / 4, nb), 256, 0, stream>>>(simA, imp, invSumP, bs);
    at_kernel<<<dim3(KN / 64, KN / 64, nb), 256, 0, stream>>>(simA, At);
    sgemmf_kernel<COUT><<<dim3(KN / 128, COUT / 64, nb), 256, 0, stream>>>(h2, At, s2, bs);
  }

  bag12_kernel<<<dim3(CMID, BN_), 256, 0, stream>>>(emb1, mTK, mTD, imp, bagk, bagd);
  bag2_kernel<<<dim3(COUT, BN_), 256, 0, stream>>>(s2, mTK, imp, bag);
  pooled_kernel<<<dim3(CIN, BN_), 256, 0, stream>>>(x, imp, pooled);
  final_kernel<<<BN_, 64, 0, stream>>>(pooled, bag, id_w, id_b, fc_w, out);
}

// Round 18
// 602.304 us; speedup vs baseline: 1.1013x; 1.0332x over previous
//
#include <hip/hip_runtime.h>
#include <hip/hip_bf16.h>
#include <math.h>

#define BN_ 32
#define CIN 512
#define KN 1024
#define CMID 128
#define COUT 64
#define NCLS 5
#define NUM_TOP 205
#define NUM_KEPT 409
#define NUM_DROP 410
#define ADJ_KK 204
#define EPSF 1e-8f
#define INV_DS (1.0f / 0.599609375f)

typedef __bf16 bf16x8 __attribute__((ext_vector_type(8)));
typedef float f32x4 __attribute__((ext_vector_type(4)));

__device__ inline ushort f2bf(float x) {
  union { __hip_bfloat16 b; ushort u; } c;
  c.b = __float2bfloat16(x);
  return c.u;
}

// async global->LDS, 16B per lane (dest = wave-uniform base + lane*16)
__device__ inline void gll16(const ushort* g, ushort* l) {
  __builtin_amdgcn_global_load_lds(
      (const __attribute__((address_space(1))) unsigned int*)g,
      (__attribute__((address_space(3))) unsigned int*)l, 16, 0, 0);
}

// ---------------- masks stage 1: top mask via rank counting --------------
__global__ __launch_bounds__(256) void masks1_kernel(const float* __restrict__ imp,
                                                     float* __restrict__ topM) {
  int b = blockIdx.y;
  int i = blockIdx.x * 256 + threadIdx.x;
  __shared__ float im[KN];
  for (int j = threadIdx.x; j < KN; j += 256) im[j] = imp[(size_t)b * KN + j];
  __syncthreads();
  float vi = im[i];
  int r0 = 0, r1 = 0, r2 = 0, r3 = 0;
  for (int j = 0; j < KN; j += 4) {
    float a0 = im[j], a1 = im[j + 1], a2 = im[j + 2], a3 = im[j + 3];
    r0 += (a0 > vi || (a0 == vi && j < i)) ? 1 : 0;
    r1 += (a1 > vi || (a1 == vi && j + 1 < i)) ? 1 : 0;
    r2 += (a2 > vi || (a2 == vi && j + 2 < i)) ? 1 : 0;
    r3 += (a3 > vi || (a3 == vi && j + 3 < i)) ? 1 : 0;
  }
  int rank = r0 + r1 + r2 + r3;
  topM[(size_t)b * KN + i] = (rank < NUM_TOP) ? 1.0f : 0.0f;
}

// ---------------- masks stage 2: kept/drop ranks, fused ------------------
__global__ __launch_bounds__(256) void masks2_kernel(const float* __restrict__ rnd,
                                                     const float* __restrict__ topM,
                                                     float* __restrict__ mTK,
                                                     float* __restrict__ mTD) {
  int b = blockIdx.y;
  int i = blockIdx.x * 256 + threadIdx.x;
  __shared__ float r1s[KN];
  __shared__ float r2s[KN];
  for (int j = threadIdx.x; j < KN; j += 256) {
    float tv = topM[(size_t)b * KN + j];
    float rv = rnd[(size_t)b * KN + j];
    r1s[j] = (tv > 0.5f) ? -10.0f : rv;
    r2s[j] = (tv > 0.5f) ? 10.0f : rv;
  }
  __syncthreads();
  float v1 = r1s[i];
  float v2 = r2s[i];
  int c1a = 0, c1b = 0, c2a = 0, c2b = 0;
  for (int j = 0; j < KN; j += 2) {
    float a0 = r1s[j], a1 = r1s[j + 1];
    float b0 = r2s[j], b1 = r2s[j + 1];
    c1a += (a0 > v1 || (a0 == v1 && j < i)) ? 1 : 0;
    c1b += (a1 > v1 || (a1 == v1 && j + 1 < i)) ? 1 : 0;
    c2a += (b0 < v2 || (b0 == v2 && j < i)) ? 1 : 0;
    c2b += (b1 < v2 || (b1 == v2 && j + 1 < i)) ? 1 : 0;
  }
  int kept = (c1a + c1b) < NUM_KEPT;
  int drop = (c2a + c2b) < NUM_DROP;
  int top = topM[(size_t)b * KN + i] > 0.5f;
  mTK[(size_t)b * KN + i] = (top || kept) ? 1.0f : 0.0f;
  mTD[(size_t)b * KN + i] = (top || drop) ? 1.0f : 0.0f;
}

// ---------------- adjP row-sum reciprocals -------------------------------
__global__ void psum_kernel(const float* __restrict__ imp, float* __restrict__ invSumP) {
  int b = blockIdx.y;
  int i = blockIdx.x * 256 + threadIdx.x;
  __shared__ float im[KN];
  for (int j = threadIdx.x; j < KN; j += 256) im[j] = imp[(size_t)b * KN + j];
  __syncthreads();
  float vi = im[i];
  float s = 0.0f;
  for (int j = 0; j < KN; ++j) {
    float d = vi - im[j];
    s += __expf(-d * d * 0.125f);
  }
  invSumP[(size_t)b * KN + i] = 1.0f / (s + 1.0f + EPSF);
}

// ---------------- per-column L2 norm reciprocals -------------------------
template <int C>
__global__ void colnorm_kernel(const float* __restrict__ f, float* __restrict__ inv) {
  int idx = blockIdx.x * 256 + threadIdx.x;
  int b = idx >> 10;
  int k = idx & (KN - 1);
  const float* fb = f + (size_t)b * C * KN + k;
  float ss = 0.0f;
  for (int c = 0; c < C; ++c) {
    float v = fb[(size_t)c * KN];
    ss += v * v;
  }
  inv[idx] = 1.0f / (sqrtf(ss) + EPSF);
}

// ------- transpose + normalize + bf16: oT[b][k][c] = f[b][c][k]*inv[b][k] --
template <int C>
__global__ void xpose_kernel(const float* __restrict__ f, const float* __restrict__ inv,
                             __hip_bfloat16* __restrict__ oT) {
  int b = blockIdx.z;
  int k0 = blockIdx.x * 64;
  int c0 = blockIdx.y * 64;
  __shared__ float t[64][65];
  const float* fb = f + (size_t)b * C * KN;
  int tx = threadIdx.x & 63;
  int ty = threadIdx.x >> 6;
  for (int r = 0; r < 64; r += 4) t[r + ty][tx] = fb[(size_t)(c0 + r + ty) * KN + k0 + tx];
  __syncthreads();
  __hip_bfloat16* ob = oT + (size_t)b * KN * C;
  for (int r = 0; r < 64; r += 4) {
    int k = r + ty;
    float s = inv[(size_t)b * KN + k0 + k];
    ob[(size_t)(k0 + k) * C + c0 + tx] = __float2bfloat16(t[tx][k] * s);
  }
}

// ---------------- MFMA sim: sim = XnT * XnT^T (Gram, symmetric) ----------
template <int C>
__global__ __launch_bounds__(256) void simf_kernel(const ushort* __restrict__ xT,
                                                   float* __restrict__ sim, int bstart, int nb) {
  int f = blockIdx.x;
  int brel, tile;
  if ((nb & 7) == 0) {
    int xcd = f & 7;
    int wdx = f >> 3;
    brel = xcd * (nb >> 3) + (wdx >> 6);
    tile = wdx & 63;
  } else {
    brel = f >> 6;
    tile = f & 63;
  }
  int b = bstart + brel;
  int t = threadIdx.x;
  int lane = t & 63;
  int wid = t >> 6;
  int iB = (tile >> 3) * 128;
  int jB = (tile & 7) * 128;
  const ushort* X = xT + (size_t)b * KN * C;

  __shared__ ushort As[2][128 * 32];
  __shared__ ushort Bs[2][128 * 32];
  __shared__ float ep[4][16][65];

  int srow = t >> 2;
  int scol = (t & 3) * 8;
  int ldst = t * 8;

  auto stage = [&](int buf, int c0) {
    gll16(X + (size_t)(iB + srow) * C + c0 + scol, &As[buf][ldst]);
    gll16(X + (size_t)(iB + 64 + srow) * C + c0 + scol, &As[buf][2048 + ldst]);
    gll16(X + (size_t)(jB + srow) * C + c0 + scol, &Bs[buf][ldst]);
    gll16(X + (size_t)(jB + 64 + srow) * C + c0 + scol, &Bs[buf][2048 + ldst]);
  };

  int i0loc = (wid >> 1) * 64;
  int j0loc = (wid & 1) * 64;
  int r = lane & 15;
  int s = (lane >> 4) * 8;

  f32x4 acc[4][4] = {};
  stage(0, 0);
  __syncthreads();
  constexpr int NT = C / 32;
  int cur = 0;
#pragma unroll 2
  for (int ks = 0; ks < NT; ++ks) {
    if (ks + 1 < NT) stage(cur ^ 1, (ks + 1) * 32);
    bf16x8 a[4], bb[4];
#pragma unroll
    for (int m = 0; m < 4; ++m)
      a[m] = *reinterpret_cast<const bf16x8*>(&As[cur][(i0loc + m * 16 + r) * 32 + s]);
#pragma unroll
    for (int n = 0; n < 4; ++n)
      bb[n] = *reinterpret_cast<const bf16x8*>(&Bs[cur][(j0loc + n * 16 + r) * 32 + s]);
#pragma unroll
    for (int m = 0; m < 4; ++m)
#pragma unroll
      for (int n = 0; n < 4; ++n)
        acc[m][n] = __builtin_amdgcn_mfma_f32_16x16x32_bf16(a[m], bb[n], acc[m][n], 0, 0, 0);
    __syncthreads();
    cur ^= 1;
  }

  float(*buf)[65] = ep[wid];
  int orow = (lane >> 4) * 4;
  int ocol = lane & 15;
  int i0 = iB + i0loc;
  int j0 = jB + j0loc;
  float* simb = sim + (size_t)brel * KN * KN;
#pragma unroll
  for (int m = 0; m < 4; ++m) {
#pragma unroll
    for (int n = 0; n < 4; ++n)
#pragma unroll
      for (int rr = 0; rr < 4; ++rr) buf[orow + rr][n * 16 + ocol] = acc[m][n][rr];
#pragma unroll
    for (int rr = 0; rr < 4; ++rr) {
      int row = rr * 4 + (lane >> 4);
      float4 v4 = *(const float4*)&buf[row][(lane & 15) * 4];
      *(float4*)(simb + (size_t)(i0 + m * 16 + row) * KN + j0 + (lane & 15) * 4) = v4;
    }
  }
}

// ------- fused per-wave threshold select + finalize ----------------------
// Bisection over bits 31..8 (24-bit threshold granularity). Count split
// across pipes: 8 keys ballot+s_bcnt (SALU), 8 keys per-lane + shfl (VALU/DS).
__global__ __launch_bounds__(256) void thrfin_kernel(float* __restrict__ A,
                                                     const float* __restrict__ imp,
                                                     const float* __restrict__ invSumP,
                                                     int bstart) {
  int brel = blockIdx.y;
  int b = bstart + brel;
  int wid = threadIdx.x >> 6;
  int lane = threadIdx.x & 63;
  int i = blockIdx.x * 4 + wid;
  float* row = A + ((size_t)brel * KN + i) * KN;
  __shared__ float im[KN];
  ((float4*)im)[threadIdx.x] = ((const float4*)(imp + (size_t)b * KN))[threadIdx.x];
  __syncthreads();

  float4 v[4];
  unsigned key[16];
#pragma unroll
  for (int q = 0; q < 4; ++q) v[q] = ((const float4*)row)[lane + 64 * q];
#pragma unroll
  for (int q = 0; q < 4; ++q) {
    const float* pv = (const float*)&v[q];
#pragma unroll
    for (int e = 0; e < 4; ++e) {
      unsigned u = __float_as_uint(pv[e]);
      key[q * 4 + e] = (u & 0x80000000u) ? ~u : (u | 0x80000000u);
    }
  }
  unsigned tk = 0u;
#pragma unroll 1
  for (int bit = 31; bit >= 8; --bit) {
    unsigned cand = tk | (1u << bit);
    int c = 0;
#pragma unroll
    for (int e = 0; e < 8; ++e)
      c += (int)__popcll(__ballot(key[e] >= cand));
    int cl = 0;
#pragma unroll
    for (int e = 8; e < 16; ++e) cl += (key[e] >= cand) ? 1 : 0;
#pragma unroll
    for (int off = 32; off > 0; off >>= 1) cl += __shfl_xor(cl, off);
    c += cl;
    if (c >= ADJ_KK) tk = cand;
  }
  float m[16];
  float s = 0.0f;
#pragma unroll
  for (int q = 0; q < 4; ++q) {
    const float* pv = (const float*)&v[q];
#pragma unroll
    for (int e = 0; e < 4; ++e) {
      float mv = (key[q * 4 + e] >= tk) ? pv[e] : 0.0f;
      m[q * 4 + e] = mv;
      s += mv;
    }
  }
#pragma unroll
  for (int off = 32; off > 0; off >>= 1) s += __shfl_xor(s, off);
  float invF = 1.0f / (s + 1.0f + EPSF);
  float vi = im[i];
  float invP = invSumP[(size_t)b * KN + i];
  ushort* rowb = (ushort*)row;
#pragma unroll
  for (int q = 0; q < 4; ++q) {
    float4 iv = ((const float4*)im)[lane + 64 * q];
    const float* ip = (const float*)&iv;
    ushort4 r;
    ushort* rp = (ushort*)&r;
    int colb = 4 * lane + 256 * q;
#pragma unroll
    for (int e = 0; e < 4; ++e) {
      float diag = (colb + e == i) ? 1.0f : 0.0f;
      float d = vi - ip[e];
      rp[e] = f2bf((m[q * 4 + e] + diag) * invF + (__expf(-d * d * 0.125f) + diag) * invP);
    }
    ((ushort4*)rowb)[lane + 64 * q] = r;
  }
}

// ------- bf16 transpose INTO sim rows' back halves -----------------------
// A bf16 lives in front 1024 ushorts of each 2048-ushort sim row; the
// transpose At[j][k] is written to ushort index j*2048 + 1024 + k of the
// same per-batch buffer (disjoint from all front halves).
__global__ __launch_bounds__(256) void at_kernel(float* __restrict__ Asim) {
  int brel = blockIdx.z;
  int k0 = blockIdx.x * 64;
  int j0 = blockIdx.y * 64;
  __shared__ ushort t[64][68];
  ushort* Ab = (ushort*)(Asim + (size_t)brel * KN * KN);
  int g = threadIdx.x & 15;
  int r = threadIdx.x >> 4;
#pragma unroll
  for (int p = 0; p < 4; ++p) {
    int row = p * 16 + r;
    *(ushort4*)&t[row][g * 4] =
        *(const ushort4*)&Ab[(size_t)(k0 + row) * 2048 + j0 + g * 4];
  }
  __syncthreads();
#pragma unroll
  for (int p = 0; p < 4; ++p) {
    int j = p * 16 + r;
    ushort4 v;
    v.x = t[g * 4 + 0][j];
    v.y = t[g * 4 + 1][j];
    v.z = t[g * 4 + 2][j];
    v.w = t[g * 4 + 3][j];
    *(ushort4*)&Ab[(size_t)(j0 + j) * 2048 + 1024 + k0 + g * 4] = v;
  }
}

// ---------------- per-node linear: h[b,o,k] = sum_c f[b,c,k] W[c,o] (bf16 out)
// o-tile = 8: 16KB LDS Ws tile, grid (M/8)*32 (2 blk/CU), b-major flat grid
// (stride 32 = 0 mod 8) keeps batch b's blocks on one XCD sharing x[b] in L2.
template <int C, int M, bool MASK>
__global__ __launch_bounds__(256) void linear_kernel(const float* __restrict__ f,
                                                     const float* __restrict__ W,
                                                     ushort* __restrict__ outp,
                                                     const float* __restrict__ mTK) {
  int fl = blockIdx.x;
  int b = fl & 31;
  int o0 = (fl >> 5) * 8;
  __shared__ float Ws[C][8];
  for (int l = threadIdx.x; l < C * 8; l += 256) {
    int c = l >> 3, o = l & 7;
    Ws[c][o] = W[(size_t)c * M + o0 + o];
  }
  __syncthreads();
  int k0 = threadIdx.x * 4;
  const float* fb = f + (size_t)b * C * KN;
  float acc[8][4] = {};
  for (int c = 0; c < C; ++c) {
    float4 xv = *(const float4*)(fb + (size_t)c * KN + k0);
#pragma unroll
    for (int o = 0; o < 8; ++o) {
      float w = Ws[c][o];
      acc[o][0] += xv.x * w;
      acc[o][1] += xv.y * w;
      acc[o][2] += xv.z * w;
      acc[o][3] += xv.w * w;
    }
  }
  float ms[4] = {1.0f, 1.0f, 1.0f, 1.0f};
  if (MASK) {
#pragma unroll
    for (int jj = 0; jj < 4; ++jj) ms[jj] = mTK[(size_t)b * KN + k0 + jj] * INV_DS;
  }
#pragma unroll
  for (int o = 0; o < 8; ++o) {
    ushort4 r;
    r.x = f2bf(acc[o][0] * ms[0]);
    r.y = f2bf(acc[o][1] * ms[1]);
    r.z = f2bf(acc[o][2] * ms[2]);
    r.w = f2bf(acc[o][3] * ms[3]);
    *(ushort4*)(outp + ((size_t)b * M + o0 + o) * KN + k0) = r;
  }
}

// ---------------- MFMA s = relu(h @ A), At read from sim back halves -----
template <int M>
__global__ __launch_bounds__(256) void sgemmf_kernel(const ushort* __restrict__ hB,
                                                     const float* __restrict__ Asim,
                                                     float* __restrict__ outp, int bstart) {
  int brel = blockIdx.z;
  int b = bstart + brel;
  int t = threadIdx.x;
  int lane = t & 63;
  int wid = t >> 6;
  int iB = blockIdx.y * 64;
  int jB = blockIdx.x * 128;
  const ushort* hb = hB + (size_t)b * M * KN;
  const ushort* Ab = (const ushort*)(Asim + (size_t)brel * KN * KN);

  __shared__ ushort Hs[2][64 * 32];
  __shared__ ushort Bs[2][128 * 32];
  __shared__ float ep[4][16][65];

  int srow = t >> 2;
  int scol = (t & 3) * 8;
  int ldst = t * 8;

  auto stage = [&](int buf, int k0) {
    gll16(hb + (size_t)(iB + srow) * KN + k0 + scol, &Hs[buf][ldst]);
    gll16(Ab + (size_t)(jB + srow) * 2048 + 1024 + k0 + scol, &Bs[buf][ldst]);
    gll16(Ab + (size_t)(jB + 64 + srow) * 2048 + 1024 + k0 + scol, &Bs[buf][2048 + ldst]);
  };

  int i0loc = (wid >> 1) * 32;
  int j0loc = (wid & 1) * 64;
  int r = lane & 15;
  int s = (lane >> 4) * 8;

  f32x4 acc[2][4] = {};
  stage(0, 0);
  __syncthreads();
  int cur = 0;
#pragma unroll 2
  for (int ks = 0; ks < KN / 32; ++ks) {
    if (ks + 1 < KN / 32) stage(cur ^ 1, (ks + 1) * 32);
    bf16x8 a[2], bb[4];
#pragma unroll
    for (int m = 0; m < 2; ++m)
      a[m] = *reinterpret_cast<const bf16x8*>(&Hs[cur][(i0loc + m * 16 + r) * 32 + s]);
#pragma unroll
    for (int n = 0; n < 4; ++n)
      bb[n] = *reinterpret_cast<const bf16x8*>(&Bs[cur][(j0loc + n * 16 + r) * 32 + s]);
#pragma unroll
    for (int m = 0; m < 2; ++m)
#pragma unroll
      for (int n = 0; n < 4; ++n)
        acc[m][n] = __builtin_amdgcn_mfma_f32_16x16x32_bf16(a[m], bb[n], acc[m][n], 0, 0, 0);
    __syncthreads();
    cur ^= 1;
  }

  float(*buf)[65] = ep[wid];
  int orow = (lane >> 4) * 4;
  int ocol = lane & 15;
  int i0 = iB + i0loc;
  int j0 = jB + j0loc;
  float* ob = outp + (size_t)b * M * KN;
#pragma unroll
  for (int m = 0; m < 2; ++m) {
#pragma unroll
    for (int n = 0; n < 4; ++n)
#pragma unroll
      for (int rr = 0; rr < 4; ++rr) buf[orow + rr][n * 16 + ocol] = fmaxf(acc[m][n][rr], 0.0f);
#pragma unroll
    for (int rr = 0; rr < 4; ++rr) {
      int row = rr * 4 + (lane >> 4);
      float4 v4 = *(const float4*)&buf[row][(lane & 15) * 4];
      *(float4*)(ob + (size_t)(i0 + m * 16 + row) * KN + j0 + (lane & 15) * 4) = v4;
    }
  }
}

// ---------------- reductions ---------------------------------------------
__global__ void bag12_kernel(const float* __restrict__ emb1, const float* __restrict__ mTK,
                             const float* __restrict__ mTD, const float* __restrict__ imp,
                             float* __restrict__ bagk, float* __restrict__ bagd) {
  int c = blockIdx.x, b = blockIdx.y;
  int t = threadIdx.x;
  const float* e = emb1 + ((size_t)b * CMID + c) * KN;
  const float* ir = imp + (size_t)b * KN;
  const float* m1 = mTK + (size_t)b * KN;
  const float* m2 = mTD + (size_t)b * KN;
  float s1 = 0.0f, sd = 0.0f;
  for (int k = t; k < KN; k += 256) {
    float ev = e[k] * ir[k];
    s1 += ev * m1[k];
    sd += ev * m2[k];
  }
  __shared__ float r1[256], r2[256];
  r1[t] = s1;
  r2[t] = sd;
  __syncthreads();
  for (int st = 128; st > 0; st >>= 1) {
    if (t < st) {
      r1[t] += r1[t + st];
      r2[t] += r2[t + st];
    }
    __syncthreads();
  }
  if (t == 0) {
    bagk[(size_t)b * CMID + c] = r1[0] * INV_DS;
    bagd[(size_t)b * CMID + c] = r2[0] * INV_DS;
  }
}

__global__ void bag2_kernel(const float* __restrict__ s2, const float* __restrict__ mTK,
                            const float* __restrict__ imp, float* __restrict__ bag) {
  int o = blockIdx.x, b = blockIdx.y;
  int t = threadIdx.x;
  const float* sr = s2 + ((size_t)b * COUT + o) * KN;
  const float* ir = imp + (size_t)b * KN;
  const float* mr = mTK + (size_t)b * KN;
  float s = 0.0f;
  for (int k = t; k < KN; k += 256) s += sr[k] * mr[k] * ir[k];
  __shared__ float red[256];
  red[t] = s;
  __syncthreads();
  for (int st = 128; st > 0; st >>= 1) {
    if (t < st) red[t] += red[t + st];
    __syncthreads();
  }
  if (t == 0) bag[(size_t)b * COUT + o] = red[0];
}

__global__ void pooled_kernel(const float* __restrict__ x, const float* __restrict__ imp,
                              float* __restrict__ pooled) {
  int c = blockIdx.x, b = blockIdx.y;
  int t = threadIdx.x;
  const float* xr = x + ((size_t)b * CIN + c) * KN;
  const float* ir = imp + (size_t)b * KN;
  float s = 0.0f;
  for (int k = t; k < KN; k += 256) s += xr[k] * ir[k];
  __shared__ float red[256];
  red[t] = s;
  __syncthreads();
  for (int st = 128; st > 0; st >>= 1) {
    if (t < st) red[t] += red[t + st];
    __syncthreads();
  }
  if (t == 0) pooled[(size_t)b * CIN + c] = red[0];
}

__global__ void final_kernel(const float* __restrict__ pooled, const float* __restrict__ bag,
                             const float* __restrict__ id_w, const float* __restrict__ id_b,
                             const float* __restrict__ fc_w, float* __restrict__ out) {
  int b = blockIdx.x;
  int o = threadIdx.x;
  __shared__ float v[COUT];
  float s = id_b[o];
  const float* pr = pooled + (size_t)b * CIN;
  for (int c = 0; c < CIN; ++c) s += pr[c] * id_w[(size_t)c * COUT + o];
  v[o] = bag[(size_t)b * COUT + o] + fmaxf(s, 0.0f);
  __syncthreads();
  if (o < NCLS) {
    float acc = 0.0f;
    for (int oo = 0; oo < COUT; ++oo) acc += v[oo] * fc_w[(size_t)oo * NCLS + o];
    out[(size_t)b * NCLS + o] = acc;
  }
}

// ---------------- launch --------------------------------------------------
extern "C" void kernel_launch(void* const* d_in, const int* in_sizes, int n_in,
                              void* d_out, int out_size, void* d_ws, size_t ws_size,
                              hipStream_t stream) {
  const float* x = (const float*)d_in[0];
  const float* imp = (const float*)d_in[1];
  const float* rnd = (const float*)d_in[2];
  const float* W1 = (const float*)d_in[3];
  const float* W2 = (const float*)d_in[4];
  const float* fc_w = (const float*)d_in[5];
  const float* id_w = (const float*)d_in[6];
  const float* id_b = (const float*)d_in[7];
  float* out = (float*)d_out;
  float* emb1 = out + BN_ * NCLS;
  float* bagk = emb1 + (size_t)BN_ * CMID * KN;
  float* bagd = bagk + (size_t)BN_ * CMID;

  float* w = (float*)d_ws;
  size_t off = 0;
  auto take = [&](size_t n) {
    float* p = w + off;
    off += n;
    return p;
  };
  float* invSumP = take((size_t)BN_ * KN);
  float* invNX = take((size_t)BN_ * KN);
  float* invNE = take((size_t)BN_ * KN);
  float* topM = take((size_t)BN_ * KN);
  float* mTK = take((size_t)BN_ * KN);
  float* mTD = take((size_t)BN_ * KN);
  float* bag = take((size_t)BN_ * COUT);
  float* pooled = take((size_t)BN_ * CIN);

  // Lifetime-aliased union region: layer-1 {xnT, h} dies before layer-2
  // {enT, h2, s2} is born (colnorm<CMID> runs after the layer-1 loop).
  const size_t xnT_f = (size_t)BN_ * CIN * KN / 2;   // xnT as floats
  const size_t h_f = (size_t)BN_ * CMID * KN / 2;    // h as floats
  const size_t enT_f = (size_t)BN_ * CMID * KN / 2;  // enT as floats
  const size_t h2_f = (size_t)BN_ * COUT * KN / 2;   // h2 as floats
  const size_t s2_f = (size_t)BN_ * COUT * KN;       // s2 floats
  size_t uA = xnT_f + h_f;
  size_t uB = enT_f + h2_f + s2_f;
  float* U = take(uA > uB ? uA : uB);
  ushort* xnT = (ushort*)U;
  ushort* h = (ushort*)(U + xnT_f);
  ushort* enT = (ushort*)U;
  ushort* h2 = (ushort*)(U + enT_f);
  float* s2 = U + enT_f + h2_f;

  long long avail = (long long)(ws_size / 4) - (long long)off;
  int nb = 1;
  const int cands[6] = {32, 16, 8, 4, 2, 1};
  for (int ci = 0; ci < 6; ++ci) {
    if ((long long)cands[ci] * KN * KN <= avail) {
      nb = cands[ci];
      break;
    }
  }
  float* simA = take((size_t)nb * KN * KN);

  masks1_kernel<<<dim3(KN / 256, BN_), 256, 0, stream>>>(imp, topM);
  masks2_kernel<<<dim3(KN / 256, BN_), 256, 0, stream>>>(rnd, topM, mTK, mTD);
  psum_kernel<<<dim3(KN / 256, BN_), 256, 0, stream>>>(imp, invSumP);
  colnorm_kernel<CIN><<<(BN_ * KN) / 256, 256, 0, stream>>>(x, invNX);
  xpose_kernel<CIN><<<dim3(KN / 64, CIN / 64, BN_), 256, 0, stream>>>(x, invNX,
                                                                      (__hip_bfloat16*)xnT);
  linear_kernel<CIN, CMID, false><<<(CMID / 8) * BN_, 256, 0, stream>>>(x, W1, h, nullptr);

  for (int bs = 0; bs < BN_; bs += nb) {
    simf_kernel<CIN><<<nb * 64, 256, 0, stream>>>(xnT, simA, bs, nb);
    thrfin_kernel<<<dim3(KN / 4, nb), 256, 0, stream>>>(simA, imp, invSumP, bs);
    at_kernel<<<dim3(KN / 64, KN / 64, nb), 256, 0, stream>>>(simA);
    sgemmf_kernel<CMID><<<dim3(KN / 128, CMID / 64, nb), 256, 0, stream>>>(h, simA, emb1, bs);
  }

  colnorm_kernel<CMID><<<(BN_ * KN) / 256, 256, 0, stream>>>(emb1, invNE);
  xpose_kernel<CMID><<<dim3(KN / 64, CMID / 64, BN_), 256, 0, stream>>>(emb1, invNE,
                                                                        (__hip_bfloat16*)enT);
  linear_kernel<CMID, COUT, true><<<(COUT / 8) * BN_, 256, 0, stream>>>(emb1, W2, h2, mTK);

  for (int bs = 0; bs < BN_; bs += nb) {
    simf_kernel<CMID><<<nb * 64, 256, 0, stream>>>(enT, simA, bs, nb);
    thrfin_kernel<<<dim3(KN / 4, nb), 256, 0, stream>>>(simA, imp, invSumP, bs);
    at_kernel<<<dim3(KN / 64, KN / 64, nb), 256, 0, stream>>>(simA);
    sgemmf_kernel<COUT><<<dim3(KN / 128, COUT / 64, nb), 256, 0, stream>>>(h2, simA, s2, bs);
  }

  bag12_kernel<<<dim3(CMID, BN_), 256, 0, stream>>>(emb1, mTK, mTD, imp, bagk, bagd);
  bag2_kernel<<<dim3(COUT, BN_), 256, 0, stream>>>(s2, mTK, imp, bag);
  pooled_kernel<<<dim3(CIN, BN_), 256, 0, stream>>>(x, imp, pooled);
  final_kernel<<<BN_, 64, 0, stream>>>(pooled, bag, id_w, id_b, fc_w, out);
}

// Round 19
// 595.765 us; speedup vs baseline: 1.1134x; 1.0110x over previous
//
#include <hip/hip_runtime.h>
#include <hip/hip_bf16.h>
#include <math.h>

#define BN_ 32
#define CIN 512
#define KN 1024
#define CMID 128
#define COUT 64
#define NCLS 5
#define NUM_TOP 205
#define NUM_KEPT 409
#define NUM_DROP 410
#define ADJ_KK 204
#define EPSF 1e-8f
#define INV_DS (1.0f / 0.599609375f)

typedef __bf16 bf16x8 __attribute__((ext_vector_type(8)));
typedef float f32x4 __attribute__((ext_vector_type(4)));

__device__ inline ushort f2bf(float x) {
  union { __hip_bfloat16 b; ushort u; } c;
  c.b = __float2bfloat16(x);
  return c.u;
}

// async global->LDS, 16B per lane (dest = wave-uniform base + lane*16)
__device__ inline void gll16(const ushort* g, ushort* l) {
  __builtin_amdgcn_global_load_lds(
      (const __attribute__((address_space(1))) unsigned int*)g,
      (__attribute__((address_space(3))) unsigned int*)l, 16, 0, 0);
}

// ---------------- masks stage 1: top mask via rank counting --------------
__global__ __launch_bounds__(256) void masks1_kernel(const float* __restrict__ imp,
                                                     float* __restrict__ topM) {
  int b = blockIdx.y;
  int i = blockIdx.x * 256 + threadIdx.x;
  __shared__ float im[KN];
  for (int j = threadIdx.x; j < KN; j += 256) im[j] = imp[(size_t)b * KN + j];
  __syncthreads();
  float vi = im[i];
  int r0 = 0, r1 = 0, r2 = 0, r3 = 0;
  for (int j = 0; j < KN; j += 4) {
    float a0 = im[j], a1 = im[j + 1], a2 = im[j + 2], a3 = im[j + 3];
    r0 += (a0 > vi || (a0 == vi && j < i)) ? 1 : 0;
    r1 += (a1 > vi || (a1 == vi && j + 1 < i)) ? 1 : 0;
    r2 += (a2 > vi || (a2 == vi && j + 2 < i)) ? 1 : 0;
    r3 += (a3 > vi || (a3 == vi && j + 3 < i)) ? 1 : 0;
  }
  int rank = r0 + r1 + r2 + r3;
  topM[(size_t)b * KN + i] = (rank < NUM_TOP) ? 1.0f : 0.0f;
}

// ---------------- masks stage 2: kept/drop ranks, fused ------------------
__global__ __launch_bounds__(256) void masks2_kernel(const float* __restrict__ rnd,
                                                     const float* __restrict__ topM,
                                                     float* __restrict__ mTK,
                                                     float* __restrict__ mTD) {
  int b = blockIdx.y;
  int i = blockIdx.x * 256 + threadIdx.x;
  __shared__ float r1s[KN];
  __shared__ float r2s[KN];
  for (int j = threadIdx.x; j < KN; j += 256) {
    float tv = topM[(size_t)b * KN + j];
    float rv = rnd[(size_t)b * KN + j];
    r1s[j] = (tv > 0.5f) ? -10.0f : rv;
    r2s[j] = (tv > 0.5f) ? 10.0f : rv;
  }
  __syncthreads();
  float v1 = r1s[i];
  float v2 = r2s[i];
  int c1a = 0, c1b = 0, c2a = 0, c2b = 0;
  for (int j = 0; j < KN; j += 2) {
    float a0 = r1s[j], a1 = r1s[j + 1];
    float b0 = r2s[j], b1 = r2s[j + 1];
    c1a += (a0 > v1 || (a0 == v1 && j < i)) ? 1 : 0;
    c1b += (a1 > v1 || (a1 == v1 && j + 1 < i)) ? 1 : 0;
    c2a += (b0 < v2 || (b0 == v2 && j < i)) ? 1 : 0;
    c2b += (b1 < v2 || (b1 == v2 && j + 1 < i)) ? 1 : 0;
  }
  int kept = (c1a + c1b) < NUM_KEPT;
  int drop = (c2a + c2b) < NUM_DROP;
  int top = topM[(size_t)b * KN + i] > 0.5f;
  mTK[(size_t)b * KN + i] = (top || kept) ? 1.0f : 0.0f;
  mTD[(size_t)b * KN + i] = (top || drop) ? 1.0f : 0.0f;
}

// ---------------- adjP row-sum reciprocals -------------------------------
__global__ void psum_kernel(const float* __restrict__ imp, float* __restrict__ invSumP) {
  int b = blockIdx.y;
  int i = blockIdx.x * 256 + threadIdx.x;
  __shared__ float im[KN];
  for (int j = threadIdx.x; j < KN; j += 256) im[j] = imp[(size_t)b * KN + j];
  __syncthreads();
  float vi = im[i];
  float s = 0.0f;
  for (int j = 0; j < KN; ++j) {
    float d = vi - im[j];
    s += __expf(-d * d * 0.125f);
  }
  invSumP[(size_t)b * KN + i] = 1.0f / (s + 1.0f + EPSF);
}

// ---------------- per-column L2 norm reciprocals -------------------------
template <int C>
__global__ void colnorm_kernel(const float* __restrict__ f, float* __restrict__ inv) {
  int idx = blockIdx.x * 256 + threadIdx.x;
  int b = idx >> 10;
  int k = idx & (KN - 1);
  const float* fb = f + (size_t)b * C * KN + k;
  float ss = 0.0f;
  for (int c = 0; c < C; ++c) {
    float v = fb[(size_t)c * KN];
    ss += v * v;
  }
  inv[idx] = 1.0f / (sqrtf(ss) + EPSF);
}

// ------- transpose+normalize+bf16 into GROUP-LOCAL buffer ---------------
// oT[brel][k][c] = f[bstart+brel][c][k] * inv[bstart+brel][k]
template <int C>
__global__ void xpose_kernel(const float* __restrict__ f, const float* __restrict__ inv,
                             __hip_bfloat16* __restrict__ oT, int bstart) {
  int brel = blockIdx.z;
  int b = bstart + brel;
  int k0 = blockIdx.x * 64;
  int c0 = blockIdx.y * 64;
  __shared__ float t[64][65];
  const float* fb = f + (size_t)b * C * KN;
  int tx = threadIdx.x & 63;
  int ty = threadIdx.x >> 6;
  for (int r = 0; r < 64; r += 4) t[r + ty][tx] = fb[(size_t)(c0 + r + ty) * KN + k0 + tx];
  __syncthreads();
  __hip_bfloat16* ob = oT + (size_t)brel * KN * C;
  for (int r = 0; r < 64; r += 4) {
    int k = r + ty;
    float s = inv[(size_t)b * KN + k0 + k];
    ob[(size_t)(k0 + k) * C + c0 + tx] = __float2bfloat16(t[tx][k] * s);
  }
}

// ---------------- MFMA sim: sim = XnT * XnT^T (Gram, symmetric) ----------
// xT is group-local (indexed by brel).
template <int C>
__global__ __launch_bounds__(256) void simf_kernel(const ushort* __restrict__ xT,
                                                   float* __restrict__ sim, int nb) {
  int f = blockIdx.x;
  int brel, tile;
  if ((nb & 7) == 0) {
    int xcd = f & 7;
    int wdx = f >> 3;
    brel = xcd * (nb >> 3) + (wdx >> 6);
    tile = wdx & 63;
  } else {
    brel = f >> 6;
    tile = f & 63;
  }
  int t = threadIdx.x;
  int lane = t & 63;
  int wid = t >> 6;
  int iB = (tile >> 3) * 128;
  int jB = (tile & 7) * 128;
  const ushort* X = xT + (size_t)brel * KN * C;

  __shared__ ushort As[2][128 * 32];
  __shared__ ushort Bs[2][128 * 32];
  __shared__ float ep[4][16][65];

  int srow = t >> 2;
  int scol = (t & 3) * 8;
  int ldst = t * 8;

  auto stage = [&](int buf, int c0) {
    gll16(X + (size_t)(iB + srow) * C + c0 + scol, &As[buf][ldst]);
    gll16(X + (size_t)(iB + 64 + srow) * C + c0 + scol, &As[buf][2048 + ldst]);
    gll16(X + (size_t)(jB + srow) * C + c0 + scol, &Bs[buf][ldst]);
    gll16(X + (size_t)(jB + 64 + srow) * C + c0 + scol, &Bs[buf][2048 + ldst]);
  };

  int i0loc = (wid >> 1) * 64;
  int j0loc = (wid & 1) * 64;
  int r = lane & 15;
  int s = (lane >> 4) * 8;

  f32x4 acc[4][4] = {};
  stage(0, 0);
  __syncthreads();
  constexpr int NT = C / 32;
  int cur = 0;
#pragma unroll 2
  for (int ks = 0; ks < NT; ++ks) {
    if (ks + 1 < NT) stage(cur ^ 1, (ks + 1) * 32);
    bf16x8 a[4], bb[4];
#pragma unroll
    for (int m = 0; m < 4; ++m)
      a[m] = *reinterpret_cast<const bf16x8*>(&As[cur][(i0loc + m * 16 + r) * 32 + s]);
#pragma unroll
    for (int n = 0; n < 4; ++n)
      bb[n] = *reinterpret_cast<const bf16x8*>(&Bs[cur][(j0loc + n * 16 + r) * 32 + s]);
#pragma unroll
    for (int m = 0; m < 4; ++m)
#pragma unroll
      for (int n = 0; n < 4; ++n)
        acc[m][n] = __builtin_amdgcn_mfma_f32_16x16x32_bf16(a[m], bb[n], acc[m][n], 0, 0, 0);
    __syncthreads();
    cur ^= 1;
  }

  float(*buf)[65] = ep[wid];
  int orow = (lane >> 4) * 4;
  int ocol = lane & 15;
  int i0 = iB + i0loc;
  int j0 = jB + j0loc;
  float* simb = sim + (size_t)brel * KN * KN;
#pragma unroll
  for (int m = 0; m < 4; ++m) {
#pragma unroll
    for (int n = 0; n < 4; ++n)
#pragma unroll
      for (int rr = 0; rr < 4; ++rr) buf[orow + rr][n * 16 + ocol] = acc[m][n][rr];
#pragma unroll
    for (int rr = 0; rr < 4; ++rr) {
      int row = rr * 4 + (lane >> 4);
      float4 v4 = *(const float4*)&buf[row][(lane & 15) * 4];
      *(float4*)(simb + (size_t)(i0 + m * 16 + row) * KN + j0 + (lane & 15) * 4) = v4;
    }
  }
}

// ------- fused per-wave threshold select + finalize ----------------------
__global__ __launch_bounds__(256) void thrfin_kernel(float* __restrict__ A,
                                                     const float* __restrict__ imp,
                                                     const float* __restrict__ invSumP,
                                                     int bstart) {
  int brel = blockIdx.y;
  int b = bstart + brel;
  int wid = threadIdx.x >> 6;
  int lane = threadIdx.x & 63;
  int i = blockIdx.x * 4 + wid;
  float* row = A + ((size_t)brel * KN + i) * KN;
  __shared__ float im[KN];
  ((float4*)im)[threadIdx.x] = ((const float4*)(imp + (size_t)b * KN))[threadIdx.x];
  __syncthreads();

  float4 v[4];
  unsigned key[16];
#pragma unroll
  for (int q = 0; q < 4; ++q) v[q] = ((const float4*)row)[lane + 64 * q];
#pragma unroll
  for (int q = 0; q < 4; ++q) {
    const float* pv = (const float*)&v[q];
#pragma unroll
    for (int e = 0; e < 4; ++e) {
      unsigned u = __float_as_uint(pv[e]);
      key[q * 4 + e] = (u & 0x80000000u) ? ~u : (u | 0x80000000u);
    }
  }
  unsigned tk = 0u;
#pragma unroll 1
  for (int bit = 31; bit >= 8; --bit) {
    unsigned cand = tk | (1u << bit);
    int c = 0;
#pragma unroll
    for (int e = 0; e < 8; ++e)
      c += (int)__popcll(__ballot(key[e] >= cand));
    int cl = 0;
#pragma unroll
    for (int e = 8; e < 16; ++e) cl += (key[e] >= cand) ? 1 : 0;
#pragma unroll
    for (int off = 32; off > 0; off >>= 1) cl += __shfl_xor(cl, off);
    c += cl;
    if (c >= ADJ_KK) tk = cand;
  }
  float m[16];
  float s = 0.0f;
#pragma unroll
  for (int q = 0; q < 4; ++q) {
    const float* pv = (const float*)&v[q];
#pragma unroll
    for (int e = 0; e < 4; ++e) {
      float mv = (key[q * 4 + e] >= tk) ? pv[e] : 0.0f;
      m[q * 4 + e] = mv;
      s += mv;
    }
  }
#pragma unroll
  for (int off = 32; off > 0; off >>= 1) s += __shfl_xor(s, off);
  float invF = 1.0f / (s + 1.0f + EPSF);
  float vi = im[i];
  float invP = invSumP[(size_t)b * KN + i];
  ushort* rowb = (ushort*)row;
#pragma unroll
  for (int q = 0; q < 4; ++q) {
    float4 iv = ((const float4*)im)[lane + 64 * q];
    const float* ip = (const float*)&iv;
    ushort4 r;
    ushort* rp = (ushort*)&r;
    int colb = 4 * lane + 256 * q;
#pragma unroll
    for (int e = 0; e < 4; ++e) {
      float diag = (colb + e == i) ? 1.0f : 0.0f;
      float d = vi - ip[e];
      rp[e] = f2bf((m[q * 4 + e] + diag) * invF + (__expf(-d * d * 0.125f) + diag) * invP);
    }
    ((ushort4*)rowb)[lane + 64 * q] = r;
  }
}

// ------- bf16 transpose INTO sim rows' back halves -----------------------
__global__ __launch_bounds__(256) void at_kernel(float* __restrict__ Asim) {
  int brel = blockIdx.z;
  int k0 = blockIdx.x * 64;
  int j0 = blockIdx.y * 64;
  __shared__ ushort t[64][68];
  ushort* Ab = (ushort*)(Asim + (size_t)brel * KN * KN);
  int g = threadIdx.x & 15;
  int r = threadIdx.x >> 4;
#pragma unroll
  for (int p = 0; p < 4; ++p) {
    int row = p * 16 + r;
    *(ushort4*)&t[row][g * 4] =
        *(const ushort4*)&Ab[(size_t)(k0 + row) * 2048 + j0 + g * 4];
  }
  __syncthreads();
#pragma unroll
  for (int p = 0; p < 4; ++p) {
    int j = p * 16 + r;
    ushort4 v;
    v.x = t[g * 4 + 0][j];
    v.y = t[g * 4 + 1][j];
    v.z = t[g * 4 + 2][j];
    v.w = t[g * 4 + 3][j];
    *(ushort4*)&Ab[(size_t)(j0 + j) * 2048 + 1024 + k0 + g * 4] = v;
  }
}

// ---------------- per-node linear: h[b,o,k] = sum_c f[b,c,k] W[c,o] (bf16 out)
template <int C, int M, bool MASK>
__global__ __launch_bounds__(256) void linear_kernel(const float* __restrict__ f,
                                                     const float* __restrict__ W,
                                                     ushort* __restrict__ outp,
                                                     const float* __restrict__ mTK) {
  int fl = blockIdx.x;
  int b = fl & 31;
  int o0 = (fl >> 5) * 8;
  __shared__ float Ws[C][8];
  for (int l = threadIdx.x; l < C * 8; l += 256) {
    int c = l >> 3, o = l & 7;
    Ws[c][o] = W[(size_t)c * M + o0 + o];
  }
  __syncthreads();
  int k0 = threadIdx.x * 4;
  const float* fb = f + (size_t)b * C * KN;
  float acc[8][4] = {};
  for (int c = 0; c < C; ++c) {
    float4 xv = *(const float4*)(fb + (size_t)c * KN + k0);
#pragma unroll
    for (int o = 0; o < 8; ++o) {
      float w = Ws[c][o];
      acc[o][0] += xv.x * w;
      acc[o][1] += xv.y * w;
      acc[o][2] += xv.z * w;
      acc[o][3] += xv.w * w;
    }
  }
  float ms[4] = {1.0f, 1.0f, 1.0f, 1.0f};
  if (MASK) {
#pragma unroll
    for (int jj = 0; jj < 4; ++jj) ms[jj] = mTK[(size_t)b * KN + k0 + jj] * INV_DS;
  }
#pragma unroll
  for (int o = 0; o < 8; ++o) {
    ushort4 r;
    r.x = f2bf(acc[o][0] * ms[0]);
    r.y = f2bf(acc[o][1] * ms[1]);
    r.z = f2bf(acc[o][2] * ms[2]);
    r.w = f2bf(acc[o][3] * ms[3]);
    *(ushort4*)(outp + ((size_t)b * M + o0 + o) * KN + k0) = r;
  }
}

// ---------------- MFMA s = relu(h @ A), At read from sim back halves -----
template <int M>
__global__ __launch_bounds__(256) void sgemmf_kernel(const ushort* __restrict__ hB,
                                                     const float* __restrict__ Asim,
                                                     float* __restrict__ outp, int bstart) {
  int brel = blockIdx.z;
  int b = bstart + brel;
  int t = threadIdx.x;
  int lane = t & 63;
  int wid = t >> 6;
  int iB = blockIdx.y * 64;
  int jB = blockIdx.x * 128;
  const ushort* hb = hB + (size_t)b * M * KN;
  const ushort* Ab = (const ushort*)(Asim + (size_t)brel * KN * KN);

  __shared__ ushort Hs[2][64 * 32];
  __shared__ ushort Bs[2][128 * 32];
  __shared__ float ep[4][16][65];

  int srow = t >> 2;
  int scol = (t & 3) * 8;
  int ldst = t * 8;

  auto stage = [&](int buf, int k0) {
    gll16(hb + (size_t)(iB + srow) * KN + k0 + scol, &Hs[buf][ldst]);
    gll16(Ab + (size_t)(jB + srow) * 2048 + 1024 + k0 + scol, &Bs[buf][ldst]);
    gll16(Ab + (size_t)(jB + 64 + srow) * 2048 + 1024 + k0 + scol, &Bs[buf][2048 + ldst]);
  };

  int i0loc = (wid >> 1) * 32;
  int j0loc = (wid & 1) * 64;
  int r = lane & 15;
  int s = (lane >> 4) * 8;

  f32x4 acc[2][4] = {};
  stage(0, 0);
  __syncthreads();
  int cur = 0;
#pragma unroll 2
  for (int ks = 0; ks < KN / 32; ++ks) {
    if (ks + 1 < KN / 32) stage(cur ^ 1, (ks + 1) * 32);
    bf16x8 a[2], bb[4];
#pragma unroll
    for (int m = 0; m < 2; ++m)
      a[m] = *reinterpret_cast<const bf16x8*>(&Hs[cur][(i0loc + m * 16 + r) * 32 + s]);
#pragma unroll
    for (int n = 0; n < 4; ++n)
      bb[n] = *reinterpret_cast<const bf16x8*>(&Bs[cur][(j0loc + n * 16 + r) * 32 + s]);
#pragma unroll
    for (int m = 0; m < 2; ++m)
#pragma unroll
      for (int n = 0; n < 4; ++n)
        acc[m][n] = __builtin_amdgcn_mfma_f32_16x16x32_bf16(a[m], bb[n], acc[m][n], 0, 0, 0);
    __syncthreads();
    cur ^= 1;
  }

  float(*buf)[65] = ep[wid];
  int orow = (lane >> 4) * 4;
  int ocol = lane & 15;
  int i0 = iB + i0loc;
  int j0 = jB + j0loc;
  float* ob = outp + (size_t)b * M * KN;
#pragma unroll
  for (int m = 0; m < 2; ++m) {
#pragma unroll
    for (int n = 0; n < 4; ++n)
#pragma unroll
      for (int rr = 0; rr < 4; ++rr) buf[orow + rr][n * 16 + ocol] = fmaxf(acc[m][n][rr], 0.0f);
#pragma unroll
    for (int rr = 0; rr < 4; ++rr) {
      int row = rr * 4 + (lane >> 4);
      float4 v4 = *(const float4*)&buf[row][(lane & 15) * 4];
      *(float4*)(ob + (size_t)(i0 + m * 16 + row) * KN + j0 + (lane & 15) * 4) = v4;
    }
  }
}

// ---------------- reductions ---------------------------------------------
__global__ void bag12_kernel(const float* __restrict__ emb1, const float* __restrict__ mTK,
                             const float* __restrict__ mTD, const float* __restrict__ imp,
                             float* __restrict__ bagk, float* __restrict__ bagd) {
  int c = blockIdx.x, b = blockIdx.y;
  int t = threadIdx.x;
  const float* e = emb1 + ((size_t)b * CMID + c) * KN;
  const float* ir = imp + (size_t)b * KN;
  const float* m1 = mTK + (size_t)b * KN;
  const float* m2 = mTD + (size_t)b * KN;
  float s1 = 0.0f, sd = 0.0f;
  for (int k = t; k < KN; k += 256) {
    float ev = e[k] * ir[k];
    s1 += ev * m1[k];
    sd += ev * m2[k];
  }
  __shared__ float r1[256], r2[256];
  r1[t] = s1;
  r2[t] = sd;
  __syncthreads();
  for (int st = 128; st > 0; st >>= 1) {
    if (t < st) {
      r1[t] += r1[t + st];
      r2[t] += r2[t + st];
    }
    __syncthreads();
  }
  if (t == 0) {
    bagk[(size_t)b * CMID + c] = r1[0] * INV_DS;
    bagd[(size_t)b * CMID + c] = r2[0] * INV_DS;
  }
}

__global__ void bag2_kernel(const float* __restrict__ s2, const float* __restrict__ mTK,
                            const float* __restrict__ imp, float* __restrict__ bag) {
  int o = blockIdx.x, b = blockIdx.y;
  int t = threadIdx.x;
  const float* sr = s2 + ((size_t)b * COUT + o) * KN;
  const float* ir = imp + (size_t)b * KN;
  const float* mr = mTK + (size_t)b * KN;
  float s = 0.0f;
  for (int k = t; k < KN; k += 256) s += sr[k] * mr[k] * ir[k];
  __shared__ float red[256];
  red[t] = s;
  __syncthreads();
  for (int st = 128; st > 0; st >>= 1) {
    if (t < st) red[t] += red[t + st];
    __syncthreads();
  }
  if (t == 0) bag[(size_t)b * COUT + o] = red[0];
}

__global__ void pooled_kernel(const float* __restrict__ x, const float* __restrict__ imp,
                              float* __restrict__ pooled) {
  int c = blockIdx.x, b = blockIdx.y;
  int t = threadIdx.x;
  const float* xr = x + ((size_t)b * CIN + c) * KN;
  const float* ir = imp + (size_t)b * KN;
  float s = 0.0f;
  for (int k = t; k < KN; k += 256) s += xr[k] * ir[k];
  __shared__ float red[256];
  red[t] = s;
  __syncthreads();
  for (int st = 128; st > 0; st >>= 1) {
    if (t < st) red[t] += red[t + st];
    __syncthreads();
  }
  if (t == 0) pooled[(size_t)b * CIN + c] = red[0];
}

__global__ void final_kernel(const float* __restrict__ pooled, const float* __restrict__ bag,
                             const float* __restrict__ id_w, const float* __restrict__ id_b,
                             const float* __restrict__ fc_w, float* __restrict__ out) {
  int b = blockIdx.x;
  int o = threadIdx.x;
  __shared__ float v[COUT];
  float s = id_b[o];
  const float* pr = pooled + (size_t)b * CIN;
  for (int c = 0; c < CIN; ++c) s += pr[c] * id_w[(size_t)c * COUT + o];
  v[o] = bag[(size_t)b * COUT + o] + fmaxf(s, 0.0f);
  __syncthreads();
  if (o < NCLS) {
    float acc = 0.0f;
    for (int oo = 0; oo < COUT; ++oo) acc += v[oo] * fc_w[(size_t)oo * NCLS + o];
    out[(size_t)b * NCLS + o] = acc;
  }
}

// ---------------- launch --------------------------------------------------
extern "C" void kernel_launch(void* const* d_in, const int* in_sizes, int n_in,
                              void* d_out, int out_size, void* d_ws, size_t ws_size,
                              hipStream_t stream) {
  const float* x = (const float*)d_in[0];
  const float* imp = (const float*)d_in[1];
  const float* rnd = (const float*)d_in[2];
  const float* W1 = (const float*)d_in[3];
  const float* W2 = (const float*)d_in[4];
  const float* fc_w = (const float*)d_in[5];
  const float* id_w = (const float*)d_in[6];
  const float* id_b = (const float*)d_in[7];
  float* out = (float*)d_out;
  float* emb1 = out + BN_ * NCLS;
  float* bagk = emb1 + (size_t)BN_ * CMID * KN;
  float* bagd = bagk + (size_t)BN_ * CMID;

  float* w = (float*)d_ws;
  size_t off = 0;
  auto take = [&](size_t n) {
    float* p = w + off;
    off += n;
    return p;
  };
  float* invSumP = take((size_t)BN_ * KN);
  float* invNX = take((size_t)BN_ * KN);
  float* invNE = take((size_t)BN_ * KN);
  float* topM = take((size_t)BN_ * KN);
  float* mTK = take((size_t)BN_ * KN);
  float* mTD = take((size_t)BN_ * KN);
  float* bag = take((size_t)BN_ * COUT);
  float* pooled = take((size_t)BN_ * CIN);

  const size_t h_f = (size_t)BN_ * CMID * KN / 2;
  const size_t h2_f = (size_t)BN_ * COUT * KN / 2;
  const size_t s2_f = (size_t)BN_ * COUT * KN;
  const size_t xg1 = (size_t)CIN * KN / 2;   // per-batch xnT floats
  const size_t eg1 = (size_t)CMID * KN / 2;  // per-batch enT floats

  // Pick largest nb whose total footprint fits.
  size_t budget = ws_size / 4;
  int nb = 1;
  const int cands[6] = {32, 16, 8, 4, 2, 1};
  for (int ci = 0; ci < 6; ++ci) {
    size_t c = cands[ci];
    size_t uA = h_f + c * xg1;
    size_t uB = h2_f + s2_f + c * eg1;
    size_t uMax = uA > uB ? uA : uB;
    if (off + uMax + c * (size_t)KN * KN <= budget) {
      nb = (int)c;
      break;
    }
  }
  size_t uA = h_f + (size_t)nb * xg1;
  size_t uB = h2_f + s2_f + (size_t)nb * eg1;
  float* U = take(uA > uB ? uA : uB);
  ushort* xnT = (ushort*)U;                       // nb*xg1 floats
  ushort* h = (ushort*)(U + (size_t)nb * xg1);    // h_f floats
  ushort* enT = (ushort*)U;                       // nb*eg1 floats
  ushort* h2 = (ushort*)(U + (size_t)nb * eg1);   // h2_f
  float* s2 = U + (size_t)nb * eg1 + h2_f;        // s2_f
  float* simA = take((size_t)nb * KN * KN);

  masks1_kernel<<<dim3(KN / 256, BN_), 256, 0, stream>>>(imp, topM);
  masks2_kernel<<<dim3(KN / 256, BN_), 256, 0, stream>>>(rnd, topM, mTK, mTD);
  psum_kernel<<<dim3(KN / 256, BN_), 256, 0, stream>>>(imp, invSumP);
  colnorm_kernel<CIN><<<(BN_ * KN) / 256, 256, 0, stream>>>(x, invNX);
  linear_kernel<CIN, CMID, false><<<(CMID / 8) * BN_, 256, 0, stream>>>(x, W1, h, nullptr);

  for (int bs = 0; bs < BN_; bs += nb) {
    xpose_kernel<CIN><<<dim3(KN / 64, CIN / 64, nb), 256, 0, stream>>>(
        x, invNX, (__hip_bfloat16*)xnT, bs);
    simf_kernel<CIN><<<nb * 64, 256, 0, stream>>>(xnT, simA, nb);
    thrfin_kernel<<<dim3(KN / 4, nb), 256, 0, stream>>>(simA, imp, invSumP, bs);
    at_kernel<<<dim3(KN / 64, KN / 64, nb), 256, 0, stream>>>(simA);
    sgemmf_kernel<CMID><<<dim3(KN / 128, CMID / 64, nb), 256, 0, stream>>>(h, simA, emb1, bs);
  }

  colnorm_kernel<CMID><<<(BN_ * KN) / 256, 256, 0, stream>>>(emb1, invNE);
  linear_kernel<CMID, COUT, true><<<(COUT / 8) * BN_, 256, 0, stream>>>(emb1, W2, h2, mTK);

  for (int bs = 0; bs < BN_; bs += nb) {
    xpose_kernel<CMID><<<dim3(KN / 64, CMID / 64, nb), 256, 0, stream>>>(
        emb1, invNE, (__hip_bfloat16*)enT, bs);
    simf_kernel<CMID><<<nb * 64, 256, 0, stream>>>(enT, simA, nb);
    thrfin_kernel<<<dim3(KN / 4, nb), 256, 0, stream>>>(simA, imp, invSumP, bs);
    at_kernel<<<dim3(KN / 64, KN / 64, nb), 256, 0, stream>>>(simA);
    sgemmf_kernel<COUT><<<dim3(KN / 128, COUT / 64, nb), 256, 0, stream>>>(h2, simA, s2, bs);
  }

  bag12_kernel<<<dim3(CMID, BN_), 256, 0, stream>>>(emb1, mTK, mTD, imp, bagk, bagd);
  bag2_kernel<<<dim3(COUT, BN_), 256, 0, stream>>>(s2, mTK, imp, bag);
  pooled_kernel<<<dim3(CIN, BN_), 256, 0, stream>>>(x, imp, pooled);
  final_kernel<<<BN_, 64, 0, stream>>>(pooled, bag, id_w, id_b, fc_w, out);
}

// Round 20
// 547.329 us; speedup vs baseline: 1.2120x; 1.0885x over previous
//
#include <hip/hip_runtime.h>
#include <hip/hip_bf16.h>
#include <math.h>

#define BN_ 32
#define CIN 512
#define KN 1024
#define CMID 128
#define COUT 64
#define NCLS 5
#define NUM_TOP 205
#define NUM_KEPT 409
#define NUM_DROP 410
#define ADJ_KK 204
#define EPSF 1e-8f
#define INV_DS (1.0f / 0.599609375f)

typedef __bf16 bf16x8 __attribute__((ext_vector_type(8)));
typedef float f32x4 __attribute__((ext_vector_type(4)));

__device__ inline ushort f2bf(float x) {
  union { __hip_bfloat16 b; ushort u; } c;
  c.b = __float2bfloat16(x);
  return c.u;
}

// async global->LDS, 16B per lane (dest = wave-uniform base + lane*16)
__device__ inline void gll16(const ushort* g, ushort* l) {
  __builtin_amdgcn_global_load_lds(
      (const __attribute__((address_space(1))) unsigned int*)g,
      (__attribute__((address_space(3))) unsigned int*)l, 16, 0, 0);
}

// ---------------- masks stage 1: top mask via rank counting --------------
__global__ __launch_bounds__(256) void masks1_kernel(const float* __restrict__ imp,
                                                     float* __restrict__ topM) {
  int b = blockIdx.y;
  int i = blockIdx.x * 256 + threadIdx.x;
  __shared__ float im[KN];
  for (int j = threadIdx.x; j < KN; j += 256) im[j] = imp[(size_t)b * KN + j];
  __syncthreads();
  float vi = im[i];
  int r0 = 0, r1 = 0, r2 = 0, r3 = 0;
  for (int j = 0; j < KN; j += 4) {
    float a0 = im[j], a1 = im[j + 1], a2 = im[j + 2], a3 = im[j + 3];
    r0 += (a0 > vi || (a0 == vi && j < i)) ? 1 : 0;
    r1 += (a1 > vi || (a1 == vi && j + 1 < i)) ? 1 : 0;
    r2 += (a2 > vi || (a2 == vi && j + 2 < i)) ? 1 : 0;
    r3 += (a3 > vi || (a3 == vi && j + 3 < i)) ? 1 : 0;
  }
  int rank = r0 + r1 + r2 + r3;
  topM[(size_t)b * KN + i] = (rank < NUM_TOP) ? 1.0f : 0.0f;
}

// ---------------- masks stage 2: kept/drop ranks, fused ------------------
__global__ __launch_bounds__(256) void masks2_kernel(const float* __restrict__ rnd,
                                                     const float* __restrict__ topM,
                                                     float* __restrict__ mTK,
                                                     float* __restrict__ mTD) {
  int b = blockIdx.y;
  int i = blockIdx.x * 256 + threadIdx.x;
  __shared__ float r1s[KN];
  __shared__ float r2s[KN];
  for (int j = threadIdx.x; j < KN; j += 256) {
    float tv = topM[(size_t)b * KN + j];
    float rv = rnd[(size_t)b * KN + j];
    r1s[j] = (tv > 0.5f) ? -10.0f : rv;
    r2s[j] = (tv > 0.5f) ? 10.0f : rv;
  }
  __syncthreads();
  float v1 = r1s[i];
  float v2 = r2s[i];
  int c1a = 0, c1b = 0, c2a = 0, c2b = 0;
  for (int j = 0; j < KN; j += 2) {
    float a0 = r1s[j], a1 = r1s[j + 1];
    float b0 = r2s[j], b1 = r2s[j + 1];
    c1a += (a0 > v1 || (a0 == v1 && j < i)) ? 1 : 0;
    c1b += (a1 > v1 || (a1 == v1 && j + 1 < i)) ? 1 : 0;
    c2a += (b0 < v2 || (b0 == v2 && j < i)) ? 1 : 0;
    c2b += (b1 < v2 || (b1 == v2 && j + 1 < i)) ? 1 : 0;
  }
  int kept = (c1a + c1b) < NUM_KEPT;
  int drop = (c2a + c2b) < NUM_DROP;
  int top = topM[(size_t)b * KN + i] > 0.5f;
  mTK[(size_t)b * KN + i] = (top || kept) ? 1.0f : 0.0f;
  mTD[(size_t)b * KN + i] = (top || drop) ? 1.0f : 0.0f;
}

// ---------------- adjP row-sum reciprocals -------------------------------
__global__ void psum_kernel(const float* __restrict__ imp, float* __restrict__ invSumP) {
  int b = blockIdx.y;
  int i = blockIdx.x * 256 + threadIdx.x;
  __shared__ float im[KN];
  for (int j = threadIdx.x; j < KN; j += 256) im[j] = imp[(size_t)b * KN + j];
  __syncthreads();
  float vi = im[i];
  float s = 0.0f;
  for (int j = 0; j < KN; ++j) {
    float d = vi - im[j];
    s += __expf(-d * d * 0.125f);
  }
  invSumP[(size_t)b * KN + i] = 1.0f / (s + 1.0f + EPSF);
}

// ---------------- per-column L2 norm: inv and nrm ------------------------
template <int C>
__global__ void colnorm_kernel(const float* __restrict__ f, float* __restrict__ inv,
                               float* __restrict__ nrm) {
  int idx = blockIdx.x * 256 + threadIdx.x;
  int b = idx >> 10;
  int k = idx & (KN - 1);
  const float* fb = f + (size_t)b * C * KN + k;
  float ss = 0.0f;
  for (int c = 0; c < C; ++c) {
    float v = fb[(size_t)c * KN];
    ss += v * v;
  }
  float n = sqrtf(ss) + EPSF;
  inv[idx] = 1.0f / n;
  nrm[idx] = n;
}

// ------- W1T[o][c] = bf16(W1[c][o]), one thread per element --------------
__global__ __launch_bounds__(256) void wtrans1_kernel(const float* __restrict__ W,
                                                      ushort* __restrict__ WT) {
  int idx = blockIdx.x * 256 + threadIdx.x;  // CMID*CIN total
  int o = idx >> 9;                          // / CIN
  int c = idx & (CIN - 1);
  WT[(size_t)o * CIN + c] = f2bf(W[(size_t)c * CMID + o]);
}

// ------- transpose+normalize+bf16 into GROUP-LOCAL buffer ---------------
template <int C>
__global__ void xpose_kernel(const float* __restrict__ f, const float* __restrict__ inv,
                             __hip_bfloat16* __restrict__ oT, int bstart) {
  int brel = blockIdx.z;
  int b = bstart + brel;
  int k0 = blockIdx.x * 64;
  int c0 = blockIdx.y * 64;
  __shared__ float t[64][65];
  const float* fb = f + (size_t)b * C * KN;
  int tx = threadIdx.x & 63;
  int ty = threadIdx.x >> 6;
  for (int r = 0; r < 64; r += 4) t[r + ty][tx] = fb[(size_t)(c0 + r + ty) * KN + k0 + tx];
  __syncthreads();
  __hip_bfloat16* ob = oT + (size_t)brel * KN * C;
  for (int r = 0; r < 64; r += 4) {
    int k = r + ty;
    float s = inv[(size_t)b * KN + k0 + k];
    ob[(size_t)(k0 + k) * C + c0 + tx] = __float2bfloat16(t[tx][k] * s);
  }
}

// ---------------- MFMA sim: sim = XnT * XnT^T (Gram, symmetric) ----------
template <int C>
__global__ __launch_bounds__(256) void simf_kernel(const ushort* __restrict__ xT,
                                                   float* __restrict__ sim, int nb) {
  int f = blockIdx.x;
  int brel, tile;
  if ((nb & 7) == 0) {
    int xcd = f & 7;
    int wdx = f >> 3;
    brel = xcd * (nb >> 3) + (wdx >> 6);
    tile = wdx & 63;
  } else {
    brel = f >> 6;
    tile = f & 63;
  }
  int t = threadIdx.x;
  int lane = t & 63;
  int wid = t >> 6;
  int iB = (tile >> 3) * 128;
  int jB = (tile & 7) * 128;
  const ushort* X = xT + (size_t)brel * KN * C;

  __shared__ ushort As[2][128 * 32];
  __shared__ ushort Bs[2][128 * 32];
  __shared__ float ep[4][16][65];

  int srow = t >> 2;
  int scol = (t & 3) * 8;
  int ldst = t * 8;

  auto stage = [&](int buf, int c0) {
    gll16(X + (size_t)(iB + srow) * C + c0 + scol, &As[buf][ldst]);
    gll16(X + (size_t)(iB + 64 + srow) * C + c0 + scol, &As[buf][2048 + ldst]);
    gll16(X + (size_t)(jB + srow) * C + c0 + scol, &Bs[buf][ldst]);
    gll16(X + (size_t)(jB + 64 + srow) * C + c0 + scol, &Bs[buf][2048 + ldst]);
  };

  int i0loc = (wid >> 1) * 64;
  int j0loc = (wid & 1) * 64;
  int r = lane & 15;
  int s = (lane >> 4) * 8;

  f32x4 acc[4][4] = {};
  stage(0, 0);
  __syncthreads();
  constexpr int NT = C / 32;
  int cur = 0;
#pragma unroll 2
  for (int ks = 0; ks < NT; ++ks) {
    if (ks + 1 < NT) stage(cur ^ 1, (ks + 1) * 32);
    bf16x8 a[4], bb[4];
#pragma unroll
    for (int m = 0; m < 4; ++m)
      a[m] = *reinterpret_cast<const bf16x8*>(&As[cur][(i0loc + m * 16 + r) * 32 + s]);
#pragma unroll
    for (int n = 0; n < 4; ++n)
      bb[n] = *reinterpret_cast<const bf16x8*>(&Bs[cur][(j0loc + n * 16 + r) * 32 + s]);
#pragma unroll
    for (int m = 0; m < 4; ++m)
#pragma unroll
      for (int n = 0; n < 4; ++n)
        acc[m][n] = __builtin_amdgcn_mfma_f32_16x16x32_bf16(a[m], bb[n], acc[m][n], 0, 0, 0);
    __syncthreads();
    cur ^= 1;
  }

  float(*buf)[65] = ep[wid];
  int orow = (lane >> 4) * 4;
  int ocol = lane & 15;
  int i0 = iB + i0loc;
  int j0 = jB + j0loc;
  float* simb = sim + (size_t)brel * KN * KN;
#pragma unroll
  for (int m = 0; m < 4; ++m) {
#pragma unroll
    for (int n = 0; n < 4; ++n)
#pragma unroll
      for (int rr = 0; rr < 4; ++rr) buf[orow + rr][n * 16 + ocol] = acc[m][n][rr];
#pragma unroll
    for (int rr = 0; rr < 4; ++rr) {
      int row = rr * 4 + (lane >> 4);
      float4 v4 = *(const float4*)&buf[row][(lane & 15) * 4];
      *(float4*)(simb + (size_t)(i0 + m * 16 + row) * KN + j0 + (lane & 15) * 4) = v4;
    }
  }
}

// ------- fused per-wave threshold select + finalize ----------------------
__global__ __launch_bounds__(256) void thrfin_kernel(float* __restrict__ A,
                                                     const float* __restrict__ imp,
                                                     const float* __restrict__ invSumP,
                                                     int bstart) {
  int brel = blockIdx.y;
  int b = bstart + brel;
  int wid = threadIdx.x >> 6;
  int lane = threadIdx.x & 63;
  int i = blockIdx.x * 4 + wid;
  float* row = A + ((size_t)brel * KN + i) * KN;
  __shared__ float im[KN];
  ((float4*)im)[threadIdx.x] = ((const float4*)(imp + (size_t)b * KN))[threadIdx.x];
  __syncthreads();

  float4 v[4];
  unsigned key[16];
#pragma unroll
  for (int q = 0; q < 4; ++q) v[q] = ((const float4*)row)[lane + 64 * q];
#pragma unroll
  for (int q = 0; q < 4; ++q) {
    const float* pv = (const float*)&v[q];
#pragma unroll
    for (int e = 0; e < 4; ++e) {
      unsigned u = __float_as_uint(pv[e]);
      key[q * 4 + e] = (u & 0x80000000u) ? ~u : (u | 0x80000000u);
    }
  }
  unsigned tk = 0u;
#pragma unroll 1
  for (int bit = 31; bit >= 8; --bit) {
    unsigned cand = tk | (1u << bit);
    int c = 0;
#pragma unroll
    for (int e = 0; e < 8; ++e)
      c += (int)__popcll(__ballot(key[e] >= cand));
    int cl = 0;
#pragma unroll
    for (int e = 8; e < 16; ++e) cl += (key[e] >= cand) ? 1 : 0;
#pragma unroll
    for (int off = 32; off > 0; off >>= 1) cl += __shfl_xor(cl, off);
    c += cl;
    if (c >= ADJ_KK) tk = cand;
  }
  float m[16];
  float s = 0.0f;
#pragma unroll
  for (int q = 0; q < 4; ++q) {
    const float* pv = (const float*)&v[q];
#pragma unroll
    for (int e = 0; e < 4; ++e) {
      float mv = (key[q * 4 + e] >= tk) ? pv[e] : 0.0f;
      m[q * 4 + e] = mv;
      s += mv;
    }
  }
#pragma unroll
  for (int off = 32; off > 0; off >>= 1) s += __shfl_xor(s, off);
  float invF = 1.0f / (s + 1.0f + EPSF);
  float vi = im[i];
  float invP = invSumP[(size_t)b * KN + i];
  ushort* rowb = (ushort*)row;
#pragma unroll
  for (int q = 0; q < 4; ++q) {
    float4 iv = ((const float4*)im)[lane + 64 * q];
    const float* ip = (const float*)&iv;
    ushort4 r;
    ushort* rp = (ushort*)&r;
    int colb = 4 * lane + 256 * q;
#pragma unroll
    for (int e = 0; e < 4; ++e) {
      float diag = (colb + e == i) ? 1.0f : 0.0f;
      float d = vi - ip[e];
      rp[e] = f2bf((m[q * 4 + e] + diag) * invF + (__expf(-d * d * 0.125f) + diag) * invP);
    }
    ((ushort4*)rowb)[lane + 64 * q] = r;
  }
}

// ------- bf16 transpose INTO sim rows' back halves -----------------------
__global__ __launch_bounds__(256) void at_kernel(float* __restrict__ Asim) {
  int brel = blockIdx.z;
  int k0 = blockIdx.x * 64;
  int j0 = blockIdx.y * 64;
  __shared__ ushort t[64][68];
  ushort* Ab = (ushort*)(Asim + (size_t)brel * KN * KN);
  int g = threadIdx.x & 15;
  int r = threadIdx.x >> 4;
#pragma unroll
  for (int p = 0; p < 4; ++p) {
    int row = p * 16 + r;
    *(ushort4*)&t[row][g * 4] =
        *(const ushort4*)&Ab[(size_t)(k0 + row) * 2048 + j0 + g * 4];
  }
  __syncthreads();
#pragma unroll
  for (int p = 0; p < 4; ++p) {
    int j = p * 16 + r;
    ushort4 v;
    v.x = t[g * 4 + 0][j];
    v.y = t[g * 4 + 1][j];
    v.z = t[g * 4 + 2][j];
    v.w = t[g * 4 + 3][j];
    *(ushort4*)&Ab[(size_t)(j0 + j) * 2048 + 1024 + k0 + g * 4] = v;
  }
}

// ---------------- MFMA layer-1 linear: h_g[brel,o,k] = nrm[k]*sum_c W1T[o,c]*xnT[k,c]
// Exact clone of sgemmf staging/compute; A-rows=W1T (stride CIN),
// B-rows=group-local xnT (stride CIN); epilogue scales by nrm, bf16 out.
__global__ __launch_bounds__(256) void linf1_kernel(const ushort* __restrict__ xg,
                                                    const ushort* __restrict__ WT,
                                                    const float* __restrict__ nrm,
                                                    ushort* __restrict__ hg, int bstart) {
  int brel = blockIdx.z;
  int b = bstart + brel;
  int t = threadIdx.x;
  int lane = t & 63;
  int wid = t >> 6;
  int iB = blockIdx.y * 64;
  int jB = blockIdx.x * 128;
  const ushort* xb = xg + (size_t)brel * KN * CIN;

  __shared__ ushort Hs[2][64 * 32];
  __shared__ ushort Bs[2][128 * 32];
  __shared__ float ep[4][16][65];

  int srow = t >> 2;
  int scol = (t & 3) * 8;
  int ldst = t * 8;

  auto stage = [&](int buf, int c0) {
    gll16(WT + (size_t)(iB + srow) * CIN + c0 + scol, &Hs[buf][ldst]);
    gll16(xb + (size_t)(jB + srow) * CIN + c0 + scol, &Bs[buf][ldst]);
    gll16(xb + (size_t)(jB + 64 + srow) * CIN + c0 + scol, &Bs[buf][2048 + ldst]);
  };

  int i0loc = (wid >> 1) * 32;
  int j0loc = (wid & 1) * 64;
  int r = lane & 15;
  int s = (lane >> 4) * 8;

  f32x4 acc[2][4] = {};
  stage(0, 0);
  __syncthreads();
  int cur = 0;
#pragma unroll 2
  for (int ks = 0; ks < CIN / 32; ++ks) {
    if (ks + 1 < CIN / 32) stage(cur ^ 1, (ks + 1) * 32);
    bf16x8 a[2], bb[4];
#pragma unroll
    for (int m = 0; m < 2; ++m)
      a[m] = *reinterpret_cast<const bf16x8*>(&Hs[cur][(i0loc + m * 16 + r) * 32 + s]);
#pragma unroll
    for (int n = 0; n < 4; ++n)
      bb[n] = *reinterpret_cast<const bf16x8*>(&Bs[cur][(j0loc + n * 16 + r) * 32 + s]);
#pragma unroll
    for (int m = 0; m < 2; ++m)
#pragma unroll
      for (int n = 0; n < 4; ++n)
        acc[m][n] = __builtin_amdgcn_mfma_f32_16x16x32_bf16(a[m], bb[n], acc[m][n], 0, 0, 0);
    __syncthreads();
    cur ^= 1;
  }

  float(*buf)[65] = ep[wid];
  int orow = (lane >> 4) * 4;
  int ocol = lane & 15;
  int i0 = iB + i0loc;
  int j0 = jB + j0loc;
#pragma unroll
  for (int m = 0; m < 2; ++m) {
#pragma unroll
    for (int n = 0; n < 4; ++n)
#pragma unroll
      for (int rr = 0; rr < 4; ++rr) buf[orow + rr][n * 16 + ocol] = acc[m][n][rr];
#pragma unroll
    for (int rr = 0; rr < 4; ++rr) {
      int row = rr * 4 + (lane >> 4);
      int kk = j0 + (lane & 15) * 4;
      float4 v4 = *(const float4*)&buf[row][(lane & 15) * 4];
      float4 nv = *(const float4*)(nrm + (size_t)b * KN + kk);
      ushort4 r4;
      r4.x = f2bf(v4.x * nv.x);
      r4.y = f2bf(v4.y * nv.y);
      r4.z = f2bf(v4.z * nv.z);
      r4.w = f2bf(v4.w * nv.w);
      *(ushort4*)(hg + ((size_t)brel * CMID + i0 + m * 16 + row) * KN + kk) = r4;
    }
  }
}

// ---------------- f32 per-node linear (layer 2 only, proven) -------------
template <int C, int M, bool MASK>
__global__ __launch_bounds__(256) void linear_kernel(const float* __restrict__ f,
                                                     const float* __restrict__ W,
                                                     ushort* __restrict__ outp,
                                                     const float* __restrict__ mTK) {
  int fl = blockIdx.x;
  int b = fl & 31;
  int o0 = (fl >> 5) * 8;
  __shared__ float Ws[C][8];
  for (int l = threadIdx.x; l < C * 8; l += 256) {
    int c = l >> 3, o = l & 7;
    Ws[c][o] = W[(size_t)c * M + o0 + o];
  }
  __syncthreads();
  int k0 = threadIdx.x * 4;
  const float* fb = f + (size_t)b * C * KN;
  float acc[8][4] = {};
  for (int c = 0; c < C; ++c) {
    float4 xv = *(const float4*)(fb + (size_t)c * KN + k0);
#pragma unroll
    for (int o = 0; o < 8; ++o) {
      float w = Ws[c][o];
      acc[o][0] += xv.x * w;
      acc[o][1] += xv.y * w;
      acc[o][2] += xv.z * w;
      acc[o][3] += xv.w * w;
    }
  }
  float ms[4] = {1.0f, 1.0f, 1.0f, 1.0f};
  if (MASK) {
#pragma unroll
    for (int jj = 0; jj < 4; ++jj) ms[jj] = mTK[(size_t)b * KN + k0 + jj] * INV_DS;
  }
#pragma unroll
  for (int o = 0; o < 8; ++o) {
    ushort4 r;
    r.x = f2bf(acc[o][0] * ms[0]);
    r.y = f2bf(acc[o][1] * ms[1]);
    r.z = f2bf(acc[o][2] * ms[2]);
    r.w = f2bf(acc[o][3] * ms[3]);
    *(ushort4*)(outp + ((size_t)b * M + o0 + o) * KN + k0) = r;
  }
}

// ---------------- MFMA s = relu(h @ A), At read from sim back halves -----
// LOCAL: h indexed by brel (group-local); else by global b.
template <int M, bool LOCAL>
__global__ __launch_bounds__(256) void sgemmf_kernel(const ushort* __restrict__ hB,
                                                     const float* __restrict__ Asim,
                                                     float* __restrict__ outp, int bstart) {
  int brel = blockIdx.z;
  int b = bstart + brel;
  int t = threadIdx.x;
  int lane = t & 63;
  int wid = t >> 6;
  int iB = blockIdx.y * 64;
  int jB = blockIdx.x * 128;
  const ushort* hb = hB + (size_t)(LOCAL ? brel : b) * M * KN;
  const ushort* Ab = (const ushort*)(Asim + (size_t)brel * KN * KN);

  __shared__ ushort Hs[2][64 * 32];
  __shared__ ushort Bs[2][128 * 32];
  __shared__ float ep[4][16][65];

  int srow = t >> 2;
  int scol = (t & 3) * 8;
  int ldst = t * 8;

  auto stage = [&](int buf, int k0) {
    gll16(hb + (size_t)(iB + srow) * KN + k0 + scol, &Hs[buf][ldst]);
    gll16(Ab + (size_t)(jB + srow) * 2048 + 1024 + k0 + scol, &Bs[buf][ldst]);
    gll16(Ab + (size_t)(jB + 64 + srow) * 2048 + 1024 + k0 + scol, &Bs[buf][2048 + ldst]);
  };

  int i0loc = (wid >> 1) * 32;
  int j0loc = (wid & 1) * 64;
  int r = lane & 15;
  int s = (lane >> 4) * 8;

  f32x4 acc[2][4] = {};
  stage(0, 0);
  __syncthreads();
  int cur = 0;
#pragma unroll 2
  for (int ks = 0; ks < KN / 32; ++ks) {
    if (ks + 1 < KN / 32) stage(cur ^ 1, (ks + 1) * 32);
    bf16x8 a[2], bb[4];
#pragma unroll
    for (int m = 0; m < 2; ++m)
      a[m] = *reinterpret_cast<const bf16x8*>(&Hs[cur][(i0loc + m * 16 + r) * 32 + s]);
#pragma unroll
    for (int n = 0; n < 4; ++n)
      bb[n] = *reinterpret_cast<const bf16x8*>(&Bs[cur][(j0loc + n * 16 + r) * 32 + s]);
#pragma unroll
    for (int m = 0; m < 2; ++m)
#pragma unroll
      for (int n = 0; n < 4; ++n)
        acc[m][n] = __builtin_amdgcn_mfma_f32_16x16x32_bf16(a[m], bb[n], acc[m][n], 0, 0, 0);
    __syncthreads();
    cur ^= 1;
  }

  float(*buf)[65] = ep[wid];
  int orow = (lane >> 4) * 4;
  int ocol = lane & 15;
  int i0 = iB + i0loc;
  int j0 = jB + j0loc;
  float* ob = outp + (size_t)b * M * KN;
#pragma unroll
  for (int m = 0; m < 2; ++m) {
#pragma unroll
    for (int n = 0; n < 4; ++n)
#pragma unroll
      for (int rr = 0; rr < 4; ++rr) buf[orow + rr][n * 16 + ocol] = fmaxf(acc[m][n][rr], 0.0f);
#pragma unroll
    for (int rr = 0; rr < 4; ++rr) {
      int row = rr * 4 + (lane >> 4);
      float4 v4 = *(const float4*)&buf[row][(lane & 15) * 4];
      *(float4*)(ob + (size_t)(i0 + m * 16 + row) * KN + j0 + (lane & 15) * 4) = v4;
    }
  }
}

// ---------------- reductions ---------------------------------------------
__global__ void bag12_kernel(const float* __restrict__ emb1, const float* __restrict__ mTK,
                             const float* __restrict__ mTD, const float* __restrict__ imp,
                             float* __restrict__ bagk, float* __restrict__ bagd) {
  int c = blockIdx.x, b = blockIdx.y;
  int t = threadIdx.x;
  const float* e = emb1 + ((size_t)b * CMID + c) * KN;
  const float* ir = imp + (size_t)b * KN;
  const float* m1 = mTK + (size_t)b * KN;
  const float* m2 = mTD + (size_t)b * KN;
  float s1 = 0.0f, sd = 0.0f;
  for (int k = t; k < KN; k += 256) {
    float ev = e[k] * ir[k];
    s1 += ev * m1[k];
    sd += ev * m2[k];
  }
  __shared__ float r1[256], r2[256];
  r1[t] = s1;
  r2[t] = sd;
  __syncthreads();
  for (int st = 128; st > 0; st >>= 1) {
    if (t < st) {
      r1[t] += r1[t + st];
      r2[t] += r2[t + st];
    }
    __syncthreads();
  }
  if (t == 0) {
    bagk[(size_t)b * CMID + c] = r1[0] * INV_DS;
    bagd[(size_t)b * CMID + c] = r2[0] * INV_DS;
  }
}

__global__ void bag2_kernel(const float* __restrict__ s2, const float* __restrict__ mTK,
                            const float* __restrict__ imp, float* __restrict__ bag) {
  int o = blockIdx.x, b = blockIdx.y;
  int t = threadIdx.x;
  const float* sr = s2 + ((size_t)b * COUT + o) * KN;
  const float* ir = imp + (size_t)b * KN;
  const float* mr = mTK + (size_t)b * KN;
  float s = 0.0f;
  for (int k = t; k < KN; k += 256) s += sr[k] * mr[k] * ir[k];
  __shared__ float red[256];
  red[t] = s;
  __syncthreads();
  for (int st = 128; st > 0; st >>= 1) {
    if (t < st) red[t] += red[t + st];
    __syncthreads();
  }
  if (t == 0) bag[(size_t)b * COUT + o] = red[0];
}

__global__ void pooled_kernel(const float* __restrict__ x, const float* __restrict__ imp,
                              float* __restrict__ pooled) {
  int c = blockIdx.x, b = blockIdx.y;
  int t = threadIdx.x;
  const float* xr = x + ((size_t)b * CIN + c) * KN;
  const float* ir = imp + (size_t)b * KN;
  float s = 0.0f;
  for (int k = t; k < KN; k += 256) s += xr[k] * ir[k];
  __shared__ float red[256];
  red[t] = s;
  __syncthreads();
  for (int st = 128; st > 0; st >>= 1) {
    if (t < st) red[t] += red[t + st];
    __syncthreads();
  }
  if (t == 0) pooled[(size_t)b * CIN + c] = red[0];
}

__global__ void final_kernel(const float* __restrict__ pooled, const float* __restrict__ bag,
                             const float* __restrict__ id_w, const float* __restrict__ id_b,
                             const float* __restrict__ fc_w, float* __restrict__ out) {
  int b = blockIdx.x;
  int o = threadIdx.x;
  __shared__ float v[COUT];
  float s = id_b[o];
  const float* pr = pooled + (size_t)b * CIN;
  for (int c = 0; c < CIN; ++c) s += pr[c] * id_w[(size_t)c * COUT + o];
  v[o] = bag[(size_t)b * COUT + o] + fmaxf(s, 0.0f);
  __syncthreads();
  if (o < NCLS) {
    float acc = 0.0f;
    for (int oo = 0; oo < COUT; ++oo) acc += v[oo] * fc_w[(size_t)oo * NCLS + o];
    out[(size_t)b * NCLS + o] = acc;
  }
}

// ---------------- launch --------------------------------------------------
extern "C" void kernel_launch(void* const* d_in, const int* in_sizes, int n_in,
                              void* d_out, int out_size, void* d_ws, size_t ws_size,
                              hipStream_t stream) {
  const float* x = (const float*)d_in[0];
  const float* imp = (const float*)d_in[1];
  const float* rnd = (const float*)d_in[2];
  const float* W1 = (const float*)d_in[3];
  const float* W2 = (const float*)d_in[4];
  const float* fc_w = (const float*)d_in[5];
  const float* id_w = (const float*)d_in[6];
  const float* id_b = (const float*)d_in[7];
  float* out = (float*)d_out;
  float* emb1 = out + BN_ * NCLS;
  float* bagk = emb1 + (size_t)BN_ * CMID * KN;
  float* bagd = bagk + (size_t)BN_ * CMID;

  float* w = (float*)d_ws;
  size_t off = 0;
  auto take = [&](size_t n) {
    float* p = w + off;
    off += n;
    return p;
  };
  float* invSumP = take((size_t)BN_ * KN);
  float* invNX = take((size_t)BN_ * KN);
  float* invNE = take((size_t)BN_ * KN);
  float* nrmX = take((size_t)BN_ * KN);
  float* nrmE = take((size_t)BN_ * KN);
  float* topM = take((size_t)BN_ * KN);
  float* mTK = take((size_t)BN_ * KN);
  float* mTD = take((size_t)BN_ * KN);
  float* bag = take((size_t)BN_ * COUT);
  float* pooled = take((size_t)BN_ * CIN);
  ushort* W1T = (ushort*)take((size_t)CMID * CIN / 2);

  const size_t h2_f = (size_t)BN_ * COUT * KN / 2;
  const size_t s2_f = (size_t)BN_ * COUT * KN;
  const size_t xg1 = (size_t)CIN * KN / 2;   // per-batch xnT floats
  const size_t hg1 = (size_t)CMID * KN / 2;  // per-batch h floats
  const size_t eg1 = (size_t)CMID * KN / 2;  // per-batch enT floats

  size_t budget = ws_size / 4;
  int nb = 1;
  const int cands[6] = {32, 16, 8, 4, 2, 1};
  for (int ci = 0; ci < 6; ++ci) {
    size_t c = cands[ci];
    size_t uA = c * (xg1 + hg1);
    size_t uB = h2_f + s2_f + c * eg1;
    size_t uMax = uA > uB ? uA : uB;
    if (off + uMax + c * (size_t)KN * KN <= budget) {
      nb = (int)c;
      break;
    }
  }
  size_t uA = (size_t)nb * (xg1 + hg1);
  size_t uB = h2_f + s2_f + (size_t)nb * eg1;
  float* U = take(uA > uB ? uA : uB);
  ushort* xnT = (ushort*)U;                        // nb*xg1 floats
  ushort* h = (ushort*)(U + (size_t)nb * xg1);     // nb*hg1 floats (group-local)
  ushort* enT = (ushort*)U;                        // nb*eg1 floats
  ushort* h2 = (ushort*)(U + (size_t)nb * eg1);    // h2_f
  float* s2 = U + (size_t)nb * eg1 + h2_f;         // s2_f
  float* simA = take((size_t)nb * KN * KN);

  masks1_kernel<<<dim3(KN / 256, BN_), 256, 0, stream>>>(imp, topM);
  masks2_kernel<<<dim3(KN / 256, BN_), 256, 0, stream>>>(rnd, topM, mTK, mTD);
  psum_kernel<<<dim3(KN / 256, BN_), 256, 0, stream>>>(imp, invSumP);
  colnorm_kernel<CIN><<<(BN_ * KN) / 256, 256, 0, stream>>>(x, invNX, nrmX);
  wtrans1_kernel<<<(CMID * CIN) / 256, 256, 0, stream>>>(W1, W1T);

  for (int bs = 0; bs < BN_; bs += nb) {
    xpose_kernel<CIN><<<dim3(KN / 64, CIN / 64, nb), 256, 0, stream>>>(
        x, invNX, (__hip_bfloat16*)xnT, bs);
    linf1_kernel<<<dim3(KN / 128, CMID / 64, nb), 256, 0, stream>>>(xnT, W1T, nrmX, h, bs);
    simf_kernel<CIN><<<nb * 64, 256, 0, stream>>>(xnT, simA, nb);
    thrfin_kernel<<<dim3(KN / 4, nb), 256, 0, stream>>>(simA, imp, invSumP, bs);
    at_kernel<<<dim3(KN / 64, KN / 64, nb), 256, 0, stream>>>(simA);
    sgemmf_kernel<CMID, true><<<dim3(KN / 128, CMID / 64, nb), 256, 0, stream>>>(h, simA, emb1,
                                                                                 bs);
  }

  colnorm_kernel<CMID><<<(BN_ * KN) / 256, 256, 0, stream>>>(emb1, invNE, nrmE);
  linear_kernel<CMID, COUT, true><<<(COUT / 8) * BN_, 256, 0, stream>>>(emb1, W2, h2, mTK);

  for (int bs = 0; bs < BN_; bs += nb) {
    xpose_kernel<CMID><<<dim3(KN / 64, CMID / 64, nb), 256, 0, stream>>>(
        emb1, invNE, (__hip_bfloat16*)enT, bs);
    simf_kernel<CMID><<<nb * 64, 256, 0, stream>>>(enT, simA, nb);
    thrfin_kernel<<<dim3(KN / 4, nb), 256, 0, stream>>>(simA, imp, invSumP, bs);
    at_kernel<<<dim3(KN / 64, KN / 64, nb), 256, 0, stream>>>(simA);
    sgemmf_kernel<COUT, false><<<dim3(KN / 128, COUT / 64, nb), 256, 0, stream>>>(h2, simA, s2,
                                                                                  bs);
  }

  bag12_kernel<<<dim3(CMID, BN_), 256, 0, stream>>>(emb1, mTK, mTD, imp, bagk, bagd);
  bag2_kernel<<<dim3(COUT, BN_), 256, 0, stream>>>(s2, mTK, imp, bag);
  pooled_kernel<<<dim3(CIN, BN_), 256, 0, stream>>>(x, imp, pooled);
  final_kernel<<<BN_, 64, 0, stream>>>(pooled, bag, id_w, id_b, fc_w, out);
}

// Round 21
// 513.873 us; speedup vs baseline: 1.2909x; 1.0651x over previous
//
#include <hip/hip_runtime.h>
#include <hip/hip_bf16.h>
#include <math.h>

#define BN_ 32
#define CIN 512
#define KN 1024
#define CMID 128
#define COUT 64
#define NCLS 5
#define NUM_TOP 205
#define NUM_KEPT 409
#define NUM_DROP 410
#define ADJ_KK 204
#define EPSF 1e-8f
#define INV_DS (1.0f / 0.599609375f)

typedef __bf16 bf16x8 __attribute__((ext_vector_type(8)));
typedef float f32x4 __attribute__((ext_vector_type(4)));

__device__ inline ushort f2bf(float x) {
  union { __hip_bfloat16 b; ushort u; } c;
  c.b = __float2bfloat16(x);
  return c.u;
}

// async global->LDS, 16B per lane (dest = wave-uniform base + lane*16)
__device__ inline void gll16(const ushort* g, ushort* l) {
  __builtin_amdgcn_global_load_lds(
      (const __attribute__((address_space(1))) unsigned int*)g,
      (__attribute__((address_space(3))) unsigned int*)l, 16, 0, 0);
}

// ---------------- masks stage 1: top mask via rank counting --------------
__global__ __launch_bounds__(256) void masks1_kernel(const float* __restrict__ imp,
                                                     float* __restrict__ topM) {
  int b = blockIdx.y;
  int i = blockIdx.x * 256 + threadIdx.x;
  __shared__ float im[KN];
  for (int j = threadIdx.x; j < KN; j += 256) im[j] = imp[(size_t)b * KN + j];
  __syncthreads();
  float vi = im[i];
  int r0 = 0, r1 = 0, r2 = 0, r3 = 0;
  for (int j = 0; j < KN; j += 4) {
    float a0 = im[j], a1 = im[j + 1], a2 = im[j + 2], a3 = im[j + 3];
    r0 += (a0 > vi || (a0 == vi && j < i)) ? 1 : 0;
    r1 += (a1 > vi || (a1 == vi && j + 1 < i)) ? 1 : 0;
    r2 += (a2 > vi || (a2 == vi && j + 2 < i)) ? 1 : 0;
    r3 += (a3 > vi || (a3 == vi && j + 3 < i)) ? 1 : 0;
  }
  int rank = r0 + r1 + r2 + r3;
  topM[(size_t)b * KN + i] = (rank < NUM_TOP) ? 1.0f : 0.0f;
}

// ---------------- masks stage 2: kept/drop ranks, fused ------------------
__global__ __launch_bounds__(256) void masks2_kernel(const float* __restrict__ rnd,
                                                     const float* __restrict__ topM,
                                                     float* __restrict__ mTK,
                                                     float* __restrict__ mTD) {
  int b = blockIdx.y;
  int i = blockIdx.x * 256 + threadIdx.x;
  __shared__ float r1s[KN];
  __shared__ float r2s[KN];
  for (int j = threadIdx.x; j < KN; j += 256) {
    float tv = topM[(size_t)b * KN + j];
    float rv = rnd[(size_t)b * KN + j];
    r1s[j] = (tv > 0.5f) ? -10.0f : rv;
    r2s[j] = (tv > 0.5f) ? 10.0f : rv;
  }
  __syncthreads();
  float v1 = r1s[i];
  float v2 = r2s[i];
  int c1a = 0, c1b = 0, c2a = 0, c2b = 0;
  for (int j = 0; j < KN; j += 2) {
    float a0 = r1s[j], a1 = r1s[j + 1];
    float b0 = r2s[j], b1 = r2s[j + 1];
    c1a += (a0 > v1 || (a0 == v1 && j < i)) ? 1 : 0;
    c1b += (a1 > v1 || (a1 == v1 && j + 1 < i)) ? 1 : 0;
    c2a += (b0 < v2 || (b0 == v2 && j < i)) ? 1 : 0;
    c2b += (b1 < v2 || (b1 == v2 && j + 1 < i)) ? 1 : 0;
  }
  int kept = (c1a + c1b) < NUM_KEPT;
  int drop = (c2a + c2b) < NUM_DROP;
  int top = topM[(size_t)b * KN + i] > 0.5f;
  mTK[(size_t)b * KN + i] = (top || kept) ? 1.0f : 0.0f;
  mTD[(size_t)b * KN + i] = (top || drop) ? 1.0f : 0.0f;
}

// ---------------- adjP row-sum reciprocals -------------------------------
__global__ void psum_kernel(const float* __restrict__ imp, float* __restrict__ invSumP) {
  int b = blockIdx.y;
  int i = blockIdx.x * 256 + threadIdx.x;
  __shared__ float im[KN];
  for (int j = threadIdx.x; j < KN; j += 256) im[j] = imp[(size_t)b * KN + j];
  __syncthreads();
  float vi = im[i];
  float s = 0.0f;
  for (int j = 0; j < KN; ++j) {
    float d = vi - im[j];
    s += __expf(-d * d * 0.125f);
  }
  invSumP[(size_t)b * KN + i] = 1.0f / (s + 1.0f + EPSF);
}

// ---------------- per-column L2 norm: inv and nrm ------------------------
template <int C>
__global__ void colnorm_kernel(const float* __restrict__ f, float* __restrict__ inv,
                               float* __restrict__ nrm) {
  int idx = blockIdx.x * 256 + threadIdx.x;
  int b = idx >> 10;
  int k = idx & (KN - 1);
  const float* fb = f + (size_t)b * C * KN + k;
  float ss = 0.0f;
  for (int c = 0; c < C; ++c) {
    float v = fb[(size_t)c * KN];
    ss += v * v;
  }
  float n = sqrtf(ss) + EPSF;
  inv[idx] = 1.0f / n;
  nrm[idx] = n;
}

// ------- W1T[o][c] = bf16(W1[c][o]), one thread per element --------------
__global__ __launch_bounds__(256) void wtrans1_kernel(const float* __restrict__ W,
                                                      ushort* __restrict__ WT) {
  int idx = blockIdx.x * 256 + threadIdx.x;  // CMID*CIN total
  int o = idx >> 9;                          // / CIN
  int c = idx & (CIN - 1);
  WT[(size_t)o * CIN + c] = f2bf(W[(size_t)c * CMID + o]);
}

// ------- transpose+normalize+bf16 into GROUP-LOCAL buffer ---------------
template <int C>
__global__ void xpose_kernel(const float* __restrict__ f, const float* __restrict__ inv,
                             __hip_bfloat16* __restrict__ oT, int bstart) {
  int brel = blockIdx.z;
  int b = bstart + brel;
  int k0 = blockIdx.x * 64;
  int c0 = blockIdx.y * 64;
  __shared__ float t[64][65];
  const float* fb = f + (size_t)b * C * KN;
  int tx = threadIdx.x & 63;
  int ty = threadIdx.x >> 6;
  for (int r = 0; r < 64; r += 4) t[r + ty][tx] = fb[(size_t)(c0 + r + ty) * KN + k0 + tx];
  __syncthreads();
  __hip_bfloat16* ob = oT + (size_t)brel * KN * C;
  for (int r = 0; r < 64; r += 4) {
    int k = r + ty;
    float s = inv[(size_t)b * KN + k0 + k];
    ob[(size_t)(k0 + k) * C + c0 + tx] = __float2bfloat16(t[tx][k] * s);
  }
}

// ---------------- MFMA sim: sim = XnT * XnT^T, bf16 out ------------------
// sim rows are 2048 ushorts: bf16 sim in front 1024, At slot in back 1024.
template <int C>
__global__ __launch_bounds__(256) void simf_kernel(const ushort* __restrict__ xT,
                                                   float* __restrict__ sim, int nb) {
  int f = blockIdx.x;
  int brel, tile;
  if ((nb & 7) == 0) {
    int xcd = f & 7;
    int wdx = f >> 3;
    brel = xcd * (nb >> 3) + (wdx >> 6);
    tile = wdx & 63;
  } else {
    brel = f >> 6;
    tile = f & 63;
  }
  int t = threadIdx.x;
  int lane = t & 63;
  int wid = t >> 6;
  int iB = (tile >> 3) * 128;
  int jB = (tile & 7) * 128;
  const ushort* X = xT + (size_t)brel * KN * C;

  __shared__ ushort As[2][128 * 32];
  __shared__ ushort Bs[2][128 * 32];
  __shared__ float ep[4][16][65];

  int srow = t >> 2;
  int scol = (t & 3) * 8;
  int ldst = t * 8;

  auto stage = [&](int buf, int c0) {
    gll16(X + (size_t)(iB + srow) * C + c0 + scol, &As[buf][ldst]);
    gll16(X + (size_t)(iB + 64 + srow) * C + c0 + scol, &As[buf][2048 + ldst]);
    gll16(X + (size_t)(jB + srow) * C + c0 + scol, &Bs[buf][ldst]);
    gll16(X + (size_t)(jB + 64 + srow) * C + c0 + scol, &Bs[buf][2048 + ldst]);
  };

  int i0loc = (wid >> 1) * 64;
  int j0loc = (wid & 1) * 64;
  int r = lane & 15;
  int s = (lane >> 4) * 8;

  f32x4 acc[4][4] = {};
  stage(0, 0);
  __syncthreads();
  constexpr int NT = C / 32;
  int cur = 0;
#pragma unroll 2
  for (int ks = 0; ks < NT; ++ks) {
    if (ks + 1 < NT) stage(cur ^ 1, (ks + 1) * 32);
    bf16x8 a[4], bb[4];
#pragma unroll
    for (int m = 0; m < 4; ++m)
      a[m] = *reinterpret_cast<const bf16x8*>(&As[cur][(i0loc + m * 16 + r) * 32 + s]);
#pragma unroll
    for (int n = 0; n < 4; ++n)
      bb[n] = *reinterpret_cast<const bf16x8*>(&Bs[cur][(j0loc + n * 16 + r) * 32 + s]);
#pragma unroll
    for (int m = 0; m < 4; ++m)
#pragma unroll
      for (int n = 0; n < 4; ++n)
        acc[m][n] = __builtin_amdgcn_mfma_f32_16x16x32_bf16(a[m], bb[n], acc[m][n], 0, 0, 0);
    __syncthreads();
    cur ^= 1;
  }

  float(*buf)[65] = ep[wid];
  int orow = (lane >> 4) * 4;
  int ocol = lane & 15;
  int i0 = iB + i0loc;
  int j0 = jB + j0loc;
  ushort* simb = (ushort*)sim + (size_t)brel * KN * 2048;
#pragma unroll
  for (int m = 0; m < 4; ++m) {
#pragma unroll
    for (int n = 0; n < 4; ++n)
#pragma unroll
      for (int rr = 0; rr < 4; ++rr) buf[orow + rr][n * 16 + ocol] = acc[m][n][rr];
#pragma unroll
    for (int rr = 0; rr < 4; ++rr) {
      int row = rr * 4 + (lane >> 4);
      float4 v4 = *(const float4*)&buf[row][(lane & 15) * 4];
      ushort4 r4;
      r4.x = f2bf(v4.x);
      r4.y = f2bf(v4.y);
      r4.z = f2bf(v4.z);
      r4.w = f2bf(v4.w);
      *(ushort4*)(simb + (size_t)(i0 + m * 16 + row) * 2048 + j0 + (lane & 15) * 4) = r4;
    }
  }
}

// ------- fused per-wave threshold select + finalize (bf16 sim) -----------
// Exact 204th-largest in the bf16 domain: 16-step bisection on 16-bit
// monotone keys. Count split: 8 keys ballot+s_bcnt (SALU), 8 keys shfl.
__global__ __launch_bounds__(256) void thrfin_kernel(float* __restrict__ A,
                                                     const float* __restrict__ imp,
                                                     const float* __restrict__ invSumP,
                                                     int bstart) {
  int brel = blockIdx.y;
  int b = bstart + brel;
  int wid = threadIdx.x >> 6;
  int lane = threadIdx.x & 63;
  int i = blockIdx.x * 4 + wid;
  ushort* row = (ushort*)A + ((size_t)brel * KN + i) * 2048;
  __shared__ float im[KN];
  ((float4*)im)[threadIdx.x] = ((const float4*)(imp + (size_t)b * KN))[threadIdx.x];
  __syncthreads();

  ushort4 v[4];
  unsigned key[16];
#pragma unroll
  for (int q = 0; q < 4; ++q) v[q] = ((const ushort4*)row)[lane + 64 * q];
#pragma unroll
  for (int q = 0; q < 4; ++q) {
    const ushort* pv = (const ushort*)&v[q];
#pragma unroll
    for (int e = 0; e < 4; ++e) {
      ushort u = pv[e];
      key[q * 4 + e] = (u & 0x8000u) ? (unsigned)(ushort)~u : (unsigned)(u | 0x8000u);
    }
  }
  unsigned tk = 0u;
#pragma unroll 1
  for (int bit = 15; bit >= 0; --bit) {
    unsigned cand = tk | (1u << bit);
    int c = 0;
#pragma unroll
    for (int e = 0; e < 8; ++e)
      c += (int)__popcll(__ballot(key[e] >= cand));
    int cl = 0;
#pragma unroll
    for (int e = 8; e < 16; ++e) cl += (key[e] >= cand) ? 1 : 0;
#pragma unroll
    for (int off = 32; off > 0; off >>= 1) cl += __shfl_xor(cl, off);
    c += cl;
    if (c >= ADJ_KK) tk = cand;
  }
  float m[16];
  float s = 0.0f;
#pragma unroll
  for (int q = 0; q < 4; ++q) {
    const ushort* pv = (const ushort*)&v[q];
#pragma unroll
    for (int e = 0; e < 4; ++e) {
      float val = __uint_as_float(((unsigned)pv[e]) << 16);
      float mv = (key[q * 4 + e] >= tk) ? val : 0.0f;
      m[q * 4 + e] = mv;
      s += mv;
    }
  }
#pragma unroll
  for (int off = 32; off > 0; off >>= 1) s += __shfl_xor(s, off);
  float invF = 1.0f / (s + 1.0f + EPSF);
  float vi = im[i];
  float invP = invSumP[(size_t)b * KN + i];
#pragma unroll
  for (int q = 0; q < 4; ++q) {
    float4 iv = ((const float4*)im)[lane + 64 * q];
    const float* ip = (const float*)&iv;
    ushort4 r;
    ushort* rp = (ushort*)&r;
    int colb = 4 * lane + 256 * q;
#pragma unroll
    for (int e = 0; e < 4; ++e) {
      float diag = (colb + e == i) ? 1.0f : 0.0f;
      float d = vi - ip[e];
      rp[e] = f2bf((m[q * 4 + e] + diag) * invF + (__expf(-d * d * 0.125f) + diag) * invP);
    }
    ((ushort4*)row)[lane + 64 * q] = r;
  }
}

// ------- bf16 transpose INTO sim rows' back halves -----------------------
__global__ __launch_bounds__(256) void at_kernel(float* __restrict__ Asim) {
  int brel = blockIdx.z;
  int k0 = blockIdx.x * 64;
  int j0 = blockIdx.y * 64;
  __shared__ ushort t[64][68];
  ushort* Ab = (ushort*)(Asim + (size_t)brel * KN * KN);
  int g = threadIdx.x & 15;
  int r = threadIdx.x >> 4;
#pragma unroll
  for (int p = 0; p < 4; ++p) {
    int row = p * 16 + r;
    *(ushort4*)&t[row][g * 4] =
        *(const ushort4*)&Ab[(size_t)(k0 + row) * 2048 + j0 + g * 4];
  }
  __syncthreads();
#pragma unroll
  for (int p = 0; p < 4; ++p) {
    int j = p * 16 + r;
    ushort4 v;
    v.x = t[g * 4 + 0][j];
    v.y = t[g * 4 + 1][j];
    v.z = t[g * 4 + 2][j];
    v.w = t[g * 4 + 3][j];
    *(ushort4*)&Ab[(size_t)(j0 + j) * 2048 + 1024 + k0 + g * 4] = v;
  }
}

// ---------------- MFMA layer-1 linear: h_g[brel,o,k] = nrm[k]*sum_c W1T[o,c]*xnT[k,c]
__global__ __launch_bounds__(256) void linf1_kernel(const ushort* __restrict__ xg,
                                                    const ushort* __restrict__ WT,
                                                    const float* __restrict__ nrm,
                                                    ushort* __restrict__ hg, int bstart) {
  int brel = blockIdx.z;
  int b = bstart + brel;
  int t = threadIdx.x;
  int lane = t & 63;
  int wid = t >> 6;
  int iB = blockIdx.y * 64;
  int jB = blockIdx.x * 128;
  const ushort* xb = xg + (size_t)brel * KN * CIN;

  __shared__ ushort Hs[2][64 * 32];
  __shared__ ushort Bs[2][128 * 32];
  __shared__ float ep[4][16][65];

  int srow = t >> 2;
  int scol = (t & 3) * 8;
  int ldst = t * 8;

  auto stage = [&](int buf, int c0) {
    gll16(WT + (size_t)(iB + srow) * CIN + c0 + scol, &Hs[buf][ldst]);
    gll16(xb + (size_t)(jB + srow) * CIN + c0 + scol, &Bs[buf][ldst]);
    gll16(xb + (size_t)(jB + 64 + srow) * CIN + c0 + scol, &Bs[buf][2048 + ldst]);
  };

  int i0loc = (wid >> 1) * 32;
  int j0loc = (wid & 1) * 64;
  int r = lane & 15;
  int s = (lane >> 4) * 8;

  f32x4 acc[2][4] = {};
  stage(0, 0);
  __syncthreads();
  int cur = 0;
#pragma unroll 2
  for (int ks = 0; ks < CIN / 32; ++ks) {
    if (ks + 1 < CIN / 32) stage(cur ^ 1, (ks + 1) * 32);
    bf16x8 a[2], bb[4];
#pragma unroll
    for (int m = 0; m < 2; ++m)
      a[m] = *reinterpret_cast<const bf16x8*>(&Hs[cur][(i0loc + m * 16 + r) * 32 + s]);
#pragma unroll
    for (int n = 0; n < 4; ++n)
      bb[n] = *reinterpret_cast<const bf16x8*>(&Bs[cur][(j0loc + n * 16 + r) * 32 + s]);
#pragma unroll
    for (int m = 0; m < 2; ++m)
#pragma unroll
      for (int n = 0; n < 4; ++n)
        acc[m][n] = __builtin_amdgcn_mfma_f32_16x16x32_bf16(a[m], bb[n], acc[m][n], 0, 0, 0);
    __syncthreads();
    cur ^= 1;
  }

  float(*buf)[65] = ep[wid];
  int orow = (lane >> 4) * 4;
  int ocol = lane & 15;
  int i0 = iB + i0loc;
  int j0 = jB + j0loc;
#pragma unroll
  for (int m = 0; m < 2; ++m) {
#pragma unroll
    for (int n = 0; n < 4; ++n)
#pragma unroll
      for (int rr = 0; rr < 4; ++rr) buf[orow + rr][n * 16 + ocol] = acc[m][n][rr];
#pragma unroll
    for (int rr = 0; rr < 4; ++rr) {
      int row = rr * 4 + (lane >> 4);
      int kk = j0 + (lane & 15) * 4;
      float4 v4 = *(const float4*)&buf[row][(lane & 15) * 4];
      float4 nv = *(const float4*)(nrm + (size_t)b * KN + kk);
      ushort4 r4;
      r4.x = f2bf(v4.x * nv.x);
      r4.y = f2bf(v4.y * nv.y);
      r4.z = f2bf(v4.z * nv.z);
      r4.w = f2bf(v4.w * nv.w);
      *(ushort4*)(hg + ((size_t)brel * CMID + i0 + m * 16 + row) * KN + kk) = r4;
    }
  }
}

// ---------------- f32 per-node linear (layer 2 only, proven) -------------
template <int C, int M, bool MASK>
__global__ __launch_bounds__(256) void linear_kernel(const float* __restrict__ f,
                                                     const float* __restrict__ W,
                                                     ushort* __restrict__ outp,
                                                     const float* __restrict__ mTK) {
  int fl = blockIdx.x;
  int b = fl & 31;
  int o0 = (fl >> 5) * 8;
  __shared__ float Ws[C][8];
  for (int l = threadIdx.x; l < C * 8; l += 256) {
    int c = l >> 3, o = l & 7;
    Ws[c][o] = W[(size_t)c * M + o0 + o];
  }
  __syncthreads();
  int k0 = threadIdx.x * 4;
  const float* fb = f + (size_t)b * C * KN;
  float acc[8][4] = {};
  for (int c = 0; c < C; ++c) {
    float4 xv = *(const float4*)(fb + (size_t)c * KN + k0);
#pragma unroll
    for (int o = 0; o < 8; ++o) {
      float w = Ws[c][o];
      acc[o][0] += xv.x * w;
      acc[o][1] += xv.y * w;
      acc[o][2] += xv.z * w;
      acc[o][3] += xv.w * w;
    }
  }
  float ms[4] = {1.0f, 1.0f, 1.0f, 1.0f};
  if (MASK) {
#pragma unroll
    for (int jj = 0; jj < 4; ++jj) ms[jj] = mTK[(size_t)b * KN + k0 + jj] * INV_DS;
  }
#pragma unroll
  for (int o = 0; o < 8; ++o) {
    ushort4 r;
    r.x = f2bf(acc[o][0] * ms[0]);
    r.y = f2bf(acc[o][1] * ms[1]);
    r.z = f2bf(acc[o][2] * ms[2]);
    r.w = f2bf(acc[o][3] * ms[3]);
    *(ushort4*)(outp + ((size_t)b * M + o0 + o) * KN + k0) = r;
  }
}

// ---------------- MFMA s = relu(h @ A), At read from sim back halves -----
template <int M, bool LOCAL>
__global__ __launch_bounds__(256) void sgemmf_kernel(const ushort* __restrict__ hB,
                                                     const float* __restrict__ Asim,
                                                     float* __restrict__ outp, int bstart) {
  int brel = blockIdx.z;
  int b = bstart + brel;
  int t = threadIdx.x;
  int lane = t & 63;
  int wid = t >> 6;
  int iB = blockIdx.y * 64;
  int jB = blockIdx.x * 128;
  const ushort* hb = hB + (size_t)(LOCAL ? brel : b) * M * KN;
  const ushort* Ab = (const ushort*)(Asim + (size_t)brel * KN * KN);

  __shared__ ushort Hs[2][64 * 32];
  __shared__ ushort Bs[2][128 * 32];
  __shared__ float ep[4][16][65];

  int srow = t >> 2;
  int scol = (t & 3) * 8;
  int ldst = t * 8;

  auto stage = [&](int buf, int k0) {
    gll16(hb + (size_t)(iB + srow) * KN + k0 + scol, &Hs[buf][ldst]);
    gll16(Ab + (size_t)(jB + srow) * 2048 + 1024 + k0 + scol, &Bs[buf][ldst]);
    gll16(Ab + (size_t)(jB + 64 + srow) * 2048 + 1024 + k0 + scol, &Bs[buf][2048 + ldst]);
  };

  int i0loc = (wid >> 1) * 32;
  int j0loc = (wid & 1) * 64;
  int r = lane & 15;
  int s = (lane >> 4) * 8;

  f32x4 acc[2][4] = {};
  stage(0, 0);
  __syncthreads();
  int cur = 0;
#pragma unroll 2
  for (int ks = 0; ks < KN / 32; ++ks) {
    if (ks + 1 < KN / 32) stage(cur ^ 1, (ks + 1) * 32);
    bf16x8 a[2], bb[4];
#pragma unroll
    for (int m = 0; m < 2; ++m)
      a[m] = *reinterpret_cast<const bf16x8*>(&Hs[cur][(i0loc + m * 16 + r) * 32 + s]);
#pragma unroll
    for (int n = 0; n < 4; ++n)
      bb[n] = *reinterpret_cast<const bf16x8*>(&Bs[cur][(j0loc + n * 16 + r) * 32 + s]);
#pragma unroll
    for (int m = 0; m < 2; ++m)
#pragma unroll
      for (int n = 0; n < 4; ++n)
        acc[m][n] = __builtin_amdgcn_mfma_f32_16x16x32_bf16(a[m], bb[n], acc[m][n], 0, 0, 0);
    __syncthreads();
    cur ^= 1;
  }

  float(*buf)[65] = ep[wid];
  int orow = (lane >> 4) * 4;
  int ocol = lane & 15;
  int i0 = iB + i0loc;
  int j0 = jB + j0loc;
  float* ob = outp + (size_t)b * M * KN;
#pragma unroll
  for (int m = 0; m < 2; ++m) {
#pragma unroll
    for (int n = 0; n < 4; ++n)
#pragma unroll
      for (int rr = 0; rr < 4; ++rr) buf[orow + rr][n * 16 + ocol] = fmaxf(acc[m][n][rr], 0.0f);
#pragma unroll
    for (int rr = 0; rr < 4; ++rr) {
      int row = rr * 4 + (lane >> 4);
      float4 v4 = *(const float4*)&buf[row][(lane & 15) * 4];
      *(float4*)(ob + (size_t)(i0 + m * 16 + row) * KN + j0 + (lane & 15) * 4) = v4;
    }
  }
}

// ---------------- reductions ---------------------------------------------
__global__ void bag12_kernel(const float* __restrict__ emb1, const float* __restrict__ mTK,
                             const float* __restrict__ mTD, const float* __restrict__ imp,
                             float* __restrict__ bagk, float* __restrict__ bagd) {
  int c = blockIdx.x, b = blockIdx.y;
  int t = threadIdx.x;
  const float* e = emb1 + ((size_t)b * CMID + c) * KN;
  const float* ir = imp + (size_t)b * KN;
  const float* m1 = mTK + (size_t)b * KN;
  const float* m2 = mTD + (size_t)b * KN;
  float s1 = 0.0f, sd = 0.0f;
  for (int k = t; k < KN; k += 256) {
    float ev = e[k] * ir[k];
    s1 += ev * m1[k];
    sd += ev * m2[k];
  }
  __shared__ float r1[256], r2[256];
  r1[t] = s1;
  r2[t] = sd;
  __syncthreads();
  for (int st = 128; st > 0; st >>= 1) {
    if (t < st) {
      r1[t] += r1[t + st];
      r2[t] += r2[t + st];
    }
    __syncthreads();
  }
  if (t == 0) {
    bagk[(size_t)b * CMID + c] = r1[0] * INV_DS;
    bagd[(size_t)b * CMID + c] = r2[0] * INV_DS;
  }
}

__global__ void bag2_kernel(const float* __restrict__ s2, const float* __restrict__ mTK,
                            const float* __restrict__ imp, float* __restrict__ bag) {
  int o = blockIdx.x, b = blockIdx.y;
  int t = threadIdx.x;
  const float* sr = s2 + ((size_t)b * COUT + o) * KN;
  const float* ir = imp + (size_t)b * KN;
  const float* mr = mTK + (size_t)b * KN;
  float s = 0.0f;
  for (int k = t; k < KN; k += 256) s += sr[k] * mr[k] * ir[k];
  __shared__ float red[256];
  red[t] = s;
  __syncthreads();
  for (int st = 128; st > 0; st >>= 1) {
    if (t < st) red[t] += red[t + st];
    __syncthreads();
  }
  if (t == 0) bag[(size_t)b * COUT + o] = red[0];
}

__global__ void pooled_kernel(const float* __restrict__ x, const float* __restrict__ imp,
                              float* __restrict__ pooled) {
  int c = blockIdx.x, b = blockIdx.y;
  int t = threadIdx.x;
  const float* xr = x + ((size_t)b * CIN + c) * KN;
  const float* ir = imp + (size_t)b * KN;
  float s = 0.0f;
  for (int k = t; k < KN; k += 256) s += xr[k] * ir[k];
  __shared__ float red[256];
  red[t] = s;
  __syncthreads();
  for (int st = 128; st > 0; st >>= 1) {
    if (t < st) red[t] += red[t + st];
    __syncthreads();
  }
  if (t == 0) pooled[(size_t)b * CIN + c] = red[0];
}

__global__ void final_kernel(const float* __restrict__ pooled, const float* __restrict__ bag,
                             const float* __restrict__ id_w, const float* __restrict__ id_b,
                             const float* __restrict__ fc_w, float* __restrict__ out) {
  int b = blockIdx.x;
  int o = threadIdx.x;
  __shared__ float v[COUT];
  float s = id_b[o];
  const float* pr = pooled + (size_t)b * CIN;
  for (int c = 0; c < CIN; ++c) s += pr[c] * id_w[(size_t)c * COUT + o];
  v[o] = bag[(size_t)b * COUT + o] + fmaxf(s, 0.0f);
  __syncthreads();
  if (o < NCLS) {
    float acc = 0.0f;
    for (int oo = 0; oo < COUT; ++oo) acc += v[oo] * fc_w[(size_t)oo * NCLS + o];
    out[(size_t)b * NCLS + o] = acc;
  }
}

// ---------------- launch --------------------------------------------------
extern "C" void kernel_launch(void* const* d_in, const int* in_sizes, int n_in,
                              void* d_out, int out_size, void* d_ws, size_t ws_size,
                              hipStream_t stream) {
  const float* x = (const float*)d_in[0];
  const float* imp = (const float*)d_in[1];
  const float* rnd = (const float*)d_in[2];
  const float* W1 = (const float*)d_in[3];
  const float* W2 = (const float*)d_in[4];
  const float* fc_w = (const float*)d_in[5];
  const float* id_w = (const float*)d_in[6];
  const float* id_b = (const float*)d_in[7];
  float* out = (float*)d_out;
  float* emb1 = out + BN_ * NCLS;
  float* bagk = emb1 + (size_t)BN_ * CMID * KN;
  float* bagd = bagk + (size_t)BN_ * CMID;

  float* w = (float*)d_ws;
  size_t off = 0;
  auto take = [&](size_t n) {
    float* p = w + off;
    off += n;
    return p;
  };
  float* invSumP = take((size_t)BN_ * KN);
  float* invNX = take((size_t)BN_ * KN);
  float* invNE = take((size_t)BN_ * KN);
  float* nrmX = take((size_t)BN_ * KN);
  float* nrmE = take((size_t)BN_ * KN);
  float* topM = take((size_t)BN_ * KN);
  float* mTK = take((size_t)BN_ * KN);
  float* mTD = take((size_t)BN_ * KN);
  float* bag = take((size_t)BN_ * COUT);
  float* pooled = take((size_t)BN_ * CIN);
  ushort* W1T = (ushort*)take((size_t)CMID * CIN / 2);

  const size_t h2_f = (size_t)BN_ * COUT * KN / 2;
  const size_t s2_f = (size_t)BN_ * COUT * KN;
  const size_t xg1 = (size_t)CIN * KN / 2;   // per-batch xnT floats
  const size_t hg1 = (size_t)CMID * KN / 2;  // per-batch h floats
  const size_t eg1 = (size_t)CMID * KN / 2;  // per-batch enT floats

  size_t budget = ws_size / 4;
  int nb = 1;
  const int cands[6] = {32, 16, 8, 4, 2, 1};
  for (int ci = 0; ci < 6; ++ci) {
    size_t c = cands[ci];
    size_t uA = c * (xg1 + hg1);
    size_t uB = h2_f + s2_f + c * eg1;
    size_t uMax = uA > uB ? uA : uB;
    if (off + uMax + c * (size_t)KN * KN <= budget) {
      nb = (int)c;
      break;
    }
  }
  size_t uA = (size_t)nb * (xg1 + hg1);
  size_t uB = h2_f + s2_f + (size_t)nb * eg1;
  float* U = take(uA > uB ? uA : uB);
  ushort* xnT = (ushort*)U;
  ushort* h = (ushort*)(U + (size_t)nb * xg1);
  ushort* enT = (ushort*)U;
  ushort* h2 = (ushort*)(U + (size_t)nb * eg1);
  float* s2 = U + (size_t)nb * eg1 + h2_f;
  float* simA = take((size_t)nb * KN * KN);

  masks1_kernel<<<dim3(KN / 256, BN_), 256, 0, stream>>>(imp, topM);
  masks2_kernel<<<dim3(KN / 256, BN_), 256, 0, stream>>>(rnd, topM, mTK, mTD);
  psum_kernel<<<dim3(KN / 256, BN_), 256, 0, stream>>>(imp, invSumP);
  colnorm_kernel<CIN><<<(BN_ * KN) / 256, 256, 0, stream>>>(x, invNX, nrmX);
  wtrans1_kernel<<<(CMID * CIN) / 256, 256, 0, stream>>>(W1, W1T);

  for (int bs = 0; bs < BN_; bs += nb) {
    xpose_kernel<CIN><<<dim3(KN / 64, CIN / 64, nb), 256, 0, stream>>>(
        x, invNX, (__hip_bfloat16*)xnT, bs);
    linf1_kernel<<<dim3(KN / 128, CMID / 64, nb), 256, 0, stream>>>(xnT, W1T, nrmX, h, bs);
    simf_kernel<CIN><<<nb * 64, 256, 0, stream>>>(xnT, simA, nb);
    thrfin_kernel<<<dim3(KN / 4, nb), 256, 0, stream>>>(simA, imp, invSumP, bs);
    at_kernel<<<dim3(KN / 64, KN / 64, nb), 256, 0, stream>>>(simA);
    sgemmf_kernel<CMID, true><<<dim3(KN / 128, CMID / 64, nb), 256, 0, stream>>>(h, simA, emb1,
                                                                                 bs);
  }

  colnorm_kernel<CMID><<<(BN_ * KN) / 256, 256, 0, stream>>>(emb1, invNE, nrmE);
  linear_kernel<CMID, COUT, true><<<(COUT / 8) * BN_, 256, 0, stream>>>(emb1, W2, h2, mTK);

  for (int bs = 0; bs < BN_; bs += nb) {
    xpose_kernel<CMID><<<dim3(KN / 64, CMID / 64, nb), 256, 0, stream>>>(
        emb1, invNE, (__hip_bfloat16*)enT, bs);
    simf_kernel<CMID><<<nb * 64, 256, 0, stream>>>(enT, simA, nb);
    thrfin_kernel<<<dim3(KN / 4, nb), 256, 0, stream>>>(simA, imp, invSumP, bs);
    at_kernel<<<dim3(KN / 64, KN / 64, nb), 256, 0, stream>>>(simA);
    sgemmf_kernel<COUT, false><<<dim3(KN / 128, COUT / 64, nb), 256, 0, stream>>>(h2, simA, s2,
                                                                                  bs);
  }

  bag12_kernel<<<dim3(CMID, BN_), 256, 0, stream>>>(emb1, mTK, mTD, imp, bagk, bagd);
  bag2_kernel<<<dim3(COUT, BN_), 256, 0, stream>>>(s2, mTK, imp, bag);
  pooled_kernel<<<dim3(CIN, BN_), 256, 0, stream>>>(x, imp, pooled);
  final_kernel<<<BN_, 64, 0, stream>>>(pooled, bag, id_w, id_b, fc_w, out);
}